// Round 1
// baseline (6910.058 us; speedup 1.0000x reference)
//
#include <hip/hip_runtime.h>

#define TPB 256
#define PPT 4

// ---------------- direct conv (correlation, NCHW in, OIHW weights) ----------------
// Each block: COB output channels for one n, TPB*PPT pixels (flat). Weights for the
// COB channels staged in LDS, interleaved [tap][COB] so the COB reads are contiguous.
template<int K, int S, int P, int COB, bool RIN, bool ROUT, bool RES>
__global__ __launch_bounds__(TPB) void conv_direct(
    const float* __restrict__ in, const float* __restrict__ w,
    const float* __restrict__ bias, const float* __restrict__ res,
    float* __restrict__ out,
    int Cin, int Hin, int Win, int Cout, int Hout, int Wout)
{
    const int tid = threadIdx.x;
    const int co0 = blockIdx.y * COB;
    const int n   = blockIdx.z;
    const int KK  = K * K;
    const int WSZ = Cin * KK;
    extern __shared__ float wl[];
    for (int i = tid; i < COB * WSZ; i += TPB) {
        int c = i / WSZ, off = i - c * WSZ;
        wl[off * COB + c] = w[(co0 + c) * WSZ + off];
    }
    __syncthreads();

    const int npix = Hout * Wout;
    const int p0 = blockIdx.x * (TPB * PPT) + tid;

    int iyb[PPT], ixb[PPT];
    float acc[COB][PPT];
#pragma unroll
    for (int c = 0; c < COB; c++)
#pragma unroll
        for (int j = 0; j < PPT; j++) acc[c][j] = 0.f;

#pragma unroll
    for (int j = 0; j < PPT; j++) {
        int p = p0 + j * TPB;
        if (p >= npix) p = 0;
        int oy = p / Wout, ox = p - oy * Wout;
        iyb[j] = oy * S - P;
        ixb[j] = ox * S - P;
    }

    const int hwin = Hin * Win;
    const float* pin = in + (size_t)(n * Cin) * hwin;

    for (int ci = 0; ci < Cin; ci++) {
        const float* pc = pin + ci * hwin;
#pragma unroll
        for (int ky = 0; ky < K; ky++) {
#pragma unroll
            for (int kx = 0; kx < K; kx++) {
                const int t = ky * K + kx;
                float wv[COB];
#pragma unroll
                for (int c = 0; c < COB; c++) wv[c] = wl[(ci * KK + t) * COB + c];
#pragma unroll
                for (int j = 0; j < PPT; j++) {
                    float v;
                    if (K == 1 && P == 0 && S == 1) {
                        v = pc[iyb[j] * Win + ixb[j]];
                    } else {
                        int iy = iyb[j] + ky, ix = ixb[j] + kx;
                        v = 0.f;
                        if ((unsigned)iy < (unsigned)Hin && (unsigned)ix < (unsigned)Win)
                            v = pc[iy * Win + ix];
                    }
                    if (RIN) v = fmaxf(v, 0.f);
#pragma unroll
                    for (int c = 0; c < COB; c++)
                        acc[c][j] = fmaf(wv[c], v, acc[c][j]);
                }
            }
        }
    }

#pragma unroll
    for (int c = 0; c < COB; c++) {
        const float bv = bias[co0 + c];
        float* po = out + (size_t)(n * Cout + co0 + c) * npix;
        const float* pr = res + (size_t)(n * Cout + co0 + c) * npix;
#pragma unroll
        for (int j = 0; j < PPT; j++) {
            int p = p0 + j * TPB;
            if (p < npix) {
                float v = acc[c][j] + bv;
                if (RES) v += pr[p];
                if (ROUT) v = fmaxf(v, 0.f);
                po[p] = v;
            }
        }
    }
}

// ---------------- transpose conv k=4 s=2 p=1 (gather form) ----------------
// out[oy,ox] has exactly 2x2 taps: ky = (oy&1)+2*ty, iy = ((oy+ky0-2)>>1)+ty (+j rows).
// Threads' PPT pixels stride by 2 rows so tap parity is invariant across j.
template<int COB, bool RIN, bool ROUT>
__global__ __launch_bounds__(TPB) void convt4s2(
    const float* __restrict__ in, const float* __restrict__ w,
    const float* __restrict__ bias, float* __restrict__ out,
    int Cin, int Hin, int Win, int Cout, int Hout, int Wout, int segs)
{
    const int tid = threadIdx.x;
    const int co0 = blockIdx.y * COB;
    const int n   = blockIdx.z;
    const int WSZ = Cin * 16;
    extern __shared__ float wl[];
    for (int i = tid; i < COB * WSZ; i += TPB) {
        int c = i / WSZ, off = i - c * WSZ;
        wl[off * COB + c] = w[(co0 + c) * WSZ + off];
    }
    __syncthreads();

    const int gr = blockIdx.x / segs;
    const int sg = blockIdx.x - gr * segs;
    const int base = sg * TPB + tid;            // within a 2-row pair (2*Wout px)
    const int rowin = base / Wout;              // 0 or 1
    const int ox  = base - rowin * Wout;
    const int oy0 = gr * (2 * PPT) + rowin;

    const int ky0 = oy0 & 1, kx0 = ox & 1;
    const int iyb0 = (oy0 + ky0 - 2) >> 1;
    const int ixb  = (ox  + kx0 - 2) >> 1;

    float acc[COB][PPT];
#pragma unroll
    for (int c = 0; c < COB; c++)
#pragma unroll
        for (int j = 0; j < PPT; j++) acc[c][j] = 0.f;

    const int hwin = Hin * Win;
    const float* pin = in + (size_t)(n * Cin) * hwin;

    for (int ci = 0; ci < Cin; ci++) {
        const float* pc = pin + ci * hwin;
#pragma unroll
        for (int ty = 0; ty < 2; ty++) {
#pragma unroll
            for (int tx = 0; tx < 2; tx++) {
                const int widx = (ky0 + 2 * ty) * 4 + (kx0 + 2 * tx);
                float wv[COB];
#pragma unroll
                for (int c = 0; c < COB; c++) wv[c] = wl[widx * COB + c];
                const int ix = ixb + tx;
                const bool xok = (unsigned)ix < (unsigned)Win;
#pragma unroll
                for (int j = 0; j < PPT; j++) {
                    int iy = iyb0 + j + ty;
                    float v = 0.f;
                    if (xok && (unsigned)iy < (unsigned)Hin) v = pc[iy * Win + ix];
                    if (RIN) v = fmaxf(v, 0.f);
#pragma unroll
                    for (int c = 0; c < COB; c++)
                        acc[c][j] = fmaf(wv[c], v, acc[c][j]);
                }
            }
        }
    }

#pragma unroll
    for (int c = 0; c < COB; c++) {
        const float bv = bias[co0 + c];
        float* po = out + (size_t)(n * Cout + co0 + c) * Hout * Wout;
#pragma unroll
        for (int j = 0; j < PPT; j++) {
            int oy = oy0 + 2 * j;
            float v = acc[c][j] + bv;
            if (ROUT) v = fmaxf(v, 0.f);
            po[oy * Wout + ox] = v;
        }
    }
}

// ---------------- VQ: nearest codebook entry, q gather, SSE partials, histogram ----------------
__global__ __launch_bounds__(256) void vq_kernel(
    const float* __restrict__ z, const float* __restrict__ cb,
    float* __restrict__ q, float* __restrict__ ssep, int* __restrict__ hist,
    int HW)
{
    __shared__ float cl[128 * 64];
    __shared__ int   hl[512];
    __shared__ float red[4];
    const int tid = threadIdx.x;
    const int t   = blockIdx.x * 256 + tid;
    for (int i = tid; i < 512; i += 256) hl[i] = 0;

    const int n   = t / HW;
    const int pix = t - n * HW;
    const float* zp = z + (size_t)(n * 64) * HW + pix;
    float x[64];
#pragma unroll
    for (int d = 0; d < 64; d++) x[d] = zp[d * HW];

    float bestd = 3.4e38f;
    int   besti = 0;
    for (int c0 = 0; c0 < 512; c0 += 128) {
        __syncthreads();
        const float4* src = (const float4*)(cb + c0 * 64);
#pragma unroll
        for (int i = 0; i < 8; i++)
            ((float4*)cl)[tid + i * 256] = src[tid + i * 256];
        __syncthreads();
        for (int k = 0; k < 128; k++) {
            const float4* c4 = (const float4*)(cl + k * 64);
            float dist = 0.f;
#pragma unroll
            for (int d4 = 0; d4 < 16; d4++) {
                float4 c = c4[d4];
                float a0 = x[d4 * 4 + 0] - c.x;
                float a1 = x[d4 * 4 + 1] - c.y;
                float a2 = x[d4 * 4 + 2] - c.z;
                float a3 = x[d4 * 4 + 3] - c.w;
                dist = fmaf(a0, a0, fmaf(a1, a1, fmaf(a2, a2, fmaf(a3, a3, dist))));
            }
            if (dist < bestd) { bestd = dist; besti = c0 + k; }  // strict < keeps first min (argmin tie rule)
        }
    }

    float* qp = q + (size_t)(n * 64) * HW + pix;
    const float* cbest = cb + (size_t)besti * 64;
#pragma unroll
    for (int d = 0; d < 64; d++) qp[d * HW] = cbest[d];

    atomicAdd(&hl[besti], 1);

    float s = bestd;                      // == sum_d (q_d - x_d)^2 for this token
#pragma unroll
    for (int o = 32; o > 0; o >>= 1) s += __shfl_down(s, o, 64);
    if ((tid & 63) == 0) red[tid >> 6] = s;
    __syncthreads();
    if (tid == 0) ssep[blockIdx.x] = red[0] + red[1] + red[2] + red[3];
    for (int i = tid; i < 512; i += 256) if (hl[i] > 0) atomicAdd(&hist[i], hl[i]);
}

__global__ void vq_init(int* hist)
{
    for (int i = threadIdx.x; i < 512; i += 256) hist[i] = 0;
}

__global__ __launch_bounds__(256) void vq_finalize(
    const float* __restrict__ ssep, const int* __restrict__ hist,
    float* __restrict__ o_loss, float* __restrict__ o_perp)
{
    __shared__ float red[256];
    const int tid = threadIdx.x;
    float h = 0.f;
    for (int i = tid; i < 512; i += 256) {
        float p = (float)hist[i] * (1.0f / 65536.0f);
        h -= p * logf(p + 1e-10f);
    }
    red[tid] = h;
    __syncthreads();
    for (int st = 128; st > 0; st >>= 1) {
        if (tid < st) red[tid] += red[tid + st];
        __syncthreads();
    }
    const float H = red[0];
    __syncthreads();
    red[tid] = ssep[tid];
    __syncthreads();
    for (int st = 128; st > 0; st >>= 1) {
        if (tid < st) red[tid] += red[tid + st];
        __syncthreads();
    }
    if (tid == 0) {
        *o_loss = 1.25f * red[0] / 4194304.0f;   // (1+beta)*mean((q-x)^2), 16*64*64*64 elems
        *o_perp = expf(H);
    }
}

extern "C" void kernel_launch(void* const* d_in, const int* in_sizes, int n_in,
                              void* d_out, int out_size, void* d_ws, size_t ws_size,
                              hipStream_t stream)
{
    const float* x       = (const float*)d_in[0];
    const float* enc_w1  = (const float*)d_in[1];
    const float* enc_b1  = (const float*)d_in[2];
    const float* enc_w2  = (const float*)d_in[3];
    const float* enc_b2  = (const float*)d_in[4];
    const float* enc_w3  = (const float*)d_in[5];
    const float* enc_b3  = (const float*)d_in[6];
    const float* enc_rw3 = (const float*)d_in[7];
    const float* enc_rb3 = (const float*)d_in[8];
    const float* enc_rw1 = (const float*)d_in[9];
    const float* enc_rb1 = (const float*)d_in[10];
    const float* pre_w   = (const float*)d_in[11];
    const float* pre_b   = (const float*)d_in[12];
    const float* cb      = (const float*)d_in[13];
    const float* dec_w1  = (const float*)d_in[14];
    const float* dec_b1  = (const float*)d_in[15];
    const float* dec_rw3 = (const float*)d_in[16];
    const float* dec_rb3 = (const float*)d_in[17];
    const float* dec_rw1 = (const float*)d_in[18];
    const float* dec_rb1 = (const float*)d_in[19];
    const float* dw1     = (const float*)d_in[20];
    const float* db1     = (const float*)d_in[21];
    const float* dw2     = (const float*)d_in[22];
    const float* db2     = (const float*)d_in[23];

    float* o      = (float*)d_out;
    float* loss_p = o;
    float* recon  = o + 1;
    float* perp_p = o + 1 + 16 * 3 * 256 * 256;

    // workspace layout (floats): A 16.78M | B 8.39M | C 8.39M | D 2.10M | SSE 256 | HIST 512
    float* ws  = (float*)d_ws;
    float* A   = ws;                     // h1 (16x64x128x128); later q; later dec_t1 out
    float* B   = A + 16777216;           // h2; later z
    float* C   = B + 8388608;            // h3/h_res/d1/d_res (in-place residual adds)
    float* Dt  = C + 8388608;            // residual 32-ch temp
    float* SSE = Dt + 2097152;           // 256 per-block partials
    int*   HIST = (int*)(SSE + 256);     // 512 counts
    float* Q   = A;

    const int N = 16;

    // encoder
    conv_direct<4,2,1,4,false,true ,false><<<dim3(16,16,N), TPB, 4*3*16*4,  stream>>>(
        x, enc_w1, enc_b1, nullptr, A, 3, 256, 256, 64, 128, 128);
    conv_direct<4,2,1,4,false,true ,false><<<dim3(4,32,N),  TPB, 4*64*16*4, stream>>>(
        A, enc_w2, enc_b2, nullptr, B, 64, 128, 128, 128, 64, 64);
    conv_direct<3,1,1,4,false,false,false><<<dim3(4,32,N),  TPB, 4*128*9*4, stream>>>(
        B, enc_w3, enc_b3, nullptr, C, 128, 64, 64, 128, 64, 64);
    // enc residual stack (in-place adds on C)
    conv_direct<3,1,1,4,true ,false,false><<<dim3(4,8,N),   TPB, 4*128*9*4, stream>>>(
        C, enc_rw3, enc_rb3, nullptr, Dt, 128, 64, 64, 32, 64, 64);
    conv_direct<1,1,0,4,true ,false,true ><<<dim3(4,32,N),  TPB, 4*32*1*4,  stream>>>(
        Dt, enc_rw1, enc_rb1, C, C, 32, 64, 64, 128, 64, 64);
    conv_direct<3,1,1,4,true ,false,false><<<dim3(4,8,N),   TPB, 4*128*9*4, stream>>>(
        C, enc_rw3 + 32*128*9, enc_rb3 + 32, nullptr, Dt, 128, 64, 64, 32, 64, 64);
    conv_direct<1,1,0,4,true ,false,true ><<<dim3(4,32,N),  TPB, 4*32*1*4,  stream>>>(
        Dt, enc_rw1 + 128*32, enc_rb1 + 128, C, C, 32, 64, 64, 128, 64, 64);
    // pre-VQ 1x1 (fuses the stack's final relu)
    conv_direct<1,1,0,4,true ,false,false><<<dim3(4,16,N),  TPB, 4*128*1*4, stream>>>(
        C, pre_w, pre_b, nullptr, B, 128, 64, 64, 64, 64, 64);

    // VQ
    vq_init<<<dim3(1), dim3(256), 0, stream>>>(HIST);
    vq_kernel<<<dim3(256), dim3(256), 0, stream>>>(B, cb, Q, SSE, HIST, 64 * 64);
    vq_finalize<<<dim3(1), dim3(256), 0, stream>>>(SSE, HIST, loss_p, perp_p);

    // decoder
    conv_direct<3,1,1,4,false,false,false><<<dim3(4,32,N),  TPB, 4*64*9*4,  stream>>>(
        Q, dec_w1, dec_b1, nullptr, C, 64, 64, 64, 128, 64, 64);
    conv_direct<3,1,1,4,true ,false,false><<<dim3(4,8,N),   TPB, 4*128*9*4, stream>>>(
        C, dec_rw3, dec_rb3, nullptr, Dt, 128, 64, 64, 32, 64, 64);
    conv_direct<1,1,0,4,true ,false,true ><<<dim3(4,32,N),  TPB, 4*32*1*4,  stream>>>(
        Dt, dec_rw1, dec_rb1, C, C, 32, 64, 64, 128, 64, 64);
    conv_direct<3,1,1,4,true ,false,false><<<dim3(4,8,N),   TPB, 4*128*9*4, stream>>>(
        C, dec_rw3 + 32*128*9, dec_rb3 + 32, nullptr, Dt, 128, 64, 64, 32, 64, 64);
    conv_direct<1,1,0,4,true ,false,true ><<<dim3(4,32,N),  TPB, 4*32*1*4,  stream>>>(
        Dt, dec_rw1 + 128*32, dec_rb1 + 128, C, C, 32, 64, 64, 128, 64, 64);
    // transpose convs (first one fuses the dec stack's final relu on input)
    convt4s2<4,true ,true ><<<dim3(16,16,N), TPB, 4*128*16*4, stream>>>(
        C, dw1, db1, A, 128, 64, 64, 64, 128, 128, 1);
    convt4s2<3,false,false><<<dim3(64,1,N),  TPB, 3*64*16*4,  stream>>>(
        A, dw2, db2, recon, 64, 128, 128, 3, 256, 256, 2);
}

// Round 2
// 4569.043 us; speedup vs baseline: 1.5124x; 1.5124x over previous
//
#include <hip/hip_runtime.h>

#define TPB 256

// ---------------- direct conv (correlation, NCHW in, OIHW weights) ----------------
// Each block: COB output channels for one n, TPB*PPT pixels (flat). Weights staged in
// LDS in CICH-channel chunks, interleaved [tap][COB] so COB reads broadcast.
template<int K, int S, int P, int COB, int CICH, int PPT, bool RIN, bool ROUT, bool RES>
__global__ __launch_bounds__(TPB) void conv_direct(
    const float* __restrict__ in, const float* __restrict__ w,
    const float* __restrict__ bias, const float* __restrict__ res,
    float* __restrict__ out,
    int Cin, int Hin, int Win, int Cout, int Hout, int Wout)
{
    const int tid = threadIdx.x;
    const int co0 = blockIdx.y * COB;
    const int n   = blockIdx.z;
    const int KK  = K * K;
    extern __shared__ float wl[];

    const int npix = Hout * Wout;
    const int p0 = blockIdx.x * (TPB * PPT) + tid;

    int iyb[PPT], ixb[PPT];
    float acc[COB][PPT];
#pragma unroll
    for (int c = 0; c < COB; c++)
#pragma unroll
        for (int j = 0; j < PPT; j++) acc[c][j] = 0.f;

#pragma unroll
    for (int j = 0; j < PPT; j++) {
        int p = p0 + j * TPB;
        if (p >= npix) p = 0;
        int oy = p / Wout, ox = p - oy * Wout;
        iyb[j] = oy * S - P;
        ixb[j] = ox * S - P;
    }

    const int hwin = Hin * Win;
    const float* pin = in + (size_t)(n * Cin) * hwin;

    for (int ci0 = 0; ci0 < Cin; ci0 += CICH) {
        __syncthreads();
        for (int i = tid; i < COB * CICH * KK; i += TPB) {
            int c = i / (CICH * KK), off = i - c * (CICH * KK);
            wl[off * COB + c] = w[(size_t)(co0 + c) * Cin * KK + ci0 * KK + off];
        }
        __syncthreads();
        const float* pin0 = pin + (size_t)ci0 * hwin;
        for (int ci = 0; ci < CICH; ci++) {
            const float* pc = pin0 + ci * hwin;
#pragma unroll
            for (int ky = 0; ky < K; ky++) {
#pragma unroll
                for (int kx = 0; kx < K; kx++) {
                    const int t = ky * K + kx;
                    float wv[COB];
#pragma unroll
                    for (int c = 0; c < COB; c++) wv[c] = wl[(ci * KK + t) * COB + c];
#pragma unroll
                    for (int j = 0; j < PPT; j++) {
                        float v;
                        if (K == 1 && P == 0 && S == 1) {
                            v = pc[iyb[j] * Win + ixb[j]];
                        } else {
                            int iy = iyb[j] + ky, ix = ixb[j] + kx;
                            v = 0.f;
                            if ((unsigned)iy < (unsigned)Hin && (unsigned)ix < (unsigned)Win)
                                v = pc[iy * Win + ix];
                        }
                        if (RIN) v = fmaxf(v, 0.f);
#pragma unroll
                        for (int c = 0; c < COB; c++)
                            acc[c][j] = fmaf(wv[c], v, acc[c][j]);
                    }
                }
            }
        }
    }

#pragma unroll
    for (int c = 0; c < COB; c++) {
        const float bv = bias[co0 + c];
        float* po = out + (size_t)(n * Cout + co0 + c) * npix;
        const float* pr = res + (size_t)(n * Cout + co0 + c) * npix;
#pragma unroll
        for (int j = 0; j < PPT; j++) {
            int p = p0 + j * TPB;
            if (p < npix) {
                float v = acc[c][j] + bv;
                if (RES) v += pr[p];
                if (ROUT) v = fmaxf(v, 0.f);
                po[p] = v;
            }
        }
    }
}

// ---------------- transpose conv k=4 s=2 p=1 (gather form) ----------------
// out[oy,ox] has exactly 2x2 taps: ky = (oy&1)+2*ty, iy = ((oy+ky0-2)>>1)+ty (+j rows).
// Threads' 4 pixels stride by 2 rows so tap parity is invariant across j.
template<int COB, int CICH, bool RIN, bool ROUT>
__global__ __launch_bounds__(TPB) void convt4s2(
    const float* __restrict__ in, const float* __restrict__ w,
    const float* __restrict__ bias, float* __restrict__ out,
    int Cin, int Hin, int Win, int Cout, int Hout, int Wout, int segs)
{
    const int PPT = 4;
    const int tid = threadIdx.x;
    const int co0 = blockIdx.y * COB;
    const int n   = blockIdx.z;
    extern __shared__ float wl[];

    const int gr = blockIdx.x / segs;
    const int sg = blockIdx.x - gr * segs;
    const int base = sg * TPB + tid;            // within a 2-row pair (2*Wout px)
    const int rowin = base / Wout;              // 0 or 1
    const int ox  = base - rowin * Wout;
    const int oy0 = gr * (2 * PPT) + rowin;

    const int ky0 = oy0 & 1, kx0 = ox & 1;
    const int iyb0 = (oy0 + ky0 - 2) >> 1;
    const int ixb  = (ox  + kx0 - 2) >> 1;

    float acc[COB][PPT];
#pragma unroll
    for (int c = 0; c < COB; c++)
#pragma unroll
        for (int j = 0; j < PPT; j++) acc[c][j] = 0.f;

    const int hwin = Hin * Win;
    const float* pin = in + (size_t)(n * Cin) * hwin;

    for (int ci0 = 0; ci0 < Cin; ci0 += CICH) {
        __syncthreads();
        for (int i = tid; i < COB * CICH * 16; i += TPB) {
            int c = i / (CICH * 16), off = i - c * (CICH * 16);
            wl[off * COB + c] = w[(size_t)(co0 + c) * Cin * 16 + ci0 * 16 + off];
        }
        __syncthreads();
        const float* pin0 = pin + (size_t)ci0 * hwin;
        for (int ci = 0; ci < CICH; ci++) {
            const float* pc = pin0 + ci * hwin;
#pragma unroll
            for (int ty = 0; ty < 2; ty++) {
#pragma unroll
                for (int tx = 0; tx < 2; tx++) {
                    const int widx = (ky0 + 2 * ty) * 4 + (kx0 + 2 * tx);
                    float wv[COB];
#pragma unroll
                    for (int c = 0; c < COB; c++) wv[c] = wl[(ci * 16 + widx) * COB + c];
                    const int ix = ixb + tx;
                    const bool xok = (unsigned)ix < (unsigned)Win;
#pragma unroll
                    for (int j = 0; j < PPT; j++) {
                        int iy = iyb0 + j + ty;
                        float v = 0.f;
                        if (xok && (unsigned)iy < (unsigned)Hin) v = pc[iy * Win + ix];
                        if (RIN) v = fmaxf(v, 0.f);
#pragma unroll
                        for (int c = 0; c < COB; c++)
                            acc[c][j] = fmaf(wv[c], v, acc[c][j]);
                    }
                }
            }
        }
    }

#pragma unroll
    for (int c = 0; c < COB; c++) {
        const float bv = bias[co0 + c];
        float* po = out + (size_t)(n * Cout + co0 + c) * Hout * Wout;
#pragma unroll
        for (int j = 0; j < PPT; j++) {
            int oy = oy0 + 2 * j;
            float v = acc[c][j] + bv;
            if (ROUT) v = fmaxf(v, 0.f);
            po[oy * Wout + ox] = v;
        }
    }
}

// ---------------- VQ: nearest codebook entry, q gather, SSE partials, histogram ----------------
__global__ __launch_bounds__(256) void vq_kernel(
    const float* __restrict__ z, const float* __restrict__ cb,
    float* __restrict__ q, float* __restrict__ ssep, int* __restrict__ hist,
    int HW)
{
    __shared__ float cl[128 * 64];
    __shared__ int   hl[512];
    __shared__ float red[4];
    const int tid = threadIdx.x;
    const int t   = blockIdx.x * 256 + tid;
    for (int i = tid; i < 512; i += 256) hl[i] = 0;

    const int n   = t / HW;
    const int pix = t - n * HW;
    const float* zp = z + (size_t)(n * 64) * HW + pix;
    float x[64];
#pragma unroll
    for (int d = 0; d < 64; d++) x[d] = zp[d * HW];

    float bestd = 3.4e38f;
    int   besti = 0;
    for (int c0 = 0; c0 < 512; c0 += 128) {
        __syncthreads();
        const float4* src = (const float4*)(cb + c0 * 64);
#pragma unroll
        for (int i = 0; i < 8; i++)
            ((float4*)cl)[tid + i * 256] = src[tid + i * 256];
        __syncthreads();
        for (int k = 0; k < 128; k++) {
            const float4* c4 = (const float4*)(cl + k * 64);
            float dist = 0.f;
#pragma unroll
            for (int d4 = 0; d4 < 16; d4++) {
                float4 c = c4[d4];
                float a0 = x[d4 * 4 + 0] - c.x;
                float a1 = x[d4 * 4 + 1] - c.y;
                float a2 = x[d4 * 4 + 2] - c.z;
                float a3 = x[d4 * 4 + 3] - c.w;
                dist = fmaf(a0, a0, fmaf(a1, a1, fmaf(a2, a2, fmaf(a3, a3, dist))));
            }
            if (dist < bestd) { bestd = dist; besti = c0 + k; }  // strict < keeps first min (argmin tie rule)
        }
    }

    float* qp = q + (size_t)(n * 64) * HW + pix;
    const float* cbest = cb + (size_t)besti * 64;
#pragma unroll
    for (int d = 0; d < 64; d++) qp[d * HW] = cbest[d];

    atomicAdd(&hl[besti], 1);

    float s = bestd;                      // == sum_d (q_d - x_d)^2 for this token
#pragma unroll
    for (int o = 32; o > 0; o >>= 1) s += __shfl_down(s, o, 64);
    if ((tid & 63) == 0) red[tid >> 6] = s;
    __syncthreads();
    if (tid == 0) ssep[blockIdx.x] = red[0] + red[1] + red[2] + red[3];
    for (int i = tid; i < 512; i += 256) if (hl[i] > 0) atomicAdd(&hist[i], hl[i]);
}

__global__ void vq_init(int* hist)
{
    for (int i = threadIdx.x; i < 512; i += 256) hist[i] = 0;
}

__global__ __launch_bounds__(256) void vq_finalize(
    const float* __restrict__ ssep, const int* __restrict__ hist,
    float* __restrict__ o_loss, float* __restrict__ o_perp)
{
    __shared__ float red[256];
    const int tid = threadIdx.x;
    float h = 0.f;
    for (int i = tid; i < 512; i += 256) {
        float p = (float)hist[i] * (1.0f / 65536.0f);
        h -= p * logf(p + 1e-10f);
    }
    red[tid] = h;
    __syncthreads();
    for (int st = 128; st > 0; st >>= 1) {
        if (tid < st) red[tid] += red[tid + st];
        __syncthreads();
    }
    const float H = red[0];
    __syncthreads();
    red[tid] = ssep[tid];
    __syncthreads();
    for (int st = 128; st > 0; st >>= 1) {
        if (tid < st) red[tid] += red[tid + st];
        __syncthreads();
    }
    if (tid == 0) {
        *o_loss = 1.25f * red[0] / 4194304.0f;   // (1+beta)*mean((q-x)^2), 16*64*64*64 elems
        *o_perp = expf(H);
    }
}

extern "C" void kernel_launch(void* const* d_in, const int* in_sizes, int n_in,
                              void* d_out, int out_size, void* d_ws, size_t ws_size,
                              hipStream_t stream)
{
    const float* x       = (const float*)d_in[0];
    const float* enc_w1  = (const float*)d_in[1];
    const float* enc_b1  = (const float*)d_in[2];
    const float* enc_w2  = (const float*)d_in[3];
    const float* enc_b2  = (const float*)d_in[4];
    const float* enc_w3  = (const float*)d_in[5];
    const float* enc_b3  = (const float*)d_in[6];
    const float* enc_rw3 = (const float*)d_in[7];
    const float* enc_rb3 = (const float*)d_in[8];
    const float* enc_rw1 = (const float*)d_in[9];
    const float* enc_rb1 = (const float*)d_in[10];
    const float* pre_w   = (const float*)d_in[11];
    const float* pre_b   = (const float*)d_in[12];
    const float* cb      = (const float*)d_in[13];
    const float* dec_w1  = (const float*)d_in[14];
    const float* dec_b1  = (const float*)d_in[15];
    const float* dec_rw3 = (const float*)d_in[16];
    const float* dec_rb3 = (const float*)d_in[17];
    const float* dec_rw1 = (const float*)d_in[18];
    const float* dec_rb1 = (const float*)d_in[19];
    const float* dw1     = (const float*)d_in[20];
    const float* db1     = (const float*)d_in[21];
    const float* dw2     = (const float*)d_in[22];
    const float* db2     = (const float*)d_in[23];

    float* o      = (float*)d_out;
    float* loss_p = o;
    float* recon  = o + 1;
    float* perp_p = o + 1 + 16 * 3 * 256 * 256;

    // workspace layout (floats): A 16.78M | B 8.39M | C 8.39M | D 2.10M | SSE 256 | HIST 512
    float* ws  = (float*)d_ws;
    float* A   = ws;                     // h1 (16x64x128x128); later q; later dec_t1 out
    float* B   = A + 16777216;           // h2; later z
    float* C   = B + 8388608;            // h3/h_res/d1/d_res (in-place residual adds)
    float* Dt  = C + 8388608;            // residual 32-ch temp
    float* SSE = Dt + 2097152;           // 256 per-block partials
    int*   HIST = (int*)(SSE + 256);     // 512 counts
    float* Q   = A;

    const int N = 16;

    // encoder
    conv_direct<4,2,1,8,3,4,false,true ,false><<<dim3(16,8,N), TPB, 8*3*16*4,  stream>>>(
        x, enc_w1, enc_b1, nullptr, A, 3, 256, 256, 64, 128, 128);
    conv_direct<4,2,1,8,32,4,false,true ,false><<<dim3(4,16,N), TPB, 8*32*16*4, stream>>>(
        A, enc_w2, enc_b2, nullptr, B, 64, 128, 128, 128, 64, 64);
    conv_direct<3,1,1,8,32,4,false,false,false><<<dim3(4,16,N), TPB, 8*32*9*4, stream>>>(
        B, enc_w3, enc_b3, nullptr, C, 128, 64, 64, 128, 64, 64);
    // enc residual stack (in-place adds on C)
    conv_direct<3,1,1,8,32,2,true ,false,false><<<dim3(8,4,N),  TPB, 8*32*9*4, stream>>>(
        C, enc_rw3, enc_rb3, nullptr, Dt, 128, 64, 64, 32, 64, 64);
    conv_direct<1,1,0,8,32,4,true ,false,true ><<<dim3(4,16,N), TPB, 8*32*1*4, stream>>>(
        Dt, enc_rw1, enc_rb1, C, C, 32, 64, 64, 128, 64, 64);
    conv_direct<3,1,1,8,32,2,true ,false,false><<<dim3(8,4,N),  TPB, 8*32*9*4, stream>>>(
        C, enc_rw3 + 32*128*9, enc_rb3 + 32, nullptr, Dt, 128, 64, 64, 32, 64, 64);
    conv_direct<1,1,0,8,32,4,true ,false,true ><<<dim3(4,16,N), TPB, 8*32*1*4, stream>>>(
        Dt, enc_rw1 + 128*32, enc_rb1 + 128, C, C, 32, 64, 64, 128, 64, 64);
    // pre-VQ 1x1 (fuses the stack's final relu)
    conv_direct<1,1,0,8,32,4,true ,false,false><<<dim3(4,8,N),  TPB, 8*32*1*4, stream>>>(
        C, pre_w, pre_b, nullptr, B, 128, 64, 64, 64, 64, 64);

    // VQ
    vq_init<<<dim3(1), dim3(256), 0, stream>>>(HIST);
    vq_kernel<<<dim3(256), dim3(256), 0, stream>>>(B, cb, Q, SSE, HIST, 64 * 64);
    vq_finalize<<<dim3(1), dim3(256), 0, stream>>>(SSE, HIST, loss_p, perp_p);

    // decoder
    conv_direct<3,1,1,8,32,4,false,false,false><<<dim3(4,16,N), TPB, 8*32*9*4, stream>>>(
        Q, dec_w1, dec_b1, nullptr, C, 64, 64, 64, 128, 64, 64);
    conv_direct<3,1,1,8,32,2,true ,false,false><<<dim3(8,4,N),  TPB, 8*32*9*4, stream>>>(
        C, dec_rw3, dec_rb3, nullptr, Dt, 128, 64, 64, 32, 64, 64);
    conv_direct<1,1,0,8,32,4,true ,false,true ><<<dim3(4,16,N), TPB, 8*32*1*4, stream>>>(
        Dt, dec_rw1, dec_rb1, C, C, 32, 64, 64, 128, 64, 64);
    conv_direct<3,1,1,8,32,2,true ,false,false><<<dim3(8,4,N),  TPB, 8*32*9*4, stream>>>(
        C, dec_rw3 + 32*128*9, dec_rb3 + 32, nullptr, Dt, 128, 64, 64, 32, 64, 64);
    conv_direct<1,1,0,8,32,4,true ,false,true ><<<dim3(4,16,N), TPB, 8*32*1*4, stream>>>(
        Dt, dec_rw1 + 128*32, dec_rb1 + 128, C, C, 32, 64, 64, 128, 64, 64);
    // transpose convs (first one fuses the dec stack's final relu on input)
    convt4s2<8,32,true ,true ><<<dim3(16,8,N), TPB, 8*32*16*4, stream>>>(
        C, dw1, db1, A, 128, 64, 64, 64, 128, 128, 1);
    convt4s2<3,32,false,false><<<dim3(64,1,N), TPB, 3*32*16*4, stream>>>(
        A, dw2, db2, recon, 64, 128, 128, 3, 256, 256, 2);
}

// Round 4
// 2986.400 us; speedup vs baseline: 2.3138x; 1.5299x over previous
//
#include <hip/hip_runtime.h>

// ================= tiled direct conv (correlation, NCHW, OIHW) =================
// Block: COB output channels x (TY x TX) output tile for one n. Full-width tiles
// (TX == Wout). Input tile (with halo) staged per channel into LDS with zero-fill
// (bounds checks + input relu at stage time). PF: software pipeline -- next
// channel's tile prefetched to regs during compute, LDS double-buffered, one
// __syncthreads per channel.
template<int K,int S,int P,int COB,int TY,int TX,bool PF,bool RIN,bool ROUT,bool RES>
__global__ __launch_bounds__(256) void conv_tiled(
    const float* __restrict__ in, const float* __restrict__ w,
    const float* __restrict__ bias, const float* __restrict__ res,
    float* __restrict__ out,
    int Cin, int Hin, int Win, int Cout, int Hout, int Wout)
{
    constexpr int IH  = (TY-1)*S + K;
    constexpr int IW  = (TX-1)*S + K;
    constexpr int ISZ = IH*IW;            // all instantiations: ISZ % 4 == 0
    constexpr int KK  = K*K;
    constexpr int WSZ = KK*COB;           // <= 128
    constexpr int RPB = 256/TX;           // row-groups covered per j-step
    constexpr int JN  = TY/RPB;           // pixels per thread
    constexpr int REGN = (ISZ + 255)/256;

    extern __shared__ float4 lds4[];
    float* lds  = (float*)lds4;
    float* tin0 = lds;
    float* wl0  = lds + ISZ;
    float* tin1 = PF ? lds + (ISZ+WSZ) : tin0;
    float* wl1  = PF ? tin1 + ISZ : wl0;

    const int tid = threadIdx.x;
    const int y0  = blockIdx.x * TY;
    const int co0 = blockIdx.y * COB;
    const int n   = blockIdx.z;
    const int col = tid % TX;
    const int rg  = tid / TX;
    const size_t hwin = (size_t)Hin*Win;
    const float* pin = in + (size_t)n*Cin*hwin;
    const int iyb = y0*S - P;

    float acc[COB][JN];
#pragma unroll
    for (int c = 0; c < COB; c++)
#pragma unroll
        for (int j = 0; j < JN; j++) acc[c][j] = 0.f;

    auto stage_direct = [&](int ci, float* ti, float* wb){
        const float* pc = pin + (size_t)ci*hwin;
        for (int i = tid; i < ISZ; i += 256) {
            int r = i / IW, cc = i - r*IW;
            int iy = iyb + r, ix = cc - P;
            float v = 0.f;
            if ((unsigned)iy < (unsigned)Hin && (unsigned)ix < (unsigned)Win)
                v = pc[(size_t)iy*Win + ix];
            if (RIN) v = fmaxf(v, 0.f);
            ti[i] = v;
        }
        if (tid < WSZ) {
            int c = tid % COB, t = tid / COB;
            wb[tid] = w[((size_t)(co0+c)*Cin + ci)*KK + t];
        }
    };

    float rv[REGN]; float wrv = 0.f;
    auto load_regs = [&](int ci){
        const float* pc = pin + (size_t)ci*hwin;
#pragma unroll
        for (int rr = 0; rr < REGN; rr++) {
            int i = tid + rr*256;
            float v = 0.f;
            if (i < ISZ) {
                int r = i / IW, cc = i - r*IW;
                int iy = iyb + r, ix = cc - P;
                if ((unsigned)iy < (unsigned)Hin && (unsigned)ix < (unsigned)Win)
                    v = pc[(size_t)iy*Win + ix];
            }
            rv[rr] = RIN ? fmaxf(v, 0.f) : v;
        }
        if (tid < WSZ) {
            int c = tid % COB, t = tid / COB;
            wrv = w[((size_t)(co0+c)*Cin + ci)*KK + t];
        }
    };
    auto write_regs = [&](float* ti, float* wb){
#pragma unroll
        for (int rr = 0; rr < REGN; rr++) {
            int i = tid + rr*256;
            if (i < ISZ) ti[i] = rv[rr];
        }
        if (tid < WSZ) wb[tid] = wrv;
    };

    const int tbase = (rg*S)*IW + col*S;
    auto compute = [&](const float* ti, const float* wb){
#pragma unroll
        for (int ky = 0; ky < K; ky++)
#pragma unroll
        for (int kx = 0; kx < K; kx++) {
            const int t = ky*K + kx;
            float wv[COB];
            if constexpr (COB % 4 == 0) {
#pragma unroll
                for (int c = 0; c < COB; c += 4) {
                    float4 f = *(const float4*)(wb + t*COB + c);
                    wv[c] = f.x; wv[c+1] = f.y; wv[c+2] = f.z; wv[c+3] = f.w;
                }
            } else {
#pragma unroll
                for (int c = 0; c < COB; c++) wv[c] = wb[t*COB + c];
            }
#pragma unroll
            for (int j = 0; j < JN; j++) {
                float v = ti[tbase + (j*RPB*S + ky)*IW + kx];
#pragma unroll
                for (int c = 0; c < COB; c++)
                    acc[c][j] = fmaf(wv[c], v, acc[c][j]);
            }
        }
    };

    if constexpr (PF) {
        stage_direct(0, tin0, wl0);
        __syncthreads();
        int cur = 0;
        for (int ci = 0; ci < Cin; ci++) {
            if (ci+1 < Cin) load_regs(ci+1);
            compute(cur ? tin1 : tin0, cur ? wl1 : wl0);
            if (ci+1 < Cin) write_regs(cur ? tin0 : tin1, cur ? wl0 : wl1);
            __syncthreads();
            cur ^= 1;
        }
    } else {
        for (int ci = 0; ci < Cin; ci++) {
            if (ci) __syncthreads();
            stage_direct(ci, tin0, wl0);
            __syncthreads();
            compute(tin0, wl0);
        }
    }

#pragma unroll
    for (int c = 0; c < COB; c++) {
        const float bv = bias[co0 + c];
        float* po = out + ((size_t)n*Cout + co0 + c)*((size_t)Hout*Wout);
        const float* pr = res + ((size_t)n*Cout + co0 + c)*((size_t)Hout*Wout);
#pragma unroll
        for (int j = 0; j < JN; j++) {
            int oy = y0 + rg + RPB*j;
            int p = oy*Wout + col;
            float v = acc[c][j] + bv;
            if (RES) v += pr[p];
            if (ROUT) v = fmaxf(v, 0.f);
            po[p] = v;
        }
    }
}

// ================= tiled transpose conv k=4 s=2 p=1 (gather form) =================
// out(oy,ox): taps ky=ky0+2ty, kx=kx0+2tx (ky0=oy&1, kx0=ox&1), iy=((oy+ky0-2)>>1)+ty.
// Tile: TY out rows (y0 even) -> input rows [y0/2-1, y0/2+TY/2], IH=TY/2+2.
// Thread covers rows per parity: oy = y0 + par + 2*(r + RG*j); iyl = par + r + RG*j + ty.
template<int TY,int TX,int COB,bool RIN,bool ROUT>
__global__ __launch_bounds__(256) void convt_tiled(
    const float* __restrict__ in, const float* __restrict__ w,
    const float* __restrict__ bias, float* __restrict__ out,
    int Cin, int Hin, int Win, int Cout, int Hout, int Wout)
{
    constexpr int IH  = TY/2 + 2;
    constexpr int IW  = TX/2 + 2;
    constexpr int ISZ = IH*IW;            // % 4 == 0 for our shapes
    constexpr int WSZ = 16*COB;
    constexpr int RG  = 256/TX;
    constexpr int JR  = (TY/2)/RG;
    constexpr int REGN = (ISZ + 255)/256;

    extern __shared__ float4 lds4[];
    float* lds  = (float*)lds4;
    float* tin0 = lds;
    float* wl0  = lds + ISZ;
    float* tin1 = lds + (ISZ+WSZ);
    float* wl1  = tin1 + ISZ;

    const int tid = threadIdx.x;
    const int y0  = blockIdx.x * TY;
    const int co0 = blockIdx.y * COB;
    const int n   = blockIdx.z;
    const int col = tid % TX;
    const int r   = tid / TX;
    const int kx0 = col & 1;
    const int ixl = (col + kx0) >> 1;
    const int iyb = y0/2 - 1;
    const size_t hwin = (size_t)Hin*Win;
    const float* pin = in + (size_t)n*Cin*hwin;

    float acc[COB][2*JR];
#pragma unroll
    for (int c = 0; c < COB; c++)
#pragma unroll
        for (int j = 0; j < 2*JR; j++) acc[c][j] = 0.f;

    auto stage_direct = [&](int ci, float* ti, float* wb){
        const float* pc = pin + (size_t)ci*hwin;
        for (int i = tid; i < ISZ; i += 256) {
            int rr = i / IW, cc = i - rr*IW;
            int iy = iyb + rr, ix = cc - 1;
            float v = 0.f;
            if ((unsigned)iy < (unsigned)Hin && (unsigned)ix < (unsigned)Win)
                v = pc[(size_t)iy*Win + ix];
            if (RIN) v = fmaxf(v, 0.f);
            ti[i] = v;
        }
        if (tid < WSZ) {
            int c = tid % COB, t = tid / COB;
            wb[tid] = w[((size_t)(co0+c)*Cin + ci)*16 + t];
        }
    };

    float rv[REGN]; float wrv = 0.f;
    auto load_regs = [&](int ci){
        const float* pc = pin + (size_t)ci*hwin;
#pragma unroll
        for (int rr = 0; rr < REGN; rr++) {
            int i = tid + rr*256;
            float v = 0.f;
            if (i < ISZ) {
                int rw = i / IW, cc = i - rw*IW;
                int iy = iyb + rw, ix = cc - 1;
                if ((unsigned)iy < (unsigned)Hin && (unsigned)ix < (unsigned)Win)
                    v = pc[(size_t)iy*Win + ix];
            }
            rv[rr] = RIN ? fmaxf(v, 0.f) : v;
        }
        if (tid < WSZ) {
            int c = tid % COB, t = tid / COB;
            wrv = w[((size_t)(co0+c)*Cin + ci)*16 + t];
        }
    };
    auto write_regs = [&](float* ti, float* wb){
#pragma unroll
        for (int rr = 0; rr < REGN; rr++) {
            int i = tid + rr*256;
            if (i < ISZ) ti[i] = rv[rr];
        }
        if (tid < WSZ) wb[tid] = wrv;
    };

    auto compute = [&](const float* ti, const float* wb){
#pragma unroll
        for (int par = 0; par < 2; par++)
#pragma unroll
        for (int ty = 0; ty < 2; ty++)
#pragma unroll
        for (int tx = 0; tx < 2; tx++) {
            const int widx = (par + 2*ty)*4 + (kx0 + 2*tx);
            float wv[COB];
            if constexpr (COB % 4 == 0) {
#pragma unroll
                for (int c = 0; c < COB; c += 4) {
                    float4 f = *(const float4*)(wb + widx*COB + c);
                    wv[c] = f.x; wv[c+1] = f.y; wv[c+2] = f.z; wv[c+3] = f.w;
                }
            } else {
#pragma unroll
                for (int c = 0; c < COB; c++) wv[c] = wb[widx*COB + c];
            }
#pragma unroll
            for (int j = 0; j < JR; j++) {
                float v = ti[(par + r + RG*j + ty)*IW + ixl + tx];
#pragma unroll
                for (int c = 0; c < COB; c++)
                    acc[c][par*JR + j] = fmaf(wv[c], v, acc[c][par*JR + j]);
            }
        }
    };

    stage_direct(0, tin0, wl0);
    __syncthreads();
    int cur = 0;
    for (int ci = 0; ci < Cin; ci++) {
        if (ci+1 < Cin) load_regs(ci+1);
        compute(cur ? tin1 : tin0, cur ? wl1 : wl0);
        if (ci+1 < Cin) write_regs(cur ? tin0 : tin1, cur ? wl0 : wl1);
        __syncthreads();
        cur ^= 1;
    }

#pragma unroll
    for (int c = 0; c < COB; c++) {
        const float bv = bias[co0 + c];
        float* po = out + ((size_t)n*Cout + co0 + c)*((size_t)Hout*Wout);
#pragma unroll
        for (int par = 0; par < 2; par++)
#pragma unroll
        for (int j = 0; j < JR; j++) {
            int oy = y0 + par + 2*(r + RG*j);
            float v = acc[c][par*JR + j] + bv;
            if (ROUT) v = fmaxf(v, 0.f);
            po[oy*Wout + col] = v;
        }
    }
}

// ================= VQ =================
// grid 1024 x 256: each block owns 64 tokens; 4 waves each scan a 128-code chunk
// (ascending), LDS combine preserves first-min tie rule. Fused q gather + SSE + hist.
__global__ __launch_bounds__(256) void vq_search(
    const float* __restrict__ z, const float* __restrict__ cb,
    float* __restrict__ q, float* __restrict__ ssep, int* __restrict__ hist, int HW)
{
    __shared__ float bdl[4][64];
    __shared__ int   bil[4][64];
    const int tid = threadIdx.x;
    const int lane = tid & 63, wvi = tid >> 6;
    const int t = blockIdx.x * 64 + lane;
    const int n = t / HW, pix = t - n*HW;
    const float* zp = z + (size_t)n*64*HW + pix;
    float x[64];
#pragma unroll
    for (int d = 0; d < 64; d++) x[d] = zp[(size_t)d*HW];

    float bd = 3.4e38f; int bi = 0;
    const int k0 = wvi*128;
    for (int k = k0; k < k0+128; k += 2) {
#pragma unroll
        for (int kk = 0; kk < 2; kk++) {
            const float4* c4 = (const float4*)(cb + (size_t)(k+kk)*64);
            float s[4] = {0.f, 0.f, 0.f, 0.f};
#pragma unroll
            for (int d4 = 0; d4 < 16; d4++) {
                float4 c = c4[d4];
                float a0 = x[4*d4+0] - c.x;
                float a1 = x[4*d4+1] - c.y;
                float a2 = x[4*d4+2] - c.z;
                float a3 = x[4*d4+3] - c.w;
                s[d4&3] += fmaf(a0,a0, a1*a1) + fmaf(a2,a2, a3*a3);
            }
            float dist = (s[0]+s[1]) + (s[2]+s[3]);
            if (dist < bd) { bd = dist; bi = k+kk; }
        }
    }
    bdl[wvi][lane] = bd; bil[wvi][lane] = bi;
    __syncthreads();
    if (wvi == 0) {
#pragma unroll
        for (int w2 = 1; w2 < 4; w2++) {
            float d2 = bdl[w2][lane];
            int   i2 = bil[w2][lane];
            if (d2 < bd) { bd = d2; bi = i2; }   // strict <, ascending chunk => global first-min
        }
        bdl[0][lane] = bd; bil[0][lane] = bi;
    }
    __syncthreads();
    bi = bil[0][lane];
    const float* cr = cb + (size_t)bi*64;
    float* qp = q + (size_t)n*64*HW + pix;
#pragma unroll
    for (int dd = 0; dd < 16; dd++)
        qp[(size_t)(wvi*16+dd)*HW] = cr[wvi*16+dd];
    if (wvi == 0) {
        float s = bd;                         // best dist == token SSE
#pragma unroll
        for (int o = 32; o > 0; o >>= 1) s += __shfl_down(s, o, 64);
        if (lane == 0) ssep[blockIdx.x] = s;
        atomicAdd(&hist[bi], 1);
    }
}

__global__ void vq_init(int* hist)
{
    for (int i = threadIdx.x; i < 512; i += 256) hist[i] = 0;
}

__global__ __launch_bounds__(256) void vq_finalize(
    const float* __restrict__ ssep, const int* __restrict__ hist,
    float* __restrict__ o_loss, float* __restrict__ o_perp)
{
    __shared__ float red[256];
    const int tid = threadIdx.x;
    float h = 0.f;
    for (int i = tid; i < 512; i += 256) {
        float p = (float)hist[i] * (1.0f / 65536.0f);
        h -= p * logf(p + 1e-10f);
    }
    red[tid] = h;
    __syncthreads();
    for (int st = 128; st > 0; st >>= 1) {
        if (tid < st) red[tid] += red[tid + st];
        __syncthreads();
    }
    const float H = red[0];
    __syncthreads();
    float s = 0.f;
    for (int i = tid; i < 1024; i += 256) s += ssep[i];
    red[tid] = s;
    __syncthreads();
    for (int st = 128; st > 0; st >>= 1) {
        if (tid < st) red[tid] += red[tid + st];
        __syncthreads();
    }
    if (tid == 0) {
        *o_loss = 1.25f * red[0] / 4194304.0f;   // (1+beta)*mean((q-x)^2), 16*64*64*64 elems
        *o_perp = expf(H);
    }
}

extern "C" void kernel_launch(void* const* d_in, const int* in_sizes, int n_in,
                              void* d_out, int out_size, void* d_ws, size_t ws_size,
                              hipStream_t stream)
{
    const float* x       = (const float*)d_in[0];
    const float* enc_w1  = (const float*)d_in[1];
    const float* enc_b1  = (const float*)d_in[2];
    const float* enc_w2  = (const float*)d_in[3];
    const float* enc_b2  = (const float*)d_in[4];
    const float* enc_w3  = (const float*)d_in[5];
    const float* enc_b3  = (const float*)d_in[6];
    const float* enc_rw3 = (const float*)d_in[7];
    const float* enc_rb3 = (const float*)d_in[8];
    const float* enc_rw1 = (const float*)d_in[9];
    const float* enc_rb1 = (const float*)d_in[10];
    const float* pre_w   = (const float*)d_in[11];
    const float* pre_b   = (const float*)d_in[12];
    const float* cb      = (const float*)d_in[13];
    const float* dec_w1  = (const float*)d_in[14];
    const float* dec_b1  = (const float*)d_in[15];
    const float* dec_rw3 = (const float*)d_in[16];
    const float* dec_rb3 = (const float*)d_in[17];
    const float* dec_rw1 = (const float*)d_in[18];
    const float* dec_rb1 = (const float*)d_in[19];
    const float* dw1     = (const float*)d_in[20];
    const float* db1     = (const float*)d_in[21];
    const float* dw2     = (const float*)d_in[22];
    const float* db2     = (const float*)d_in[23];

    float* o      = (float*)d_out;
    float* loss_p = o;
    float* recon  = o + 1;
    float* perp_p = o + 1 + 16 * 3 * 256 * 256;

    // ws layout (floats): A 16.78M | B 8.39M | C 8.39M | Dt 2.10M | SSE 1024 | HIST 512
    float* ws  = (float*)d_ws;
    float* A   = ws;
    float* B   = A + 16777216;
    float* C   = B + 8388608;
    float* Dt  = C + 8388608;
    float* SSE = Dt + 2097152;
    int*   HIST = (int*)(SSE + 1024);
    float* Q   = A;

    const int N = 16;

    // encoder
    conv_tiled<4,2,1,8, 8,128,false,false,true ,false><<<dim3(16, 8,N),256,(18*258+128)*4,stream>>>(
        x, enc_w1, enc_b1, nullptr, A, 3, 256, 256, 64, 128, 128);
    conv_tiled<4,2,1,8,16, 64,false,false,true ,false><<<dim3( 4,16,N),256,(34*130+128)*4,stream>>>(
        A, enc_w2, enc_b2, nullptr, B, 64, 128, 128, 128, 64, 64);
    conv_tiled<3,1,1,8,16, 64,true ,false,false,false><<<dim3( 4,16,N),256,2*(18*66+72)*4,stream>>>(
        B, enc_w3, enc_b3, nullptr, C, 128, 64, 64, 128, 64, 64);
    // enc residual stack
    conv_tiled<3,1,1,8, 8, 64,true ,true ,false,false><<<dim3( 8, 4,N),256,2*(10*66+72)*4,stream>>>(
        C, enc_rw3, enc_rb3, nullptr, Dt, 128, 64, 64, 32, 64, 64);
    conv_tiled<1,1,0,8,16, 64,true ,true ,false,true ><<<dim3( 4,16,N),256,2*(16*64+ 8)*4,stream>>>(
        Dt, enc_rw1, enc_rb1, C, C, 32, 64, 64, 128, 64, 64);
    conv_tiled<3,1,1,8, 8, 64,true ,true ,false,false><<<dim3( 8, 4,N),256,2*(10*66+72)*4,stream>>>(
        C, enc_rw3 + 32*128*9, enc_rb3 + 32, nullptr, Dt, 128, 64, 64, 32, 64, 64);
    conv_tiled<1,1,0,8,16, 64,true ,true ,false,true ><<<dim3( 4,16,N),256,2*(16*64+ 8)*4,stream>>>(
        Dt, enc_rw1 + 128*32, enc_rb1 + 128, C, C, 32, 64, 64, 128, 64, 64);
    // pre-VQ 1x1 (fuses the stack's final relu)
    conv_tiled<1,1,0,8,16, 64,true ,true ,false,false><<<dim3( 4, 8,N),256,2*(16*64+ 8)*4,stream>>>(
        C, pre_w, pre_b, nullptr, B, 128, 64, 64, 64, 64, 64);

    // VQ
    vq_init<<<dim3(1), dim3(256), 0, stream>>>(HIST);
    vq_search<<<dim3(1024), dim3(256), 0, stream>>>(B, cb, Q, SSE, HIST, 64 * 64);
    vq_finalize<<<dim3(1), dim3(256), 0, stream>>>(SSE, HIST, loss_p, perp_p);

    // decoder
    conv_tiled<3,1,1,8,16, 64,true ,false,false,false><<<dim3( 4,16,N),256,2*(18*66+72)*4,stream>>>(
        Q, dec_w1, dec_b1, nullptr, C, 64, 64, 64, 128, 64, 64);
    conv_tiled<3,1,1,8, 8, 64,true ,true ,false,false><<<dim3( 8, 4,N),256,2*(10*66+72)*4,stream>>>(
        C, dec_rw3, dec_rb3, nullptr, Dt, 128, 64, 64, 32, 64, 64);
    conv_tiled<1,1,0,8,16, 64,true ,true ,false,true ><<<dim3( 4,16,N),256,2*(16*64+ 8)*4,stream>>>(
        Dt, dec_rw1, dec_rb1, C, C, 32, 64, 64, 128, 64, 64);
    conv_tiled<3,1,1,8, 8, 64,true ,true ,false,false><<<dim3( 8, 4,N),256,2*(10*66+72)*4,stream>>>(
        C, dec_rw3 + 32*128*9, dec_rb3 + 32, nullptr, Dt, 128, 64, 64, 32, 64, 64);
    conv_tiled<1,1,0,8,16, 64,true ,true ,false,true ><<<dim3( 4,16,N),256,2*(16*64+ 8)*4,stream>>>(
        Dt, dec_rw1 + 128*32, dec_rb1 + 128, C, C, 32, 64, 64, 128, 64, 64);
    // transpose convs (first fuses the dec stack's final relu on its input)
    convt_tiled<8,128,8,true ,true ><<<dim3(16, 8,N),256,2*(6* 66+128)*4,stream>>>(
        C, dw1, db1, A, 128, 64, 64, 64, 128, 128);
    convt_tiled<8,256,3,false,false><<<dim3(32, 1,N),256,2*(6*130+ 48)*4,stream>>>(
        A, dw2, db2, recon, 64, 128, 128, 3, 256, 256);
}

// Round 5
// 1757.623 us; speedup vs baseline: 3.9315x; 1.6991x over previous
//
#include <hip/hip_runtime.h>

typedef __attribute__((ext_vector_type(8)))  short bf16x8;
typedef __attribute__((ext_vector_type(16))) float f32x16;

// split fp32 -> (hi, lo) bf16 pair, RNE both
__device__ inline void fsplit(float v, unsigned short& h, unsigned short& l)
{
    union { float f; unsigned u; } a; a.f = v;
    unsigned uh = a.u + 0x7fffu + ((a.u >> 16) & 1u);
    h = (unsigned short)(uh >> 16);
    union { float f; unsigned u; } hb; hb.u = (unsigned)h << 16;
    float r = v - hb.f;
    union { float f; unsigned u; } b; b.f = r;
    unsigned ul = b.u + 0x7fffu + ((b.u >> 16) & 1u);
    l = (unsigned short)(ul >> 16);
}

// pack OIHW fp32 weights -> [tap][co_pad][ci_pad] bf16 hi/lo, zero-padded
__global__ void pack_w(const float* __restrict__ w, unsigned short* __restrict__ hi,
                       unsigned short* __restrict__ lo, int Cout, int Cin, int KK,
                       int CoP, int CiP)
{
    int i = blockIdx.x * 256 + threadIdx.x;
    int tot = KK * CoP * CiP;
    if (i >= tot) return;
    int t  = i / (CoP * CiP);
    int r  = i - t * (CoP * CiP);
    int co = r / CiP;
    int ci = r - co * CiP;
    float v = (co < Cout && ci < Cin) ? w[((size_t)co * Cin + ci) * KK + t] : 0.f;
    unsigned short h, l;
    fsplit(v, h, l);
    hi[i] = h; lo[i] = l;
}

// ============ MFMA direct conv (correlation, NCHW, packed weights) ============
// Block: 32*WM couts x (TR x TC) output tile, 4 waves (WM*WN=4), wave-tile 32co x 32px.
// Per 16-ci chunk: stage input tile (zero-fill + optional input relu) as bf16 hi/lo
// pairs in LDS ([pos][16ci], pitch 12 words -> B-frag = one aligned ds_read_b128),
// then per tap: A hi/lo from global packed weights, 3 MFMAs (hh, hl, lh).
template<int K,int S,int P,int CIN,int COUT,int HIN,int WIN,int HOUT,int WOUT,
         int TR,int TC,int WM,int WN,int CO_PAD,int CI_PAD,bool RIN,bool ROUT,bool RES>
__global__ __launch_bounds__(256) void conv_mfma(
    const float* __restrict__ in, const unsigned short* __restrict__ wpH,
    const unsigned short* __restrict__ wpL, const float* __restrict__ bias,
    const float* __restrict__ res, float* __restrict__ out)
{
    constexpr int IHT = (TR - 1) * S + K;
    constexpr int IW  = (TC - 1) * S + K;
    constexpr int PS  = IHT * IW;
    constexpr int KK  = K * K;
    constexpr int NCH = CI_PAD / 16;
    constexpr int XB  = WOUT / TC;

    __shared__ unsigned lbufH[PS * 12];
    __shared__ unsigned lbufL[PS * 12];

    const int tid = threadIdx.x;
    const int bx  = blockIdx.x;
    const int r0  = (bx / XB) * TR;
    const int c0  = (bx % XB) * TC;
    const int co0 = blockIdx.y * (32 * WM);
    const int n   = blockIdx.z;

    const int l  = tid & 63;
    const int wv = tid >> 6;
    const int wm = wv / WN;
    const int wn = wv % WN;
    const int ln = l & 31;
    const int kg = l >> 5;

    const int q  = wn * 32 + ln;
    const int lr = q / TC;
    const int lc = q % TC;
    const int coA = co0 + wm * 32 + ln;

    f32x16 acc0 = {};
    f32x16 acc1 = {};

    const float* pin = in + (size_t)n * CIN * HIN * WIN;
    const int pb = (lr * S) * IW + lc * S;

    for (int kc = 0; kc < NCH; kc++) {
        __syncthreads();
        for (int idx = tid; idx < PS * 8; idx += 256) {
            int c2  = idx / PS;
            int pos = idx - c2 * PS;
            int gy  = r0 * S - P + pos / IW;
            int gx  = c0 * S - P + pos % IW;
            int ci0 = kc * 16 + 2 * c2;
            float v0 = 0.f, v1 = 0.f;
            if ((unsigned)gy < (unsigned)HIN && (unsigned)gx < (unsigned)WIN) {
                const float* pp = pin + (size_t)gy * WIN + gx;
                if (ci0     < CIN) v0 = pp[(size_t)ci0 * HIN * WIN];
                if (ci0 + 1 < CIN) v1 = pp[(size_t)(ci0 + 1) * HIN * WIN];
            }
            if (RIN) { v0 = fmaxf(v0, 0.f); v1 = fmaxf(v1, 0.f); }
            unsigned short h0, l0, h1, l1;
            fsplit(v0, h0, l0); fsplit(v1, h1, l1);
            lbufH[pos * 12 + c2] = (unsigned)h0 | ((unsigned)h1 << 16);
            lbufL[pos * 12 + c2] = (unsigned)l0 | ((unsigned)l1 << 16);
        }
        __syncthreads();
#pragma unroll
        for (int t = 0; t < KK; t++) {
            const int ky = t / K, kx = t % K;
            const size_t wo = ((size_t)t * CO_PAD + coA) * CI_PAD + kc * 16 + kg * 8;
            bf16x8 aH = *(const bf16x8*)(wpH + wo);
            bf16x8 aL = *(const bf16x8*)(wpL + wo);
            const int word = (pb + ky * IW + kx) * 12 + kg * 4;
            bf16x8 bH = *(const bf16x8*)(&lbufH[word]);
            bf16x8 bL = *(const bf16x8*)(&lbufL[word]);
            acc0 = __builtin_amdgcn_mfma_f32_32x32x16_bf16(aH, bH, acc0, 0, 0, 0);
            acc1 = __builtin_amdgcn_mfma_f32_32x32x16_bf16(aH, bL, acc1, 0, 0, 0);
            acc1 = __builtin_amdgcn_mfma_f32_32x32x16_bf16(aL, bH, acc1, 0, 0, 0);
        }
    }

    const size_t obase = (size_t)n * COUT * HOUT * WOUT;
    const int gy = r0 + lr, gx = c0 + lc;
#pragma unroll
    for (int r = 0; r < 16; r++) {
        int m  = (r & 3) + 8 * (r >> 2) + 4 * kg;
        int co = co0 + wm * 32 + m;
        if (co < COUT) {
            size_t ad = obase + ((size_t)co * HOUT + gy) * WOUT + gx;
            float v = acc0[r] + acc1[r] + bias[co];
            if (RES) v += res[ad];
            if (ROUT) v = fmaxf(v, 0.f);
            out[ad] = v;
        }
    }
}

// ============ MFMA transpose conv k=4 s=2 p=1 (gather/parity form) ============
// Block: one output row oy x one x-parity, 32*WM couts, 4 waves. Lane pixel i ->
// ox = 2i+par. Taps: (ky0+2ty, par+2tx), input rows iyb+ty, cols i+par-1+tx.
template<int CIN,int COUT,int HIN,int WIN,int WM,int WN,int CO_PAD,bool RIN,bool ROUT>
__global__ __launch_bounds__(256) void convt_mfma(
    const float* __restrict__ in, const unsigned short* __restrict__ wpH,
    const unsigned short* __restrict__ wpL, const float* __restrict__ bias,
    float* __restrict__ out)
{
    constexpr int WS  = 32 * WN + 2;
    constexpr int PS  = 2 * WS;
    constexpr int NCH = CIN / 16;
    constexpr int HOUT = 2 * HIN, WOUT = 2 * WIN;
    constexpr int CI_PAD = CIN;

    __shared__ unsigned lbufH[PS * 12];
    __shared__ unsigned lbufL[PS * 12];

    const int tid = threadIdx.x;
    const int oy  = blockIdx.x >> 1;
    const int par = blockIdx.x & 1;
    const int co0 = blockIdx.y * (32 * WM);
    const int n   = blockIdx.z;

    const int ky0 = oy & 1;
    const int iyb = ((oy + ky0) >> 1) - 1;
    const int cb  = par - 1;

    const int l  = tid & 63, wv = tid >> 6;
    const int wm = wv / WN, wn = wv % WN;
    const int ln = l & 31, kg = l >> 5;
    const int q  = wn * 32 + ln;
    const int coA = co0 + wm * 32 + ln;

    f32x16 acc0 = {};
    f32x16 acc1 = {};
    const float* pin = in + (size_t)n * CIN * HIN * WIN;

    for (int kc = 0; kc < NCH; kc++) {
        __syncthreads();
        for (int idx = tid; idx < PS * 8; idx += 256) {
            int c2  = idx / PS;
            int pos = idx - c2 * PS;
            int rr = pos / WS, cc = pos - rr * WS;
            int gy = iyb + rr, gx = cb + cc;
            int ci0 = kc * 16 + 2 * c2;
            float v0 = 0.f, v1 = 0.f;
            if ((unsigned)gy < (unsigned)HIN && (unsigned)gx < (unsigned)WIN) {
                const float* pp = pin + (size_t)gy * WIN + gx;
                v0 = pp[(size_t)ci0 * HIN * WIN];
                v1 = pp[(size_t)(ci0 + 1) * HIN * WIN];
            }
            if (RIN) { v0 = fmaxf(v0, 0.f); v1 = fmaxf(v1, 0.f); }
            unsigned short h0, l0, h1, l1;
            fsplit(v0, h0, l0); fsplit(v1, h1, l1);
            lbufH[pos * 12 + c2] = (unsigned)h0 | ((unsigned)h1 << 16);
            lbufL[pos * 12 + c2] = (unsigned)l0 | ((unsigned)l1 << 16);
        }
        __syncthreads();
#pragma unroll
        for (int ty = 0; ty < 2; ty++)
#pragma unroll
        for (int tx = 0; tx < 2; tx++) {
            const int widx = (ky0 + 2 * ty) * 4 + (par + 2 * tx);
            const size_t wo = ((size_t)widx * CO_PAD + coA) * CI_PAD + kc * 16 + kg * 8;
            bf16x8 aH = *(const bf16x8*)(wpH + wo);
            bf16x8 aL = *(const bf16x8*)(wpL + wo);
            const int word = (ty * WS + q + tx) * 12 + kg * 4;
            bf16x8 bH = *(const bf16x8*)(&lbufH[word]);
            bf16x8 bL = *(const bf16x8*)(&lbufL[word]);
            acc0 = __builtin_amdgcn_mfma_f32_32x32x16_bf16(aH, bH, acc0, 0, 0, 0);
            acc1 = __builtin_amdgcn_mfma_f32_32x32x16_bf16(aH, bL, acc1, 0, 0, 0);
            acc1 = __builtin_amdgcn_mfma_f32_32x32x16_bf16(aL, bH, acc1, 0, 0, 0);
        }
    }

    const int ox = 2 * q + par;
#pragma unroll
    for (int r = 0; r < 16; r++) {
        int m  = (r & 3) + 8 * (r >> 2) + 4 * kg;
        int co = co0 + wm * 32 + m;
        if (co < COUT) {
            size_t ad = (((size_t)n * COUT + co) * HOUT + oy) * WOUT + ox;
            float v = acc0[r] + acc1[r] + bias[co];
            if (ROUT) v = fmaxf(v, 0.f);
            out[ad] = v;
        }
    }
}

// ================= VQ (fp32, exact semantics) =================
__global__ __launch_bounds__(256) void vq_search(
    const float* __restrict__ z, const float* __restrict__ cb,
    float* __restrict__ q, float* __restrict__ ssep, int* __restrict__ hist, int HW)
{
    __shared__ float bdl[4][64];
    __shared__ int   bil[4][64];
    const int tid = threadIdx.x;
    const int lane = tid & 63, wvi = tid >> 6;
    const int t = blockIdx.x * 64 + lane;
    const int n = t / HW, pix = t - n * HW;
    const float* zp = z + (size_t)n * 64 * HW + pix;
    float x[64];
#pragma unroll
    for (int d = 0; d < 64; d++) x[d] = zp[(size_t)d * HW];

    float bd = 3.4e38f; int bi = 0;
    const int k0 = wvi * 128;
    for (int k = k0; k < k0 + 128; k += 2) {
#pragma unroll
        for (int kk = 0; kk < 2; kk++) {
            const float4* c4 = (const float4*)(cb + (size_t)(k + kk) * 64);
            float s[4] = {0.f, 0.f, 0.f, 0.f};
#pragma unroll
            for (int d4 = 0; d4 < 16; d4++) {
                float4 c = c4[d4];
                float a0 = x[4*d4+0] - c.x;
                float a1 = x[4*d4+1] - c.y;
                float a2 = x[4*d4+2] - c.z;
                float a3 = x[4*d4+3] - c.w;
                s[d4&3] += fmaf(a0,a0, a1*a1) + fmaf(a2,a2, a3*a3);
            }
            float dist = (s[0]+s[1]) + (s[2]+s[3]);
            if (dist < bd) { bd = dist; bi = k + kk; }
        }
    }
    bdl[wvi][lane] = bd; bil[wvi][lane] = bi;
    __syncthreads();
    if (wvi == 0) {
#pragma unroll
        for (int w2 = 1; w2 < 4; w2++) {
            float d2 = bdl[w2][lane];
            int   i2 = bil[w2][lane];
            if (d2 < bd) { bd = d2; bi = i2; }   // strict <, ascending chunks => first-min
        }
        bdl[0][lane] = bd; bil[0][lane] = bi;
    }
    __syncthreads();
    bi = bil[0][lane];
    const float* cr = cb + (size_t)bi * 64;
    float* qp = q + (size_t)n * 64 * HW + pix;
#pragma unroll
    for (int dd = 0; dd < 16; dd++)
        qp[(size_t)(wvi * 16 + dd) * HW] = cr[wvi * 16 + dd];
    if (wvi == 0) {
        float s = bd;
#pragma unroll
        for (int o = 32; o > 0; o >>= 1) s += __shfl_down(s, o, 64);
        if (lane == 0) ssep[blockIdx.x] = s;
        atomicAdd(&hist[bi], 1);
    }
}

__global__ void vq_init(int* hist)
{
    for (int i = threadIdx.x; i < 512; i += 256) hist[i] = 0;
}

__global__ __launch_bounds__(256) void vq_finalize(
    const float* __restrict__ ssep, const int* __restrict__ hist,
    float* __restrict__ o_loss, float* __restrict__ o_perp)
{
    __shared__ float red[256];
    const int tid = threadIdx.x;
    float h = 0.f;
    for (int i = tid; i < 512; i += 256) {
        float p = (float)hist[i] * (1.0f / 65536.0f);
        h -= p * logf(p + 1e-10f);
    }
    red[tid] = h;
    __syncthreads();
    for (int st = 128; st > 0; st >>= 1) {
        if (tid < st) red[tid] += red[tid + st];
        __syncthreads();
    }
    const float H = red[0];
    __syncthreads();
    float s = 0.f;
    for (int i = tid; i < 1024; i += 256) s += ssep[i];
    red[tid] = s;
    __syncthreads();
    for (int st = 128; st > 0; st >>= 1) {
        if (tid < st) red[tid] += red[tid + st];
        __syncthreads();
    }
    if (tid == 0) {
        *o_loss = 1.25f * red[0] / 4194304.0f;
        *o_perp = expf(H);
    }
}

extern "C" void kernel_launch(void* const* d_in, const int* in_sizes, int n_in,
                              void* d_out, int out_size, void* d_ws, size_t ws_size,
                              hipStream_t stream)
{
    const float* x       = (const float*)d_in[0];
    const float* enc_w1  = (const float*)d_in[1];
    const float* enc_b1  = (const float*)d_in[2];
    const float* enc_w2  = (const float*)d_in[3];
    const float* enc_b2  = (const float*)d_in[4];
    const float* enc_w3  = (const float*)d_in[5];
    const float* enc_b3  = (const float*)d_in[6];
    const float* enc_rw3 = (const float*)d_in[7];
    const float* enc_rb3 = (const float*)d_in[8];
    const float* enc_rw1 = (const float*)d_in[9];
    const float* enc_rb1 = (const float*)d_in[10];
    const float* pre_w   = (const float*)d_in[11];
    const float* pre_b   = (const float*)d_in[12];
    const float* cb      = (const float*)d_in[13];
    const float* dec_w1  = (const float*)d_in[14];
    const float* dec_b1  = (const float*)d_in[15];
    const float* dec_rw3 = (const float*)d_in[16];
    const float* dec_rb3 = (const float*)d_in[17];
    const float* dec_rw1 = (const float*)d_in[18];
    const float* dec_rb1 = (const float*)d_in[19];
    const float* dw1     = (const float*)d_in[20];
    const float* db1     = (const float*)d_in[21];
    const float* dw2     = (const float*)d_in[22];
    const float* db2     = (const float*)d_in[23];

    float* o      = (float*)d_out;
    float* loss_p = o;
    float* recon  = o + 1;
    float* perp_p = o + 1 + 16 * 3 * 256 * 256;

    // ws: A 16.78M | B 8.39M | C 8.39M | Dt 2.10M | SSE 1024 | HIST 512 | packed weights
    float* ws  = (float*)d_ws;
    float* A   = ws;
    float* B   = A + 16777216;
    float* C   = B + 8388608;
    float* Dt  = C + 8388608;
    float* SSE = Dt + 2097152;
    int*   HIST = (int*)(SSE + 1024);
    float* Q   = A;

    unsigned short* wp_cur = (unsigned short*)(((size_t)(HIST + 512) + 31) & ~(size_t)31);
    auto carve = [&](size_t n_us) {
        unsigned short* p = wp_cur;
        wp_cur += ((n_us + 15) & ~(size_t)15);
        return p;
    };
    auto PK = [&](const float* w, unsigned short* hi, unsigned short* lo,
                  int Co, int Ci, int KK, int CoP, int CiP) {
        int tot = KK * CoP * CiP;
        pack_w<<<dim3((tot + 255) / 256), dim3(256), 0, stream>>>(w, hi, lo, Co, Ci, KK, CoP, CiP);
    };

    // packed-weight slots (hi/lo)
    unsigned short *e1H = carve(16*64*16),  *e1L = carve(16*64*16);
    unsigned short *e2H = carve(16*128*64), *e2L = carve(16*128*64);
    unsigned short *e3H = carve(9*128*128), *e3L = carve(9*128*128);
    unsigned short *er3aH = carve(9*32*128), *er3aL = carve(9*32*128);
    unsigned short *er3bH = carve(9*32*128), *er3bL = carve(9*32*128);
    unsigned short *er1aH = carve(128*32),   *er1aL = carve(128*32);
    unsigned short *er1bH = carve(128*32),   *er1bL = carve(128*32);
    unsigned short *preH = carve(64*128),    *preL = carve(64*128);
    unsigned short *d1H  = carve(9*128*64),  *d1L  = carve(9*128*64);
    unsigned short *dr3aH = carve(9*32*128), *dr3aL = carve(9*32*128);
    unsigned short *dr3bH = carve(9*32*128), *dr3bL = carve(9*32*128);
    unsigned short *dr1aH = carve(128*32),   *dr1aL = carve(128*32);
    unsigned short *dr1bH = carve(128*32),   *dr1bL = carve(128*32);
    unsigned short *ct1H = carve(16*64*128), *ct1L = carve(16*64*128);
    unsigned short *ct2H = carve(16*32*64),  *ct2L = carve(16*32*64);

    PK(enc_w1, e1H, e1L, 64, 3, 16, 64, 16);
    PK(enc_w2, e2H, e2L, 128, 64, 16, 128, 64);
    PK(enc_w3, e3H, e3L, 128, 128, 9, 128, 128);
    PK(enc_rw3,             er3aH, er3aL, 32, 128, 9, 32, 128);
    PK(enc_rw3 + 32*128*9,  er3bH, er3bL, 32, 128, 9, 32, 128);
    PK(enc_rw1,             er1aH, er1aL, 128, 32, 1, 128, 32);
    PK(enc_rw1 + 128*32,    er1bH, er1bL, 128, 32, 1, 128, 32);
    PK(pre_w, preH, preL, 64, 128, 1, 64, 128);
    PK(dec_w1, d1H, d1L, 128, 64, 9, 128, 64);
    PK(dec_rw3,             dr3aH, dr3aL, 32, 128, 9, 32, 128);
    PK(dec_rw3 + 32*128*9,  dr3bH, dr3bL, 32, 128, 9, 32, 128);
    PK(dec_rw1,             dr1aH, dr1aL, 128, 32, 1, 128, 32);
    PK(dec_rw1 + 128*32,    dr1bH, dr1bL, 128, 32, 1, 128, 32);
    PK(dw1, ct1H, ct1L, 64, 128, 16, 64, 128);
    PK(dw2, ct2H, ct2L, 3, 64, 16, 32, 64);

    const int N = 16;

    // ---- encoder ----
    conv_mfma<4,2,1, 3,64, 256,256, 128,128, 1,64, 2,2, 64,16,  false,true ,false>
        <<<dim3(256,1,N),256,0,stream>>>(x, e1H, e1L, enc_b1, nullptr, A);
    conv_mfma<4,2,1, 64,128, 128,128, 64,64, 1,64, 2,2, 128,64, false,true ,false>
        <<<dim3(64,2,N),256,0,stream>>>(A, e2H, e2L, enc_b2, nullptr, B);
    conv_mfma<3,1,1, 128,128, 64,64, 64,64, 1,64, 2,2, 128,128, false,false,false>
        <<<dim3(64,2,N),256,0,stream>>>(B, e3H, e3L, enc_b3, nullptr, C);
    conv_mfma<3,1,1, 128,32, 64,64, 64,64, 2,64, 1,4, 32,128,   true ,false,false>
        <<<dim3(32,1,N),256,0,stream>>>(C, er3aH, er3aL, enc_rb3, nullptr, Dt);
    conv_mfma<1,1,0, 32,128, 64,64, 64,64, 1,64, 2,2, 128,32,   true ,false,true >
        <<<dim3(64,2,N),256,0,stream>>>(Dt, er1aH, er1aL, enc_rb1, C, C);
    conv_mfma<3,1,1, 128,32, 64,64, 64,64, 2,64, 1,4, 32,128,   true ,false,false>
        <<<dim3(32,1,N),256,0,stream>>>(C, er3bH, er3bL, enc_rb3 + 32, nullptr, Dt);
    conv_mfma<1,1,0, 32,128, 64,64, 64,64, 1,64, 2,2, 128,32,   true ,false,true >
        <<<dim3(64,2,N),256,0,stream>>>(Dt, er1bH, er1bL, enc_rb1 + 128, C, C);
    conv_mfma<1,1,0, 128,64, 64,64, 64,64, 1,64, 2,2, 64,128,   true ,false,false>
        <<<dim3(64,1,N),256,0,stream>>>(C, preH, preL, pre_b, nullptr, B);

    // ---- VQ ----
    vq_init<<<dim3(1), dim3(256), 0, stream>>>(HIST);
    vq_search<<<dim3(1024), dim3(256), 0, stream>>>(B, cb, Q, SSE, HIST, 64 * 64);
    vq_finalize<<<dim3(1), dim3(256), 0, stream>>>(SSE, HIST, loss_p, perp_p);

    // ---- decoder ----
    conv_mfma<3,1,1, 64,128, 64,64, 64,64, 1,64, 2,2, 128,64,   false,false,false>
        <<<dim3(64,2,N),256,0,stream>>>(Q, d1H, d1L, dec_b1, nullptr, C);
    conv_mfma<3,1,1, 128,32, 64,64, 64,64, 2,64, 1,4, 32,128,   true ,false,false>
        <<<dim3(32,1,N),256,0,stream>>>(C, dr3aH, dr3aL, dec_rb3, nullptr, Dt);
    conv_mfma<1,1,0, 32,128, 64,64, 64,64, 1,64, 2,2, 128,32,   true ,false,true >
        <<<dim3(64,2,N),256,0,stream>>>(Dt, dr1aH, dr1aL, dec_rb1, C, C);
    conv_mfma<3,1,1, 128,32, 64,64, 64,64, 2,64, 1,4, 32,128,   true ,false,false>
        <<<dim3(32,1,N),256,0,stream>>>(C, dr3bH, dr3bL, dec_rb3 + 32, nullptr, Dt);
    conv_mfma<1,1,0, 32,128, 64,64, 64,64, 1,64, 2,2, 128,32,   true ,false,true >
        <<<dim3(64,2,N),256,0,stream>>>(Dt, dr1bH, dr1bL, dec_rb1 + 128, C, C);
    convt_mfma<128,64, 64,64, 2,2, 64,  true ,true >
        <<<dim3(256,1,N),256,0,stream>>>(C, ct1H, ct1L, db1, A);
    convt_mfma<64,3, 128,128, 1,4, 32,  false,false>
        <<<dim3(512,1,N),256,0,stream>>>(A, ct2H, ct2L, db2, recon);
}

// Round 6
// 1408.816 us; speedup vs baseline: 4.9049x; 1.2476x over previous
//
#include <hip/hip_runtime.h>

typedef __attribute__((ext_vector_type(8)))  short bf16x8;
typedef __attribute__((ext_vector_type(16))) float f32x16;

// split fp32 -> (hi, lo) bf16 pair, RNE both
__device__ inline void fsplit(float v, unsigned short& h, unsigned short& l)
{
    union { float f; unsigned u; } a; a.f = v;
    unsigned uh = a.u + 0x7fffu + ((a.u >> 16) & 1u);
    h = (unsigned short)(uh >> 16);
    union { float f; unsigned u; } hb; hb.u = (unsigned)h << 16;
    float r = v - hb.f;
    union { float f; unsigned u; } b; b.f = r;
    unsigned ul = b.u + 0x7fffu + ((b.u >> 16) & 1u);
    l = (unsigned short)(ul >> 16);
}

__device__ inline float bf2f(unsigned short u)
{
    union { float f; unsigned v; } a; a.v = (unsigned)u << 16; return a.f;
}

// pack OIHW fp32 weights -> [tap][co_pad][ci_pad] bf16 hi/lo, zero-padded
__global__ void pack_w(const float* __restrict__ w, unsigned short* __restrict__ hi,
                       unsigned short* __restrict__ lo, int Cout, int Cin, int KK,
                       int CoP, int CiP)
{
    int i = blockIdx.x * 256 + threadIdx.x;
    int tot = KK * CoP * CiP;
    if (i >= tot) return;
    int t  = i / (CoP * CiP);
    int r  = i - t * (CoP * CiP);
    int co = r / CiP;
    int ci = r - co * CiP;
    float v = (co < Cout && ci < Cin) ? w[((size_t)co * Cin + ci) * KK + t] : 0.f;
    unsigned short h, l;
    fsplit(v, h, l);
    hi[i] = h; lo[i] = l;
}

__global__ void cb_norm(const float* __restrict__ cb, float* __restrict__ cn)
{
    int i = blockIdx.x * 256 + threadIdx.x;
    if (i >= 512) return;
    float s = 0.f;
    for (int d = 0; d < 64; d++) s = fmaf(cb[i*64+d], cb[i*64+d], s);
    cn[i] = s;
}

// ============ MFMA direct conv (correlation, NCHW, packed weights) ============
// 4 waves: WM co-wave-groups x WN px-groups (32 px each); each wave computes CO2
// co-groups of 32 (acc pairs). Input chunk (16 ci) staged in LDS as bf16 hi/lo,
// [pos][16ci] pitch-12 words. Register-prefetch pipeline: chunk k+1 loaded+split
// during MFMA on chunk k, written to LDS after the read barrier.
template<int K,int S,int P,int CIN,int COUT,int HIN,int WIN,int HOUT,int WOUT,
         int TR,int TC,int WM,int WN,int CO2,int CO_PAD,int CI_PAD,
         bool RIN,bool ROUT,bool RES>
__global__ __launch_bounds__(256) void conv_mfma(
    const float* __restrict__ in, const unsigned short* __restrict__ wpH,
    const unsigned short* __restrict__ wpL, const float* __restrict__ bias,
    const float* __restrict__ res, float* __restrict__ out)
{
    constexpr int IHT = (TR - 1) * S + K;
    constexpr int IW  = (TC - 1) * S + K;
    constexpr int PS  = IHT * IW;
    constexpr int KK  = K * K;
    constexpr int NCH = CI_PAD / 16;
    constexpr int XB  = WOUT / TC;
    constexpr int REGN = (PS * 8 + 255) / 256;

    __shared__ __align__(16) unsigned lbufH[PS * 12];
    __shared__ __align__(16) unsigned lbufL[PS * 12];

    const int tid = threadIdx.x;
    const int bx  = blockIdx.x;
    const int r0  = (bx / XB) * TR;
    const int c0  = (bx % XB) * TC;
    const int n   = blockIdx.z;

    const int l  = tid & 63;
    const int wv = tid >> 6;
    const int wm = wv / WN;
    const int wn = wv % WN;
    const int ln = l & 31;
    const int kg = l >> 5;

    const int q  = wn * 32 + ln;
    const int lr = q / TC;
    const int lc = q % TC;

    f32x16 acc[CO2][2];
#pragma unroll
    for (int g = 0; g < CO2; g++) { acc[g][0] = (f32x16){}; acc[g][1] = (f32x16){}; }

    const float* pin = in + (size_t)n * CIN * HIN * WIN;
    const int pb = (lr * S) * IW + lc * S;

    auto stage_direct = [&](int kc){
        for (int idx = tid; idx < PS * 8; idx += 256) {
            int c2  = idx / PS;
            int pos = idx - c2 * PS;
            int gy  = r0 * S - P + pos / IW;
            int gx  = c0 * S - P + pos % IW;
            int ci0 = kc * 16 + 2 * c2;
            float v0 = 0.f, v1 = 0.f;
            if ((unsigned)gy < (unsigned)HIN && (unsigned)gx < (unsigned)WIN) {
                const float* pp = pin + (size_t)gy * WIN + gx;
                if (ci0     < CIN) v0 = pp[(size_t)ci0 * HIN * WIN];
                if (ci0 + 1 < CIN) v1 = pp[(size_t)(ci0 + 1) * HIN * WIN];
            }
            if (RIN) { v0 = fmaxf(v0, 0.f); v1 = fmaxf(v1, 0.f); }
            unsigned short h0, l0, h1, l1;
            fsplit(v0, h0, l0); fsplit(v1, h1, l1);
            lbufH[pos * 12 + c2] = (unsigned)h0 | ((unsigned)h1 << 16);
            lbufL[pos * 12 + c2] = (unsigned)l0 | ((unsigned)l1 << 16);
        }
    };

    unsigned rvH[REGN], rvL[REGN];
    auto load_regs = [&](int kc){
#pragma unroll
        for (int rr = 0; rr < REGN; rr++) {
            int idx = tid + rr * 256;
            unsigned uH = 0, uL = 0;
            if (idx < PS * 8) {
                int c2  = idx / PS;
                int pos = idx - c2 * PS;
                int gy  = r0 * S - P + pos / IW;
                int gx  = c0 * S - P + pos % IW;
                int ci0 = kc * 16 + 2 * c2;
                float v0 = 0.f, v1 = 0.f;
                if ((unsigned)gy < (unsigned)HIN && (unsigned)gx < (unsigned)WIN) {
                    const float* pp = pin + (size_t)gy * WIN + gx;
                    if (ci0     < CIN) v0 = pp[(size_t)ci0 * HIN * WIN];
                    if (ci0 + 1 < CIN) v1 = pp[(size_t)(ci0 + 1) * HIN * WIN];
                }
                if (RIN) { v0 = fmaxf(v0, 0.f); v1 = fmaxf(v1, 0.f); }
                unsigned short h0, l0, h1, l1;
                fsplit(v0, h0, l0); fsplit(v1, h1, l1);
                uH = (unsigned)h0 | ((unsigned)h1 << 16);
                uL = (unsigned)l0 | ((unsigned)l1 << 16);
            }
            rvH[rr] = uH; rvL[rr] = uL;
        }
    };
    auto write_regs = [&](){
#pragma unroll
        for (int rr = 0; rr < REGN; rr++) {
            int idx = tid + rr * 256;
            if (idx < PS * 8) {
                int c2  = idx / PS;
                int pos = idx - c2 * PS;
                lbufH[pos * 12 + c2] = rvH[rr];
                lbufL[pos * 12 + c2] = rvL[rr];
            }
        }
    };

    auto compute = [&](int kc){
#pragma unroll
        for (int t = 0; t < KK; t++) {
            const int ky = t / K, kx = t % K;
            const int word = (pb + ky * IW + kx) * 12 + kg * 4;
            bf16x8 bH = *(const bf16x8*)(&lbufH[word]);
            bf16x8 bL = *(const bf16x8*)(&lbufL[word]);
#pragma unroll
            for (int g = 0; g < CO2; g++) {
                const int coA = (wm * CO2 + g) * 32 + ln;
                const size_t wo = ((size_t)t * CO_PAD + coA) * CI_PAD + kc * 16 + kg * 8;
                bf16x8 aH = *(const bf16x8*)(wpH + wo);
                bf16x8 aL = *(const bf16x8*)(wpL + wo);
                acc[g][0] = __builtin_amdgcn_mfma_f32_32x32x16_bf16(aH, bH, acc[g][0], 0, 0, 0);
                acc[g][1] = __builtin_amdgcn_mfma_f32_32x32x16_bf16(aH, bL, acc[g][1], 0, 0, 0);
                acc[g][1] = __builtin_amdgcn_mfma_f32_32x32x16_bf16(aL, bH, acc[g][1], 0, 0, 0);
            }
        }
    };

    stage_direct(0);
    __syncthreads();
    for (int kc = 0; kc < NCH; kc++) {
        const bool more = (kc + 1 < NCH);
        if (more) load_regs(kc + 1);
        compute(kc);
        if (more) {
            __syncthreads();
            write_regs();
            __syncthreads();
        }
    }

    const size_t obase = (size_t)n * COUT * HOUT * WOUT;
    const int gy = r0 + lr, gx = c0 + lc;
#pragma unroll
    for (int g = 0; g < CO2; g++) {
#pragma unroll
        for (int r = 0; r < 16; r++) {
            int m  = (r & 3) + 8 * (r >> 2) + 4 * kg;
            int co = (wm * CO2 + g) * 32 + m;
            if (co < COUT) {
                size_t ad = obase + ((size_t)co * HOUT + gy) * WOUT + gx;
                float v = acc[g][0][r] + acc[g][1][r] + bias[co];
                if (RES) v += res[ad];
                if (ROUT) v = fmaxf(v, 0.f);
                out[ad] = v;
            }
        }
    }
}

// ============ MFMA transpose conv k=4 s=2 p=1 (gather/parity form) ============
// Block: one out row oy x one x-half; 4 waves = 2 parities x 2 x-blocks (parity
// per-wave => taps wave-uniform). Each wave: CO2 co-groups of 32.
// ox = xh*128 + p + 2*(xb*32+ln); taps (ky0+2ty, p+2tx); ix = xh*64+xb*32+ln+p-1+tx.
template<int CIN,int COUT,int HIN,int WIN,int CO2,int CO_PAD,bool RIN,bool ROUT>
__global__ __launch_bounds__(256) void convt_mfma(
    const float* __restrict__ in, const unsigned short* __restrict__ wpH,
    const unsigned short* __restrict__ wpL, const float* __restrict__ bias,
    float* __restrict__ out)
{
    constexpr int HOUT = 2 * HIN, WOUT = 2 * WIN;
    constexpr int XHN  = WOUT / 128;
    constexpr int PS   = 2 * 68;
    constexpr int NCH  = CIN / 16;
    constexpr int REGN = (PS * 8 + 255) / 256;

    __shared__ __align__(16) unsigned lbufH[PS * 12];
    __shared__ __align__(16) unsigned lbufL[PS * 12];

    const int tid = threadIdx.x;
    const int oy  = blockIdx.x / XHN;
    const int xh  = blockIdx.x % XHN;
    const int n   = blockIdx.z;

    const int ky0 = oy & 1;
    const int iyb = ((oy + ky0) >> 1) - 1;

    const int l  = tid & 63, wv = tid >> 6;
    const int p  = wv & 1, xb = wv >> 1;
    const int ln = l & 31, kg = l >> 5;

    f32x16 acc[CO2][2];
#pragma unroll
    for (int g = 0; g < CO2; g++) { acc[g][0] = (f32x16){}; acc[g][1] = (f32x16){}; }

    const float* pin = in + (size_t)n * CIN * HIN * WIN;

    auto stage_direct = [&](int kc){
        for (int idx = tid; idx < PS * 8; idx += 256) {
            int c2  = idx / PS;
            int pos = idx - c2 * PS;
            int rr  = pos / 68, cc = pos - rr * 68;
            int gy  = iyb + rr, gx = xh * 64 + cc - 1;
            int ci0 = kc * 16 + 2 * c2;
            float v0 = 0.f, v1 = 0.f;
            if ((unsigned)gy < (unsigned)HIN && (unsigned)gx < (unsigned)WIN) {
                const float* pp = pin + (size_t)gy * WIN + gx;
                v0 = pp[(size_t)ci0 * HIN * WIN];
                v1 = pp[(size_t)(ci0 + 1) * HIN * WIN];
            }
            if (RIN) { v0 = fmaxf(v0, 0.f); v1 = fmaxf(v1, 0.f); }
            unsigned short h0, l0, h1, l1;
            fsplit(v0, h0, l0); fsplit(v1, h1, l1);
            lbufH[pos * 12 + c2] = (unsigned)h0 | ((unsigned)h1 << 16);
            lbufL[pos * 12 + c2] = (unsigned)l0 | ((unsigned)l1 << 16);
        }
    };

    unsigned rvH[REGN], rvL[REGN];
    auto load_regs = [&](int kc){
#pragma unroll
        for (int rr2 = 0; rr2 < REGN; rr2++) {
            int idx = tid + rr2 * 256;
            unsigned uH = 0, uL = 0;
            if (idx < PS * 8) {
                int c2  = idx / PS;
                int pos = idx - c2 * PS;
                int rr  = pos / 68, cc = pos - rr * 68;
                int gy  = iyb + rr, gx = xh * 64 + cc - 1;
                int ci0 = kc * 16 + 2 * c2;
                float v0 = 0.f, v1 = 0.f;
                if ((unsigned)gy < (unsigned)HIN && (unsigned)gx < (unsigned)WIN) {
                    const float* pp = pin + (size_t)gy * WIN + gx;
                    v0 = pp[(size_t)ci0 * HIN * WIN];
                    v1 = pp[(size_t)(ci0 + 1) * HIN * WIN];
                }
                if (RIN) { v0 = fmaxf(v0, 0.f); v1 = fmaxf(v1, 0.f); }
                unsigned short h0, l0, h1, l1;
                fsplit(v0, h0, l0); fsplit(v1, h1, l1);
                uH = (unsigned)h0 | ((unsigned)h1 << 16);
                uL = (unsigned)l0 | ((unsigned)l1 << 16);
            }
            rvH[rr2] = uH; rvL[rr2] = uL;
        }
    };
    auto write_regs = [&](){
#pragma unroll
        for (int rr2 = 0; rr2 < REGN; rr2++) {
            int idx = tid + rr2 * 256;
            if (idx < PS * 8) {
                int c2  = idx / PS;
                int pos = idx - c2 * PS;
                lbufH[pos * 12 + c2] = rvH[rr2];
                lbufL[pos * 12 + c2] = rvL[rr2];
            }
        }
    };

    auto compute = [&](int kc){
#pragma unroll
        for (int ty = 0; ty < 2; ty++)
#pragma unroll
        for (int tx = 0; tx < 2; tx++) {
            const int widx = (ky0 + 2 * ty) * 4 + (p + 2 * tx);
            const int word = (ty * 68 + xb * 32 + ln + p + tx) * 12 + kg * 4;
            bf16x8 bH = *(const bf16x8*)(&lbufH[word]);
            bf16x8 bL = *(const bf16x8*)(&lbufL[word]);
#pragma unroll
            for (int g = 0; g < CO2; g++) {
                const int coA = g * 32 + ln;
                const size_t wo = ((size_t)widx * CO_PAD + coA) * CIN + kc * 16 + kg * 8;
                bf16x8 aH = *(const bf16x8*)(wpH + wo);
                bf16x8 aL = *(const bf16x8*)(wpL + wo);
                acc[g][0] = __builtin_amdgcn_mfma_f32_32x32x16_bf16(aH, bH, acc[g][0], 0, 0, 0);
                acc[g][1] = __builtin_amdgcn_mfma_f32_32x32x16_bf16(aH, bL, acc[g][1], 0, 0, 0);
                acc[g][1] = __builtin_amdgcn_mfma_f32_32x32x16_bf16(aL, bH, acc[g][1], 0, 0, 0);
            }
        }
    };

    stage_direct(0);
    __syncthreads();
    for (int kc = 0; kc < NCH; kc++) {
        const bool more = (kc + 1 < NCH);
        if (more) load_regs(kc + 1);
        compute(kc);
        if (more) {
            __syncthreads();
            write_regs();
            __syncthreads();
        }
    }

    const int ox = xh * 128 + p + 2 * (xb * 32 + ln);
#pragma unroll
    for (int g = 0; g < CO2; g++) {
#pragma unroll
        for (int r = 0; r < 16; r++) {
            int m  = (r & 3) + 8 * (r >> 2) + 4 * kg;
            int co = g * 32 + m;
            if (co < COUT) {
                size_t ad = (((size_t)n * COUT + co) * HOUT + oy) * WOUT + ox;
                float v = acc[g][0][r] + acc[g][1][r] + bias[co];
                if (ROUT) v = fmaxf(v, 0.f);
                out[ad] = v;
            }
        }
    }
}

// ================= VQ via MFMA =================
// Block = 128 tokens (4 waves x 32). z tile staged in LDS bf16 hi/lo. Per wave:
// loop 16 code-groups of 32, s = x.c via 3-MFMA split, m = |c|^2 - 2s, tracked
// argmin (codes ascending per lane; cross-half combine by (dist, index)).
__global__ __launch_bounds__(256) void vq_mfma(
    const float* __restrict__ z, const unsigned short* __restrict__ cbH,
    const unsigned short* __restrict__ cbL, const float* __restrict__ cbf,
    const float* __restrict__ cnorm, float* __restrict__ q,
    float* __restrict__ ssep, int* __restrict__ hist)
{
    __shared__ __align__(16) unsigned short zH[128 * 72];
    __shared__ __align__(16) unsigned short zL[128 * 72];
    __shared__ float cnl[512];
    __shared__ int   hl[512];

    const int tid = threadIdx.x;
    const int blk = blockIdx.x;

    for (int i = tid; i < 512; i += 256) { cnl[i] = cnorm[i]; hl[i] = 0; }

    for (int idx = tid; idx < 8192; idx += 256) {
        int tok = idx >> 6, d = idx & 63;
        int t = blk * 128 + tok;
        int n = t >> 12, pix = t & 4095;
        float v = z[((size_t)n * 64 + d) * 4096 + pix];
        unsigned short h, l;
        fsplit(v, h, l);
        zH[tok * 72 + d] = h;
        zL[tok * 72 + d] = l;
    }
    __syncthreads();

    const int l  = tid & 63, wv = tid >> 6;
    const int ln = l & 31, kg = l >> 5;
    const int tok = wv * 32 + ln;

    // |x|^2 from reconstructed hi+lo (matches staged values to ~2^-18)
    float xn = 0.f;
#pragma unroll
    for (int j8 = 0; j8 < 8; j8++) {
        bf16x8 vH = *(const bf16x8*)(&zH[tok * 72 + j8 * 8]);
        bf16x8 vL = *(const bf16x8*)(&zL[tok * 72 + j8 * 8]);
#pragma unroll
        for (int j = 0; j < 8; j++) {
            float xv = bf2f((unsigned short)vH[j]) + bf2f((unsigned short)vL[j]);
            xn = fmaf(xv, xv, xn);
        }
    }

    float bm = 3.4e38f; int bidx = 0;
    for (int cg = 0; cg < 16; cg++) {
        f32x16 a0 = {}, a1 = {};
#pragma unroll
        for (int ks = 0; ks < 4; ks++) {
            const size_t wo = ((size_t)(cg * 32 + ln)) * 64 + ks * 16 + kg * 8;
            bf16x8 aH = *(const bf16x8*)(cbH + wo);
            bf16x8 aL = *(const bf16x8*)(cbL + wo);
            bf16x8 bH = *(const bf16x8*)(&zH[tok * 72 + ks * 16 + kg * 8]);
            bf16x8 bL = *(const bf16x8*)(&zL[tok * 72 + ks * 16 + kg * 8]);
            a0 = __builtin_amdgcn_mfma_f32_32x32x16_bf16(aH, bH, a0, 0, 0, 0);
            a1 = __builtin_amdgcn_mfma_f32_32x32x16_bf16(aH, bL, a1, 0, 0, 0);
            a1 = __builtin_amdgcn_mfma_f32_32x32x16_bf16(aL, bH, a1, 0, 0, 0);
        }
#pragma unroll
        for (int r = 0; r < 16; r++) {
            int m    = (r & 3) + 8 * (r >> 2) + 4 * kg;   // ascending in r
            int code = cg * 32 + m;
            float s  = a0[r] + a1[r];
            float dm = cnl[code] - 2.f * s;
            if (dm < bm) { bm = dm; bidx = code; }
        }
    }

    // combine the two half-wave code subsets (same token), tie -> lower index
    float bm2 = __shfl_xor(bm, 32);
    int   bi2 = __shfl_xor(bidx, 32);
    if (bm2 < bm || (bm2 == bm && bi2 < bidx)) { bm = bm2; bidx = bi2; }

    // q gather (exact fp32 codebook rows)
    {
        int t = blk * 128 + tok;
        int n = t >> 12, pix = t & 4095;
#pragma unroll
        for (int j = 0; j < 32; j++) {
            int d = kg * 32 + j;
            q[((size_t)n * 64 + d) * 4096 + pix] = cbf[(size_t)bidx * 64 + d];
        }
    }

    float bestd = xn + bm;
    float c = (kg == 0) ? bestd : 0.f;
#pragma unroll
    for (int o = 32; o > 0; o >>= 1) c += __shfl_down(c, o, 64);
    if (l == 0) ssep[blk * 4 + wv] = c;
    if (kg == 0) atomicAdd(&hl[bidx], 1);
    __syncthreads();
    for (int i = tid; i < 512; i += 256) if (hl[i] > 0) atomicAdd(&hist[i], hl[i]);
}

__global__ void vq_init(int* hist)
{
    for (int i = threadIdx.x; i < 512; i += 256) hist[i] = 0;
}

__global__ __launch_bounds__(256) void vq_finalize(
    const float* __restrict__ ssep, const int* __restrict__ hist,
    float* __restrict__ o_loss, float* __restrict__ o_perp)
{
    __shared__ float red[256];
    const int tid = threadIdx.x;
    float h = 0.f;
    for (int i = tid; i < 512; i += 256) {
        float p = (float)hist[i] * (1.0f / 65536.0f);
        h -= p * logf(p + 1e-10f);
    }
    red[tid] = h;
    __syncthreads();
    for (int st = 128; st > 0; st >>= 1) {
        if (tid < st) red[tid] += red[tid + st];
        __syncthreads();
    }
    const float H = red[0];
    __syncthreads();
    float s = 0.f;
    for (int i = tid; i < 2048; i += 256) s += ssep[i];
    red[tid] = s;
    __syncthreads();
    for (int st = 128; st > 0; st >>= 1) {
        if (tid < st) red[tid] += red[tid + st];
        __syncthreads();
    }
    if (tid == 0) {
        *o_loss = 1.25f * red[0] / 4194304.0f;
        *o_perp = expf(H);
    }
}

extern "C" void kernel_launch(void* const* d_in, const int* in_sizes, int n_in,
                              void* d_out, int out_size, void* d_ws, size_t ws_size,
                              hipStream_t stream)
{
    const float* x       = (const float*)d_in[0];
    const float* enc_w1  = (const float*)d_in[1];
    const float* enc_b1  = (const float*)d_in[2];
    const float* enc_w2  = (const float*)d_in[3];
    const float* enc_b2  = (const float*)d_in[4];
    const float* enc_w3  = (const float*)d_in[5];
    const float* enc_b3  = (const float*)d_in[6];
    const float* enc_rw3 = (const float*)d_in[7];
    const float* enc_rb3 = (const float*)d_in[8];
    const float* enc_rw1 = (const float*)d_in[9];
    const float* enc_rb1 = (const float*)d_in[10];
    const float* pre_w   = (const float*)d_in[11];
    const float* pre_b   = (const float*)d_in[12];
    const float* cb      = (const float*)d_in[13];
    const float* dec_w1  = (const float*)d_in[14];
    const float* dec_b1  = (const float*)d_in[15];
    const float* dec_rw3 = (const float*)d_in[16];
    const float* dec_rb3 = (const float*)d_in[17];
    const float* dec_rw1 = (const float*)d_in[18];
    const float* dec_rb1 = (const float*)d_in[19];
    const float* dw1     = (const float*)d_in[20];
    const float* db1     = (const float*)d_in[21];
    const float* dw2     = (const float*)d_in[22];
    const float* db2     = (const float*)d_in[23];

    float* o      = (float*)d_out;
    float* loss_p = o;
    float* recon  = o + 1;
    float* perp_p = o + 1 + 16 * 3 * 256 * 256;

    // ws: A 16.78M | B 8.39M | C 8.39M | Dt 2.10M | SSE 2048 | HIST 512 | packed data
    float* ws  = (float*)d_ws;
    float* A   = ws;
    float* B   = A + 16777216;
    float* C   = B + 8388608;
    float* Dt  = C + 8388608;
    float* SSE = Dt + 2097152;
    int*   HIST = (int*)(SSE + 2048);
    float* Q   = A;

    unsigned short* wp_cur = (unsigned short*)(((size_t)(HIST + 512) + 31) & ~(size_t)31);
    auto carve = [&](size_t n_us) {
        unsigned short* p = wp_cur;
        wp_cur += ((n_us + 15) & ~(size_t)15);
        return p;
    };
    auto PK = [&](const float* w, unsigned short* hi, unsigned short* lo,
                  int Co, int Ci, int KK, int CoP, int CiP) {
        int tot = KK * CoP * CiP;
        pack_w<<<dim3((tot + 255) / 256), dim3(256), 0, stream>>>(w, hi, lo, Co, Ci, KK, CoP, CiP);
    };

    unsigned short *e1H = carve(16*64*16),  *e1L = carve(16*64*16);
    unsigned short *e2H = carve(16*128*64), *e2L = carve(16*128*64);
    unsigned short *e3H = carve(9*128*128), *e3L = carve(9*128*128);
    unsigned short *er3aH = carve(9*32*128), *er3aL = carve(9*32*128);
    unsigned short *er3bH = carve(9*32*128), *er3bL = carve(9*32*128);
    unsigned short *er1aH = carve(128*32),   *er1aL = carve(128*32);
    unsigned short *er1bH = carve(128*32),   *er1bL = carve(128*32);
    unsigned short *preH = carve(64*128),    *preL = carve(64*128);
    unsigned short *d1H  = carve(9*128*64),  *d1L  = carve(9*128*64);
    unsigned short *dr3aH = carve(9*32*128), *dr3aL = carve(9*32*128);
    unsigned short *dr3bH = carve(9*32*128), *dr3bL = carve(9*32*128);
    unsigned short *dr1aH = carve(128*32),   *dr1aL = carve(128*32);
    unsigned short *dr1bH = carve(128*32),   *dr1bL = carve(128*32);
    unsigned short *ct1H = carve(16*64*128), *ct1L = carve(16*64*128);
    unsigned short *ct2H = carve(16*32*64),  *ct2L = carve(16*32*64);
    unsigned short *cbH  = carve(512*64),    *cbL  = carve(512*64);
    float* CN = (float*)carve(1024);

    PK(enc_w1, e1H, e1L, 64, 3, 16, 64, 16);
    PK(enc_w2, e2H, e2L, 128, 64, 16, 128, 64);
    PK(enc_w3, e3H, e3L, 128, 128, 9, 128, 128);
    PK(enc_rw3,             er3aH, er3aL, 32, 128, 9, 32, 128);
    PK(enc_rw3 + 32*128*9,  er3bH, er3bL, 32, 128, 9, 32, 128);
    PK(enc_rw1,             er1aH, er1aL, 128, 32, 1, 128, 32);
    PK(enc_rw1 + 128*32,    er1bH, er1bL, 128, 32, 1, 128, 32);
    PK(pre_w, preH, preL, 64, 128, 1, 64, 128);
    PK(dec_w1, d1H, d1L, 128, 64, 9, 128, 64);
    PK(dec_rw3,             dr3aH, dr3aL, 32, 128, 9, 32, 128);
    PK(dec_rw3 + 32*128*9,  dr3bH, dr3bL, 32, 128, 9, 32, 128);
    PK(dec_rw1,             dr1aH, dr1aL, 128, 32, 1, 128, 32);
    PK(dec_rw1 + 128*32,    dr1bH, dr1bL, 128, 32, 1, 128, 32);
    PK(dw1, ct1H, ct1L, 64, 128, 16, 64, 128);
    PK(dw2, ct2H, ct2L, 3, 64, 16, 32, 64);
    PK(cb,  cbH,  cbL,  512, 64, 1, 512, 64);
    cb_norm<<<dim3(2), dim3(256), 0, stream>>>(cb, CN);

    const int N = 16;

    // ---- encoder ----
    conv_mfma<4,2,1, 3,64, 256,256, 128,128, 1,128, 1,4,2, 64,16,  false,true ,false>
        <<<dim3(128,1,N),256,0,stream>>>(x, e1H, e1L, enc_b1, nullptr, A);
    conv_mfma<4,2,1, 64,128, 128,128, 64,64, 1,64, 2,2,2, 128,64, false,true ,false>
        <<<dim3(64,1,N),256,0,stream>>>(A, e2H, e2L, enc_b2, nullptr, B);
    conv_mfma<3,1,1, 128,128, 64,64, 64,64, 1,64, 2,2,2, 128,128, false,false,false>
        <<<dim3(64,1,N),256,0,stream>>>(B, e3H, e3L, enc_b3, nullptr, C);
    conv_mfma<3,1,1, 128,32, 64,64, 64,64, 2,64, 1,4,1, 32,128,   true ,false,false>
        <<<dim3(32,1,N),256,0,stream>>>(C, er3aH, er3aL, enc_rb3, nullptr, Dt);
    conv_mfma<1,1,0, 32,128, 64,64, 64,64, 1,64, 2,2,2, 128,32,   true ,false,true >
        <<<dim3(64,1,N),256,0,stream>>>(Dt, er1aH, er1aL, enc_rb1, C, C);
    conv_mfma<3,1,1, 128,32, 64,64, 64,64, 2,64, 1,4,1, 32,128,   true ,false,false>
        <<<dim3(32,1,N),256,0,stream>>>(C, er3bH, er3bL, enc_rb3 + 32, nullptr, Dt);
    conv_mfma<1,1,0, 32,128, 64,64, 64,64, 1,64, 2,2,2, 128,32,   true ,false,true >
        <<<dim3(64,1,N),256,0,stream>>>(Dt, er1bH, er1bL, enc_rb1 + 128, C, C);
    conv_mfma<1,1,0, 128,64, 64,64, 64,64, 1,64, 2,2,1, 64,128,   true ,false,false>
        <<<dim3(64,1,N),256,0,stream>>>(C, preH, preL, pre_b, nullptr, B);

    // ---- VQ ----
    vq_init<<<dim3(1), dim3(256), 0, stream>>>(HIST);
    vq_mfma<<<dim3(512), dim3(256), 0, stream>>>(B, cbH, cbL, cb, CN, Q, SSE, HIST);
    vq_finalize<<<dim3(1), dim3(256), 0, stream>>>(SSE, HIST, loss_p, perp_p);

    // ---- decoder ----
    conv_mfma<3,1,1, 64,128, 64,64, 64,64, 1,64, 2,2,2, 128,64,   false,false,false>
        <<<dim3(64,1,N),256,0,stream>>>(Q, d1H, d1L, dec_b1, nullptr, C);
    conv_mfma<3,1,1, 128,32, 64,64, 64,64, 2,64, 1,4,1, 32,128,   true ,false,false>
        <<<dim3(32,1,N),256,0,stream>>>(C, dr3aH, dr3aL, dec_rb3, nullptr, Dt);
    conv_mfma<1,1,0, 32,128, 64,64, 64,64, 1,64, 2,2,2, 128,32,   true ,false,true >
        <<<dim3(64,1,N),256,0,stream>>>(Dt, dr1aH, dr1aL, dec_rb1, C, C);
    conv_mfma<3,1,1, 128,32, 64,64, 64,64, 2,64, 1,4,1, 32,128,   true ,false,false>
        <<<dim3(32,1,N),256,0,stream>>>(C, dr3bH, dr3bL, dec_rb3 + 32, nullptr, Dt);
    conv_mfma<1,1,0, 32,128, 64,64, 64,64, 1,64, 2,2,2, 128,32,   true ,false,true >
        <<<dim3(64,1,N),256,0,stream>>>(Dt, dr1bH, dr1bL, dec_rb1 + 128, C, C);
    convt_mfma<128,64, 64,64, 2, 64,  true ,true >
        <<<dim3(128,1,N),256,0,stream>>>(C, ct1H, ct1L, db1, A);
    convt_mfma<64,3, 128,128, 1, 32,  false,false>
        <<<dim3(512,1,N),256,0,stream>>>(A, ct2H, ct2L, db2, recon);
}

// Round 7
// 1163.924 us; speedup vs baseline: 5.9369x; 1.2104x over previous
//
#include <hip/hip_runtime.h>

typedef __attribute__((ext_vector_type(8)))  short bf16x8;
typedef __attribute__((ext_vector_type(16))) float f32x16;
typedef unsigned long long u64t;

__device__ __forceinline__ int swzu(int u) { return u ^ ((u >> 5) & 3); }

// split fp32 -> (hi, lo) bf16 pair, RNE both
__device__ __forceinline__ void fsplit(float v, unsigned short& h, unsigned short& l)
{
    union { float f; unsigned u; } a; a.f = v;
    unsigned uh = a.u + 0x7fffu + ((a.u >> 16) & 1u);
    h = (unsigned short)(uh >> 16);
    union { float f; unsigned u; } hb; hb.u = (unsigned)h << 16;
    float r = v - hb.f;
    union { float f; unsigned u; } b; b.f = r;
    unsigned ul = b.u + 0x7fffu + ((b.u >> 16) & 1u);
    l = (unsigned short)(ul >> 16);
}

__device__ __forceinline__ float bf2f(unsigned short u)
{
    union { float f; unsigned v; } a; a.v = (unsigned)u << 16; return a.f;
}

// pack OIHW fp32 weights -> [tap][co_pad][ci_pad] bf16 hi/lo, zero-padded
__global__ void pack_w(const float* __restrict__ w, unsigned short* __restrict__ hi,
                       unsigned short* __restrict__ lo, int Cout, int Cin, int KK,
                       int CoP, int CiP)
{
    int i = blockIdx.x * 256 + threadIdx.x;
    int tot = KK * CoP * CiP;
    if (i >= tot) return;
    int t  = i / (CoP * CiP);
    int r  = i - t * (CoP * CiP);
    int co = r / CiP;
    int ci = r - co * CiP;
    float v = (co < Cout && ci < Cin) ? w[((size_t)co * Cin + ci) * KK + t] : 0.f;
    unsigned short h, l;
    fsplit(v, h, l);
    hi[i] = h; lo[i] = l;
}

__global__ void cb_norm(const float* __restrict__ cb, float* __restrict__ cn)
{
    int i = blockIdx.x * 256 + threadIdx.x;
    if (i >= 512) return;
    float s = 0.f;
    for (int d = 0; d < 64; d++) s = fmaf(cb[i*64+d], cb[i*64+d], s);
    cn[i] = s;
}

// pack input image (3 ch) -> packed [n][cg=2][256][256][8], channels 3..15 zero
__global__ __launch_bounds__(256) void pack_x(const float* __restrict__ x,
    unsigned short* __restrict__ PH, unsigned short* __restrict__ PL)
{
    int idx = blockIdx.x * 256 + threadIdx.x;      // 16*65536 total
    int n = idx >> 16, pix = idx & 65535;
    unsigned short h[8], l[8];
#pragma unroll
    for (int c = 0; c < 8; c++) { h[c] = 0; l[c] = 0; }
#pragma unroll
    for (int c = 0; c < 3; c++) {
        float v = x[((size_t)(n * 3 + c) << 16) + pix];
        fsplit(v, h[c], l[c]);
    }
    uint4 hv, lv;
    hv.x = h[0] | ((unsigned)h[1] << 16); hv.y = h[2] | ((unsigned)h[3] << 16);
    hv.z = h[4] | ((unsigned)h[5] << 16); hv.w = h[6] | ((unsigned)h[7] << 16);
    lv.x = l[0] | ((unsigned)l[1] << 16); lv.y = l[2] | ((unsigned)l[3] << 16);
    lv.z = l[4] | ((unsigned)l[5] << 16); lv.w = l[6] | ((unsigned)l[7] << 16);
    uint4 z4 = make_uint4(0, 0, 0, 0);
    size_t b0 = (((size_t)(n * 2) << 16) + pix) * 8;
    size_t b1 = (((size_t)(n * 2 + 1) << 16) + pix) * 8;
    *(uint4*)(PH + b0) = hv; *(uint4*)(PL + b0) = lv;
    *(uint4*)(PH + b1) = z4; *(uint4*)(PL + b1) = z4;
}

// ============ MFMA direct conv, packed bf16 hi/lo in/out ============
// Input: packed [n][cg][H][W][8]. LDS tile: 16B units (pos,kg), XOR-swizzled.
// Epilogue: optional fp32 NCHW store (WF32) + packed store (PACK, relu if PRELU).
template<int K,int S,int P,int CIP,int COUT,int HIN,int WIN,int HOUT,int WOUT,
         int TR,int TC,int WM,int WN,int CO2,int CO_PAD,
         bool PACK,bool PRELU,bool WF32,bool ROUT,bool RES>
__global__ __launch_bounds__(256) void conv_mfma(
    const unsigned short* __restrict__ inH, const unsigned short* __restrict__ inL,
    const unsigned short* __restrict__ wpH, const unsigned short* __restrict__ wpL,
    const float* __restrict__ bias, const float* __restrict__ res,
    float* __restrict__ outF, unsigned short* __restrict__ outPH,
    unsigned short* __restrict__ outPL)
{
    constexpr int IHT = (TR - 1) * S + K;
    constexpr int IW  = (TC - 1) * S + K;
    constexpr int PS  = IHT * IW;
    constexpr int UN  = PS * 2;
    constexpr int KK  = K * K;
    constexpr int NCH = CIP / 16;
    constexpr int CG  = CIP / 8;
    constexpr int CGO = (COUT + 7) / 8;
    constexpr int XB  = WOUT / TC;
    constexpr int REGU = (UN + 255) / 256;

    __shared__ uint4 lbH[UN];
    __shared__ uint4 lbL[UN];

    const int tid = threadIdx.x;
    const int bx  = blockIdx.x;
    const int r0  = (bx / XB) * TR;
    const int c0  = (bx % XB) * TC;
    const int n   = blockIdx.z;

    const int l  = tid & 63, wv = tid >> 6;
    const int wm = wv / WN, wn = wv % WN;
    const int ln = l & 31, kg = l >> 5;
    const int q  = wn * 32 + ln;
    const int lr = q / TC, lc = q % TC;

    const int iy0 = r0 * S - P, ix0 = c0 * S - P;
    const size_t inb = (size_t)n * CG * HIN * WIN;

    f32x16 acc[CO2][2];
#pragma unroll
    for (int g = 0; g < CO2; g++) { acc[g][0] = (f32x16){}; acc[g][1] = (f32x16){}; }

    auto unit_load = [&](int u, int cgb, uint4& hv, uint4& lv){
        int kgu = u & 1, pos = u >> 1;
        int py = pos / IW, px = pos - py * IW;
        int gy = iy0 + py, gx = ix0 + px;
        bool ok = ((unsigned)gy < (unsigned)HIN) && ((unsigned)gx < (unsigned)WIN);
        hv = make_uint4(0,0,0,0); lv = hv;
        if (ok) {
            size_t a = (inb + ((size_t)(cgb + kgu) * HIN + gy) * WIN + gx) * 8;
            hv = *(const uint4*)(inH + a);
            lv = *(const uint4*)(inL + a);
        }
    };

    auto stage_direct = [&](int kc){
        for (int idx = tid; idx < UN; idx += 256) {
            uint4 hv, lv;
            unit_load(idx, kc * 2, hv, lv);
            lbH[swzu(idx)] = hv;
            lbL[swzu(idx)] = lv;
        }
    };

    uint4 rvH[REGU], rvL[REGU];
    auto load_regs = [&](int kc){
#pragma unroll
        for (int rr = 0; rr < REGU; rr++) {
            int idx = tid + rr * 256;
            uint4 hv = make_uint4(0,0,0,0), lv = hv;
            if (idx < UN) unit_load(idx, kc * 2, hv, lv);
            rvH[rr] = hv; rvL[rr] = lv;
        }
    };
    auto write_regs = [&](){
#pragma unroll
        for (int rr = 0; rr < REGU; rr++) {
            int idx = tid + rr * 256;
            if (idx < UN) { lbH[swzu(idx)] = rvH[rr]; lbL[swzu(idx)] = rvL[rr]; }
        }
    };

    auto compute = [&](int kc){
#pragma unroll
        for (int t = 0; t < KK; t++) {
            const int ky = t / K, kx = t % K;
            const int u = ((lr * S + ky) * IW + lc * S + kx) * 2 + kg;
            bf16x8 bH = *(const bf16x8*)&lbH[swzu(u)];
            bf16x8 bL = *(const bf16x8*)&lbL[swzu(u)];
#pragma unroll
            for (int g = 0; g < CO2; g++) {
                const int coA = (wm * CO2 + g) * 32 + ln;
                const size_t wo = ((size_t)t * CO_PAD + coA) * CIP + kc * 16 + kg * 8;
                bf16x8 aH = *(const bf16x8*)(wpH + wo);
                bf16x8 aL = *(const bf16x8*)(wpL + wo);
                acc[g][0] = __builtin_amdgcn_mfma_f32_32x32x16_bf16(aH, bH, acc[g][0], 0, 0, 0);
                acc[g][1] = __builtin_amdgcn_mfma_f32_32x32x16_bf16(aH, bL, acc[g][1], 0, 0, 0);
                acc[g][1] = __builtin_amdgcn_mfma_f32_32x32x16_bf16(aL, bH, acc[g][1], 0, 0, 0);
            }
        }
    };

    stage_direct(0);
    __syncthreads();
    for (int kc = 0; kc < NCH; kc++) {
        const bool more = (kc + 1 < NCH);
        if (more) load_regs(kc + 1);
        compute(kc);
        if (more) {
            __syncthreads();
            write_regs();
            __syncthreads();
        }
    }

    const int gy = r0 + lr, gx = c0 + lc;
    const size_t HWo = (size_t)HOUT * WOUT;
#pragma unroll
    for (int g = 0; g < CO2; g++) {
        const int co32 = (wm * CO2 + g) * 32;
#pragma unroll
        for (int rq = 0; rq < 4; rq++) {
            const int cb4 = co32 + 8 * rq + 4 * kg;
            float v[4];
#pragma unroll
            for (int i = 0; i < 4; i++) {
                const int r = rq * 4 + i;
                const int co = cb4 + i;
                float bv = (co < COUT) ? bias[co] : 0.f;
                float vv = acc[g][0][r] + acc[g][1][r] + bv;
                if (RES && co < COUT)
                    vv += res[((size_t)n * COUT + co) * HWo + (size_t)gy * WOUT + gx];
                if (ROUT) vv = fmaxf(vv, 0.f);
                if (WF32 && co < COUT)
                    outF[((size_t)n * COUT + co) * HWo + (size_t)gy * WOUT + gx] = vv;
                v[i] = vv;
            }
            if (PACK) {
                u64t uh = 0, ul = 0;
#pragma unroll
                for (int i = 0; i < 4; i++) {
                    float pv = PRELU ? fmaxf(v[i], 0.f) : v[i];
                    unsigned short ph, pl;
                    fsplit(pv, ph, pl);
                    uh |= (u64t)ph << (16 * i);
                    ul |= (u64t)pl << (16 * i);
                }
                size_t pa = (((size_t)n * CGO + (co32 >> 3) + rq) * HOUT + gy) * (size_t)WOUT * 8
                          + (size_t)gx * 8 + 4 * kg;
                *(u64t*)(outPH + pa) = uh;
                *(u64t*)(outPL + pa) = ul;
            }
        }
    }
}

// ============ MFMA transpose conv k=4 s=2 p=1, packed in/out ============
// Block: one out row oy x one 128-wide x-half; 4 waves = 2 parities x 2 x-blocks.
template<int CIP,int COUT,int HIN,int WIN,int CO2,int CO_PAD,
         bool PACK,bool WF32,bool ROUT>
__global__ __launch_bounds__(256) void convt_mfma(
    const unsigned short* __restrict__ inH, const unsigned short* __restrict__ inL,
    const unsigned short* __restrict__ wpH, const unsigned short* __restrict__ wpL,
    const float* __restrict__ bias, float* __restrict__ outF,
    unsigned short* __restrict__ outPH, unsigned short* __restrict__ outPL)
{
    constexpr int HOUT = 2 * HIN, WOUT = 2 * WIN;
    constexpr int XHN  = WOUT / 128;
    constexpr int PS   = 2 * 68;
    constexpr int UN   = PS * 2;
    constexpr int NCH  = CIP / 16;
    constexpr int CG   = CIP / 8;
    constexpr int CGO  = (COUT + 7) / 8;
    constexpr int REGU = (UN + 255) / 256;

    __shared__ uint4 lbH[UN];
    __shared__ uint4 lbL[UN];

    const int tid = threadIdx.x;
    const int oy  = blockIdx.x / XHN;
    const int xh  = blockIdx.x % XHN;
    const int n   = blockIdx.z;

    const int ky0 = oy & 1;
    const int iyb = ((oy + ky0) >> 1) - 1;

    const int l  = tid & 63, wv = tid >> 6;
    const int p  = wv & 1, xb = wv >> 1;
    const int ln = l & 31, kg = l >> 5;

    const size_t inb = (size_t)n * CG * HIN * WIN;

    f32x16 acc[CO2][2];
#pragma unroll
    for (int g = 0; g < CO2; g++) { acc[g][0] = (f32x16){}; acc[g][1] = (f32x16){}; }

    auto unit_load = [&](int u, int cgb, uint4& hv, uint4& lv){
        int kgu = u & 1, pos = u >> 1;
        int rr = pos / 68, cc = pos - rr * 68;
        int gy = iyb + rr, gx = xh * 64 + cc - 1;
        bool ok = ((unsigned)gy < (unsigned)HIN) && ((unsigned)gx < (unsigned)WIN);
        hv = make_uint4(0,0,0,0); lv = hv;
        if (ok) {
            size_t a = (inb + ((size_t)(cgb + kgu) * HIN + gy) * WIN + gx) * 8;
            hv = *(const uint4*)(inH + a);
            lv = *(const uint4*)(inL + a);
        }
    };

    auto stage_direct = [&](int kc){
        for (int idx = tid; idx < UN; idx += 256) {
            uint4 hv, lv;
            unit_load(idx, kc * 2, hv, lv);
            lbH[swzu(idx)] = hv;
            lbL[swzu(idx)] = lv;
        }
    };

    uint4 rvH[REGU], rvL[REGU];
    auto load_regs = [&](int kc){
#pragma unroll
        for (int rr = 0; rr < REGU; rr++) {
            int idx = tid + rr * 256;
            uint4 hv = make_uint4(0,0,0,0), lv = hv;
            if (idx < UN) unit_load(idx, kc * 2, hv, lv);
            rvH[rr] = hv; rvL[rr] = lv;
        }
    };
    auto write_regs = [&](){
#pragma unroll
        for (int rr = 0; rr < REGU; rr++) {
            int idx = tid + rr * 256;
            if (idx < UN) { lbH[swzu(idx)] = rvH[rr]; lbL[swzu(idx)] = rvL[rr]; }
        }
    };

    auto compute = [&](int kc){
#pragma unroll
        for (int ty = 0; ty < 2; ty++)
#pragma unroll
        for (int tx = 0; tx < 2; tx++) {
            const int widx = (ky0 + 2 * ty) * 4 + (p + 2 * tx);
            const int u = (ty * 68 + xb * 32 + ln + p + tx) * 2 + kg;
            bf16x8 bH = *(const bf16x8*)&lbH[swzu(u)];
            bf16x8 bL = *(const bf16x8*)&lbL[swzu(u)];
#pragma unroll
            for (int g = 0; g < CO2; g++) {
                const int coA = g * 32 + ln;
                const size_t wo = ((size_t)widx * CO_PAD + coA) * CIP + kc * 16 + kg * 8;
                bf16x8 aH = *(const bf16x8*)(wpH + wo);
                bf16x8 aL = *(const bf16x8*)(wpL + wo);
                acc[g][0] = __builtin_amdgcn_mfma_f32_32x32x16_bf16(aH, bH, acc[g][0], 0, 0, 0);
                acc[g][1] = __builtin_amdgcn_mfma_f32_32x32x16_bf16(aH, bL, acc[g][1], 0, 0, 0);
                acc[g][1] = __builtin_amdgcn_mfma_f32_32x32x16_bf16(aL, bH, acc[g][1], 0, 0, 0);
            }
        }
    };

    stage_direct(0);
    __syncthreads();
    for (int kc = 0; kc < NCH; kc++) {
        const bool more = (kc + 1 < NCH);
        if (more) load_regs(kc + 1);
        compute(kc);
        if (more) {
            __syncthreads();
            write_regs();
            __syncthreads();
        }
    }

    const int ox = xh * 128 + p + 2 * (xb * 32 + ln);
    const size_t HWo = (size_t)HOUT * WOUT;
#pragma unroll
    for (int g = 0; g < CO2; g++) {
        const int co32 = g * 32;
#pragma unroll
        for (int rq = 0; rq < 4; rq++) {
            const int cb4 = co32 + 8 * rq + 4 * kg;
            float v[4];
#pragma unroll
            for (int i = 0; i < 4; i++) {
                const int r = rq * 4 + i;
                const int co = cb4 + i;
                float bv = (co < COUT) ? bias[co] : 0.f;
                float vv = acc[g][0][r] + acc[g][1][r] + bv;
                if (ROUT) vv = fmaxf(vv, 0.f);
                if (WF32 && co < COUT)
                    outF[((size_t)n * COUT + co) * HWo + (size_t)oy * WOUT + ox] = vv;
                v[i] = vv;
            }
            if (PACK) {
                u64t uh = 0, ul = 0;
#pragma unroll
                for (int i = 0; i < 4; i++) {
                    unsigned short ph, pl;
                    fsplit(v[i], ph, pl);
                    uh |= (u64t)ph << (16 * i);
                    ul |= (u64t)pl << (16 * i);
                }
                size_t pa = (((size_t)n * CGO + (co32 >> 3) + rq) * HOUT + oy) * (size_t)WOUT * 8
                          + (size_t)ox * 8 + 4 * kg;
                *(u64t*)(outPH + pa) = uh;
                *(u64t*)(outPL + pa) = ul;
            }
        }
    }
}

// ================= VQ via MFMA (packed z in, packed q out) =================
__global__ __launch_bounds__(256) void vq_mfma(
    const unsigned short* __restrict__ zPH, const unsigned short* __restrict__ zPL,
    const unsigned short* __restrict__ cbH, const unsigned short* __restrict__ cbL,
    const float* __restrict__ cnorm,
    unsigned short* __restrict__ qPH, unsigned short* __restrict__ qPL,
    float* __restrict__ ssep, int* __restrict__ hist)
{
    __shared__ unsigned short zH[128 * 72];
    __shared__ unsigned short zL[128 * 72];
    __shared__ float cnl[512];
    __shared__ int   hl[512];

    const int tid = threadIdx.x;
    const int blk = blockIdx.x;

    for (int i = tid; i < 512; i += 256) { cnl[i] = cnorm[i]; hl[i] = 0; }

    for (int idx = tid; idx < 1024; idx += 256) {
        int tok = idx >> 3, cg = idx & 7;
        int t = blk * 128 + tok;
        int n = t >> 12, pix = t & 4095;
        size_t a = (((size_t)(n * 8 + cg)) * 4096 + pix) * 8;
        *(uint4*)&zH[tok * 72 + cg * 8] = *(const uint4*)(zPH + a);
        *(uint4*)&zL[tok * 72 + cg * 8] = *(const uint4*)(zPL + a);
    }
    __syncthreads();

    const int l  = tid & 63, wv = tid >> 6;
    const int ln = l & 31, kg = l >> 5;
    const int tok = wv * 32 + ln;

    float xn = 0.f;
#pragma unroll
    for (int j8 = 0; j8 < 8; j8++) {
        bf16x8 vH = *(const bf16x8*)&zH[tok * 72 + j8 * 8];
        bf16x8 vL = *(const bf16x8*)&zL[tok * 72 + j8 * 8];
#pragma unroll
        for (int j = 0; j < 8; j++) {
            float xv = bf2f((unsigned short)vH[j]) + bf2f((unsigned short)vL[j]);
            xn = fmaf(xv, xv, xn);
        }
    }

    float bm = 3.4e38f; int bidx = 0;
    for (int cg = 0; cg < 16; cg++) {
        f32x16 a0 = {}, a1 = {};
#pragma unroll
        for (int ks = 0; ks < 4; ks++) {
            const size_t wo = ((size_t)(cg * 32 + ln)) * 64 + ks * 16 + kg * 8;
            bf16x8 aH = *(const bf16x8*)(cbH + wo);
            bf16x8 aL = *(const bf16x8*)(cbL + wo);
            bf16x8 bH = *(const bf16x8*)&zH[tok * 72 + ks * 16 + kg * 8];
            bf16x8 bL = *(const bf16x8*)&zL[tok * 72 + ks * 16 + kg * 8];
            a0 = __builtin_amdgcn_mfma_f32_32x32x16_bf16(aH, bH, a0, 0, 0, 0);
            a1 = __builtin_amdgcn_mfma_f32_32x32x16_bf16(aH, bL, a1, 0, 0, 0);
            a1 = __builtin_amdgcn_mfma_f32_32x32x16_bf16(aL, bH, a1, 0, 0, 0);
        }
#pragma unroll
        for (int r = 0; r < 16; r++) {
            int m    = (r & 3) + 8 * (r >> 2) + 4 * kg;   // ascending in r
            int code = cg * 32 + m;
            float s  = a0[r] + a1[r];
            float dm = cnl[code] - 2.f * s;
            if (dm < bm) { bm = dm; bidx = code; }
        }
    }

    float bm2 = __shfl_xor(bm, 32);
    int   bi2 = __shfl_xor(bidx, 32);
    if (bm2 < bm || (bm2 == bm && bi2 < bidx)) { bm = bm2; bidx = bi2; }

    // packed q gather from packed codebook
    {
        int t = blk * 128 + tok;
        int n = t >> 12, pix = t & 4095;
#pragma unroll
        for (int cgl = 0; cgl < 4; cgl++) {
            int cg = kg * 4 + cgl;
            uint4 hv = *(const uint4*)(cbH + (size_t)bidx * 64 + cg * 8);
            uint4 lv = *(const uint4*)(cbL + (size_t)bidx * 64 + cg * 8);
            size_t a = (((size_t)(n * 8 + cg)) * 4096 + pix) * 8;
            *(uint4*)(qPH + a) = hv;
            *(uint4*)(qPL + a) = lv;
        }
    }

    float bestd = xn + bm;
    float c = (kg == 0) ? bestd : 0.f;
#pragma unroll
    for (int o = 32; o > 0; o >>= 1) c += __shfl_down(c, o, 64);
    if (l == 0) ssep[blk * 4 + wv] = c;
    if (kg == 0) atomicAdd(&hl[bidx], 1);
    __syncthreads();
    for (int i = tid; i < 512; i += 256) if (hl[i] > 0) atomicAdd(&hist[i], hl[i]);
}

__global__ void vq_init(int* hist)
{
    for (int i = threadIdx.x; i < 512; i += 256) hist[i] = 0;
}

__global__ __launch_bounds__(256) void vq_finalize(
    const float* __restrict__ ssep, const int* __restrict__ hist,
    float* __restrict__ o_loss, float* __restrict__ o_perp)
{
    __shared__ float red[256];
    const int tid = threadIdx.x;
    float h = 0.f;
    for (int i = tid; i < 512; i += 256) {
        float p = (float)hist[i] * (1.0f / 65536.0f);
        h -= p * logf(p + 1e-10f);
    }
    red[tid] = h;
    __syncthreads();
    for (int st = 128; st > 0; st >>= 1) {
        if (tid < st) red[tid] += red[tid + st];
        __syncthreads();
    }
    const float H = red[0];
    __syncthreads();
    float s = 0.f;
    for (int i = tid; i < 2048; i += 256) s += ssep[i];
    red[tid] = s;
    __syncthreads();
    for (int st = 128; st > 0; st >>= 1) {
        if (tid < st) red[tid] += red[tid + st];
        __syncthreads();
    }
    if (tid == 0) {
        *o_loss = 1.25f * red[0] / 4194304.0f;
        *o_perp = expf(H);
    }
}

extern "C" void kernel_launch(void* const* d_in, const int* in_sizes, int n_in,
                              void* d_out, int out_size, void* d_ws, size_t ws_size,
                              hipStream_t stream)
{
    const float* x       = (const float*)d_in[0];
    const float* enc_w1  = (const float*)d_in[1];
    const float* enc_b1  = (const float*)d_in[2];
    const float* enc_w2  = (const float*)d_in[3];
    const float* enc_b2  = (const float*)d_in[4];
    const float* enc_w3  = (const float*)d_in[5];
    const float* enc_b3  = (const float*)d_in[6];
    const float* enc_rw3 = (const float*)d_in[7];
    const float* enc_rb3 = (const float*)d_in[8];
    const float* enc_rw1 = (const float*)d_in[9];
    const float* enc_rb1 = (const float*)d_in[10];
    const float* pre_w   = (const float*)d_in[11];
    const float* pre_b   = (const float*)d_in[12];
    const float* cb      = (const float*)d_in[13];
    const float* dec_w1  = (const float*)d_in[14];
    const float* dec_b1  = (const float*)d_in[15];
    const float* dec_rw3 = (const float*)d_in[16];
    const float* dec_rb3 = (const float*)d_in[17];
    const float* dec_rw1 = (const float*)d_in[18];
    const float* dec_rb1 = (const float*)d_in[19];
    const float* dw1     = (const float*)d_in[20];
    const float* db1     = (const float*)d_in[21];
    const float* dw2     = (const float*)d_in[22];
    const float* db2     = (const float*)d_in[23];

    float* o      = (float*)d_out;
    float* loss_p = o;
    float* recon  = o + 1;
    float* perp_p = o + 1 + 16 * 3 * 256 * 256;

    // ws: R1(H,L) 16.78M shorts each | R2(H,L) | Cf 8.39M f32 | SSE 2048 | HIST | weights
    unsigned short* R1H = (unsigned short*)d_ws;
    unsigned short* R1L = R1H + 16777216;
    unsigned short* R2H = R1L + 16777216;
    unsigned short* R2L = R2H + 16777216;
    float* Cf  = (float*)(R2L + 16777216);
    float* SSE = Cf + 8388608;
    int*   HIST = (int*)(SSE + 2048);

    // packed activation aliases (lifetime-disjoint)
    unsigned short *xPH = R1H,            *xPL = R1L;             // until enc1
    unsigned short *BPH = R1H,            *BPL = R1L;             // enc2->enc3
    unsigned short *zPH = R1H + 8388608,  *zPL = R1L + 8388608;   // pre->vq
    unsigned short *DtPH = R1H + 12582912,*DtPL = R1L + 12582912; // res temps
    unsigned short *dAPH = R1H,           *dAPL = R1L;            // convt1->convt2
    unsigned short *APH = R2H,            *APL = R2L;             // enc1->enc2
    unsigned short *CPH = R2H,            *CPL = R2L;             // relu(C), enc3..convt1
    unsigned short *qPH = R2H + 8388608,  *qPL = R2L + 8388608;   // vq->dec1

    unsigned short* wp_cur = (unsigned short*)(((size_t)(HIST + 512) + 31) & ~(size_t)31);
    auto carve = [&](size_t n_us) {
        unsigned short* p = wp_cur;
        wp_cur += ((n_us + 15) & ~(size_t)15);
        return p;
    };
    auto PK = [&](const float* w, unsigned short* hi, unsigned short* lo,
                  int Co, int Ci, int KK, int CoP, int CiP) {
        int tot = KK * CoP * CiP;
        pack_w<<<dim3((tot + 255) / 256), dim3(256), 0, stream>>>(w, hi, lo, Co, Ci, KK, CoP, CiP);
    };

    unsigned short *e1H = carve(16*64*16),  *e1L = carve(16*64*16);
    unsigned short *e2H = carve(16*128*64), *e2L = carve(16*128*64);
    unsigned short *e3H = carve(9*128*128), *e3L = carve(9*128*128);
    unsigned short *er3aH = carve(9*32*128), *er3aL = carve(9*32*128);
    unsigned short *er3bH = carve(9*32*128), *er3bL = carve(9*32*128);
    unsigned short *er1aH = carve(128*32),   *er1aL = carve(128*32);
    unsigned short *er1bH = carve(128*32),   *er1bL = carve(128*32);
    unsigned short *preH = carve(64*128),    *preL = carve(64*128);
    unsigned short *d1H  = carve(9*128*64),  *d1L  = carve(9*128*64);
    unsigned short *dr3aH = carve(9*32*128), *dr3aL = carve(9*32*128);
    unsigned short *dr3bH = carve(9*32*128), *dr3bL = carve(9*32*128);
    unsigned short *dr1aH = carve(128*32),   *dr1aL = carve(128*32);
    unsigned short *dr1bH = carve(128*32),   *dr1bL = carve(128*32);
    unsigned short *ct1H = carve(16*64*128), *ct1L = carve(16*64*128);
    unsigned short *ct2H = carve(16*32*64),  *ct2L = carve(16*32*64);
    unsigned short *cbH  = carve(512*64),    *cbL  = carve(512*64);
    float* CN = (float*)carve(1024);

    PK(enc_w1, e1H, e1L, 64, 3, 16, 64, 16);
    PK(enc_w2, e2H, e2L, 128, 64, 16, 128, 64);
    PK(enc_w3, e3H, e3L, 128, 128, 9, 128, 128);
    PK(enc_rw3,             er3aH, er3aL, 32, 128, 9, 32, 128);
    PK(enc_rw3 + 32*128*9,  er3bH, er3bL, 32, 128, 9, 32, 128);
    PK(enc_rw1,             er1aH, er1aL, 128, 32, 1, 128, 32);
    PK(enc_rw1 + 128*32,    er1bH, er1bL, 128, 32, 1, 128, 32);
    PK(pre_w, preH, preL, 64, 128, 1, 64, 128);
    PK(dec_w1, d1H, d1L, 128, 64, 9, 128, 64);
    PK(dec_rw3,             dr3aH, dr3aL, 32, 128, 9, 32, 128);
    PK(dec_rw3 + 32*128*9,  dr3bH, dr3bL, 32, 128, 9, 32, 128);
    PK(dec_rw1,             dr1aH, dr1aL, 128, 32, 1, 128, 32);
    PK(dec_rw1 + 128*32,    dr1bH, dr1bL, 128, 32, 1, 128, 32);
    PK(dw1, ct1H, ct1L, 64, 128, 16, 64, 128);
    PK(dw2, ct2H, ct2L, 3, 64, 16, 32, 64);
    PK(cb,  cbH,  cbL,  512, 64, 1, 512, 64);
    cb_norm<<<dim3(2), dim3(256), 0, stream>>>(cb, CN);
    pack_x<<<dim3(4096), dim3(256), 0, stream>>>(x, xPH, xPL);

    const int N = 16;

    // ---- encoder ----
    conv_mfma<4,2,1, 16,64, 256,256, 128,128, 1,64, 2,2,1, 64,  true,false,false,true,false>
        <<<dim3(256,1,N),256,0,stream>>>(xPH,xPL, e1H,e1L, enc_b1, nullptr, nullptr, APH,APL);
    conv_mfma<4,2,1, 64,128, 128,128, 64,64, 1,64, 2,2,2, 128, true,false,false,true,false>
        <<<dim3(64,1,N),256,0,stream>>>(APH,APL, e2H,e2L, enc_b2, nullptr, nullptr, BPH,BPL);
    conv_mfma<3,1,1, 128,128, 64,64, 64,64, 1,64, 2,2,2, 128, true,true,true,false,false>
        <<<dim3(64,1,N),256,0,stream>>>(BPH,BPL, e3H,e3L, enc_b3, nullptr, Cf, CPH,CPL);
    conv_mfma<3,1,1, 128,32, 64,64, 64,64, 2,64, 1,4,1, 32,   true,true,false,false,false>
        <<<dim3(32,1,N),256,0,stream>>>(CPH,CPL, er3aH,er3aL, enc_rb3, nullptr, nullptr, DtPH,DtPL);
    conv_mfma<1,1,0, 32,128, 64,64, 64,64, 1,64, 2,2,2, 128,  true,true,true,false,true>
        <<<dim3(64,1,N),256,0,stream>>>(DtPH,DtPL, er1aH,er1aL, enc_rb1, Cf, Cf, CPH,CPL);
    conv_mfma<3,1,1, 128,32, 64,64, 64,64, 2,64, 1,4,1, 32,   true,true,false,false,false>
        <<<dim3(32,1,N),256,0,stream>>>(CPH,CPL, er3bH,er3bL, enc_rb3 + 32, nullptr, nullptr, DtPH,DtPL);
    conv_mfma<1,1,0, 32,128, 64,64, 64,64, 1,64, 2,2,2, 128,  true,true,true,false,true>
        <<<dim3(64,1,N),256,0,stream>>>(DtPH,DtPL, er1bH,er1bL, enc_rb1 + 128, Cf, Cf, CPH,CPL);
    conv_mfma<1,1,0, 128,64, 64,64, 64,64, 1,64, 2,2,1, 64,   true,false,false,false,false>
        <<<dim3(64,1,N),256,0,stream>>>(CPH,CPL, preH,preL, pre_b, nullptr, nullptr, zPH,zPL);

    // ---- VQ ----
    vq_init<<<dim3(1), dim3(256), 0, stream>>>(HIST);
    vq_mfma<<<dim3(512), dim3(256), 0, stream>>>(zPH,zPL, cbH,cbL, CN, qPH,qPL, SSE, HIST);
    vq_finalize<<<dim3(1), dim3(256), 0, stream>>>(SSE, HIST, loss_p, perp_p);

    // ---- decoder ----
    conv_mfma<3,1,1, 64,128, 64,64, 64,64, 1,64, 2,2,2, 128,  true,true,true,false,false>
        <<<dim3(64,1,N),256,0,stream>>>(qPH,qPL, d1H,d1L, dec_b1, nullptr, Cf, CPH,CPL);
    conv_mfma<3,1,1, 128,32, 64,64, 64,64, 2,64, 1,4,1, 32,   true,true,false,false,false>
        <<<dim3(32,1,N),256,0,stream>>>(CPH,CPL, dr3aH,dr3aL, dec_rb3, nullptr, nullptr, DtPH,DtPL);
    conv_mfma<1,1,0, 32,128, 64,64, 64,64, 1,64, 2,2,2, 128,  true,true,true,false,true>
        <<<dim3(64,1,N),256,0,stream>>>(DtPH,DtPL, dr1aH,dr1aL, dec_rb1, Cf, Cf, CPH,CPL);
    conv_mfma<3,1,1, 128,32, 64,64, 64,64, 2,64, 1,4,1, 32,   true,true,false,false,false>
        <<<dim3(32,1,N),256,0,stream>>>(CPH,CPL, dr3bH,dr3bL, dec_rb3 + 32, nullptr, nullptr, DtPH,DtPL);
    conv_mfma<1,1,0, 32,128, 64,64, 64,64, 1,64, 2,2,2, 128,  true,true,true,false,true>
        <<<dim3(64,1,N),256,0,stream>>>(DtPH,DtPL, dr1bH,dr1bL, dec_rb1 + 128, Cf, Cf, CPH,CPL);
    convt_mfma<128,64, 64,64, 2, 64,  true,false,true>
        <<<dim3(128,1,N),256,0,stream>>>(CPH,CPL, ct1H,ct1L, db1, nullptr, dAPH,dAPL);
    convt_mfma<64,3, 128,128, 1, 32,  false,true,false>
        <<<dim3(512,1,N),256,0,stream>>>(dAPH,dAPL, ct2H,ct2L, db2, recon, nullptr,nullptr);
}

// Round 8
// 1112.835 us; speedup vs baseline: 6.2094x; 1.0459x over previous
//
#include <hip/hip_runtime.h>

typedef __attribute__((ext_vector_type(8)))  short bf16x8;
typedef __attribute__((ext_vector_type(16))) float f32x16;
typedef unsigned long long u64t;

// bank-spread swizzle: permutes u mod 8 for lane-strides 1,2,4 (16B units)
__device__ __forceinline__ int swzu(int u)
{
    return u ^ (((u >> 3) & 1) | (((u >> 4) & 1) << 1));
}

// split fp32 -> (hi, lo) bf16 pair, RNE both
__device__ __forceinline__ void fsplit(float v, unsigned short& h, unsigned short& l)
{
    union { float f; unsigned u; } a; a.f = v;
    unsigned uh = a.u + 0x7fffu + ((a.u >> 16) & 1u);
    h = (unsigned short)(uh >> 16);
    union { float f; unsigned u; } hb; hb.u = (unsigned)h << 16;
    float r = v - hb.f;
    union { float f; unsigned u; } b; b.f = r;
    unsigned ul = b.u + 0x7fffu + ((b.u >> 16) & 1u);
    l = (unsigned short)(ul >> 16);
}

__device__ __forceinline__ float bf2f(unsigned short u)
{
    union { float f; unsigned v; } a; a.v = (unsigned)u << 16; return a.f;
}

// pack OIHW fp32 weights -> [tap][co_pad][ci_pad] bf16 hi/lo, zero-padded
__global__ void pack_w(const float* __restrict__ w, unsigned short* __restrict__ hi,
                       unsigned short* __restrict__ lo, int Cout, int Cin, int KK,
                       int CoP, int CiP)
{
    int i = blockIdx.x * 256 + threadIdx.x;
    int tot = KK * CoP * CiP;
    if (i >= tot) return;
    int t  = i / (CoP * CiP);
    int r  = i - t * (CoP * CiP);
    int co = r / CiP;
    int ci = r - co * CiP;
    float v = (co < Cout && ci < Cin) ? w[((size_t)co * Cin + ci) * KK + t] : 0.f;
    unsigned short h, l;
    fsplit(v, h, l);
    hi[i] = h; lo[i] = l;
}

__global__ void cb_norm(const float* __restrict__ cb, float* __restrict__ cn)
{
    int i = blockIdx.x * 256 + threadIdx.x;
    if (i >= 512) return;
    float s = 0.f;
    for (int d = 0; d < 64; d++) s = fmaf(cb[i*64+d], cb[i*64+d], s);
    cn[i] = s;
}

// pack input image (3 ch) -> packed [n][cg=2][256][256][8], channels 3..15 zero
__global__ __launch_bounds__(256) void pack_x(const float* __restrict__ x,
    unsigned short* __restrict__ PH, unsigned short* __restrict__ PL)
{
    int idx = blockIdx.x * 256 + threadIdx.x;      // 16*65536 total
    int n = idx >> 16, pix = idx & 65535;
    unsigned short h[8], l[8];
#pragma unroll
    for (int c = 0; c < 8; c++) { h[c] = 0; l[c] = 0; }
#pragma unroll
    for (int c = 0; c < 3; c++) {
        float v = x[((size_t)(n * 3 + c) << 16) + pix];
        fsplit(v, h[c], l[c]);
    }
    uint4 hv, lv;
    hv.x = h[0] | ((unsigned)h[1] << 16); hv.y = h[2] | ((unsigned)h[3] << 16);
    hv.z = h[4] | ((unsigned)h[5] << 16); hv.w = h[6] | ((unsigned)h[7] << 16);
    lv.x = l[0] | ((unsigned)l[1] << 16); lv.y = l[2] | ((unsigned)l[3] << 16);
    lv.z = l[4] | ((unsigned)l[5] << 16); lv.w = l[6] | ((unsigned)l[7] << 16);
    uint4 z4 = make_uint4(0, 0, 0, 0);
    size_t b0 = (((size_t)(n * 2) << 16) + pix) * 8;
    size_t b1 = (((size_t)(n * 2 + 1) << 16) + pix) * 8;
    *(uint4*)(PH + b0) = hv; *(uint4*)(PL + b0) = lv;
    *(uint4*)(PH + b1) = z4; *(uint4*)(PL + b1) = z4;
}

// ============ MFMA direct conv, packed bf16 hi/lo in/out ============
// blockIdx.y tiles couts by WM*CO2*32. A-operand (weights) double-buffered in
// registers one (tap,g)-step ahead. Input chunk in LDS, swizzled 16B units.
template<int K,int S,int P,int CIP,int COUT,int HIN,int WIN,int HOUT,int WOUT,
         int TR,int TC,int WM,int WN,int CO2,int CO_PAD,
         bool PACK,bool PRELU,bool WF32,bool ROUT,bool RES>
__global__ __launch_bounds__(256) void conv_mfma(
    const unsigned short* __restrict__ inH, const unsigned short* __restrict__ inL,
    const unsigned short* __restrict__ wpH, const unsigned short* __restrict__ wpL,
    const float* __restrict__ bias, const float* __restrict__ res,
    float* __restrict__ outF, unsigned short* __restrict__ outPH,
    unsigned short* __restrict__ outPL)
{
    constexpr int IHT = (TR - 1) * S + K;
    constexpr int IW  = (TC - 1) * S + K;
    constexpr int PS  = IHT * IW;
    constexpr int UN  = PS * 2;
    constexpr int KK  = K * K;
    constexpr int NCH = CIP / 16;
    constexpr int CG  = CIP / 8;
    constexpr int CGO = (COUT + 7) / 8;
    constexpr int XB  = WOUT / TC;
    constexpr int REGU = (UN + 255) / 256;

    __shared__ uint4 lbH[UN];
    __shared__ uint4 lbL[UN];

    const int tid = threadIdx.x;
    const int bx  = blockIdx.x;
    const int r0  = (bx / XB) * TR;
    const int c0  = (bx % XB) * TC;
    const int co0 = blockIdx.y * (WM * CO2 * 32);
    const int n   = blockIdx.z;

    const int l  = tid & 63, wv = tid >> 6;
    const int wm = wv / WN, wn = wv % WN;
    const int ln = l & 31, kg = l >> 5;
    const int q  = wn * 32 + ln;
    const int lr = q / TC, lc = q % TC;

    const int iy0 = r0 * S - P, ix0 = c0 * S - P;
    const size_t inb = (size_t)n * CG * HIN * WIN;

    f32x16 acc[CO2][2];
#pragma unroll
    for (int g = 0; g < CO2; g++) { acc[g][0] = (f32x16){}; acc[g][1] = (f32x16){}; }

    auto unit_load = [&](int u, int cgb, uint4& hv, uint4& lv){
        int kgu = u & 1, pos = u >> 1;
        int py = pos / IW, px = pos - py * IW;
        int gy = iy0 + py, gx = ix0 + px;
        bool ok = ((unsigned)gy < (unsigned)HIN) && ((unsigned)gx < (unsigned)WIN);
        hv = make_uint4(0,0,0,0); lv = hv;
        if (ok) {
            size_t a = (inb + ((size_t)(cgb + kgu) * HIN + gy) * WIN + gx) * 8;
            hv = *(const uint4*)(inH + a);
            lv = *(const uint4*)(inL + a);
        }
    };

    auto stage_direct = [&](int kc){
        for (int idx = tid; idx < UN; idx += 256) {
            uint4 hv, lv;
            unit_load(idx, kc * 2, hv, lv);
            lbH[swzu(idx)] = hv;
            lbL[swzu(idx)] = lv;
        }
    };

    uint4 rvH[REGU], rvL[REGU];
    auto load_regs = [&](int kc){
#pragma unroll
        for (int rr = 0; rr < REGU; rr++) {
            int idx = tid + rr * 256;
            uint4 hv = make_uint4(0,0,0,0), lv = hv;
            if (idx < UN) unit_load(idx, kc * 2, hv, lv);
            rvH[rr] = hv; rvL[rr] = lv;
        }
    };
    auto write_regs = [&](){
#pragma unroll
        for (int rr = 0; rr < REGU; rr++) {
            int idx = tid + rr * 256;
            if (idx < UN) { lbH[swzu(idx)] = rvH[rr]; lbL[swzu(idx)] = rvL[rr]; }
        }
    };

    auto compute = [&](int kc){
        bf16x8 aHb[2], aLb[2];
        bf16x8 bH, bL;
        auto loadA = [&](int step, int s){
            const int t = step / CO2, g = step % CO2;
            const int coA = co0 + (wm * CO2 + g) * 32 + ln;
            const size_t wo = ((size_t)t * CO_PAD + coA) * CIP + kc * 16 + kg * 8;
            aHb[s] = *(const bf16x8*)(wpH + wo);
            aLb[s] = *(const bf16x8*)(wpL + wo);
        };
        loadA(0, 0);
#pragma unroll
        for (int step = 0; step < KK * CO2; step++) {
            const int t = step / CO2, g = step % CO2;
            if (g == 0) {
                const int ky = t / K, kx = t % K;
                const int u = ((lr * S + ky) * IW + lc * S + kx) * 2 + kg;
                bH = *(const bf16x8*)&lbH[swzu(u)];
                bL = *(const bf16x8*)&lbL[swzu(u)];
            }
            if (step + 1 < KK * CO2) loadA(step + 1, (step + 1) & 1);
            const int s = step & 1;
            acc[g][0] = __builtin_amdgcn_mfma_f32_32x32x16_bf16(aHb[s], bH, acc[g][0], 0, 0, 0);
            acc[g][1] = __builtin_amdgcn_mfma_f32_32x32x16_bf16(aHb[s], bL, acc[g][1], 0, 0, 0);
            acc[g][1] = __builtin_amdgcn_mfma_f32_32x32x16_bf16(aLb[s], bH, acc[g][1], 0, 0, 0);
        }
    };

    stage_direct(0);
    __syncthreads();
    for (int kc = 0; kc < NCH; kc++) {
        const bool more = (kc + 1 < NCH);
        if (more) load_regs(kc + 1);
        compute(kc);
        if (more) {
            __syncthreads();
            write_regs();
            __syncthreads();
        }
    }

    const int gy = r0 + lr, gx = c0 + lc;
    const size_t HWo = (size_t)HOUT * WOUT;
#pragma unroll
    for (int g = 0; g < CO2; g++) {
        const int co32 = co0 + (wm * CO2 + g) * 32;
#pragma unroll
        for (int rq = 0; rq < 4; rq++) {
            const int cb4 = co32 + 8 * rq + 4 * kg;
            float v[4];
#pragma unroll
            for (int i = 0; i < 4; i++) {
                const int r = rq * 4 + i;
                const int co = cb4 + i;
                float bv = (co < COUT) ? bias[co] : 0.f;
                float vv = acc[g][0][r] + acc[g][1][r] + bv;
                if (RES && co < COUT)
                    vv += res[((size_t)n * COUT + co) * HWo + (size_t)gy * WOUT + gx];
                if (ROUT) vv = fmaxf(vv, 0.f);
                if (WF32 && co < COUT)
                    outF[((size_t)n * COUT + co) * HWo + (size_t)gy * WOUT + gx] = vv;
                v[i] = vv;
            }
            if (PACK) {
                u64t uh = 0, ul = 0;
#pragma unroll
                for (int i = 0; i < 4; i++) {
                    float pv = PRELU ? fmaxf(v[i], 0.f) : v[i];
                    unsigned short ph, pl;
                    fsplit(pv, ph, pl);
                    uh |= (u64t)ph << (16 * i);
                    ul |= (u64t)pl << (16 * i);
                }
                size_t pa = (((size_t)n * CGO + (co32 >> 3) + rq) * HOUT + gy) * (size_t)WOUT * 8
                          + (size_t)gx * 8 + 4 * kg;
                *(u64t*)(outPH + pa) = uh;
                *(u64t*)(outPL + pa) = ul;
            }
        }
    }
}

// ============ MFMA transpose conv k=4 s=2 p=1, packed in/out ============
// Block: one out row oy x one 128-wide x-half; 4 waves = 2 parities x 2 x-blocks.
// blockIdx.y tiles couts by CO2*32. A double-buffered in registers.
template<int CIP,int COUT,int HIN,int WIN,int CO2,int CO_PAD,
         bool PACK,bool WF32,bool ROUT>
__global__ __launch_bounds__(256) void convt_mfma(
    const unsigned short* __restrict__ inH, const unsigned short* __restrict__ inL,
    const unsigned short* __restrict__ wpH, const unsigned short* __restrict__ wpL,
    const float* __restrict__ bias, float* __restrict__ outF,
    unsigned short* __restrict__ outPH, unsigned short* __restrict__ outPL)
{
    constexpr int HOUT = 2 * HIN, WOUT = 2 * WIN;
    constexpr int XHN  = WOUT / 128;
    constexpr int PS   = 2 * 68;
    constexpr int UN   = PS * 2;
    constexpr int NCH  = CIP / 16;
    constexpr int CG   = CIP / 8;
    constexpr int CGO  = (COUT + 7) / 8;
    constexpr int REGU = (UN + 255) / 256;

    __shared__ uint4 lbH[UN];
    __shared__ uint4 lbL[UN];

    const int tid = threadIdx.x;
    const int oy  = blockIdx.x / XHN;
    const int xh  = blockIdx.x % XHN;
    const int co0 = blockIdx.y * (CO2 * 32);
    const int n   = blockIdx.z;

    const int ky0 = oy & 1;
    const int iyb = ((oy + ky0) >> 1) - 1;

    const int l  = tid & 63, wv = tid >> 6;
    const int p  = wv & 1, xb = wv >> 1;
    const int ln = l & 31, kg = l >> 5;

    const size_t inb = (size_t)n * CG * HIN * WIN;

    f32x16 acc[CO2][2];
#pragma unroll
    for (int g = 0; g < CO2; g++) { acc[g][0] = (f32x16){}; acc[g][1] = (f32x16){}; }

    auto unit_load = [&](int u, int cgb, uint4& hv, uint4& lv){
        int kgu = u & 1, pos = u >> 1;
        int rr = pos / 68, cc = pos - rr * 68;
        int gy = iyb + rr, gx = xh * 64 + cc - 1;
        bool ok = ((unsigned)gy < (unsigned)HIN) && ((unsigned)gx < (unsigned)WIN);
        hv = make_uint4(0,0,0,0); lv = hv;
        if (ok) {
            size_t a = (inb + ((size_t)(cgb + kgu) * HIN + gy) * WIN + gx) * 8;
            hv = *(const uint4*)(inH + a);
            lv = *(const uint4*)(inL + a);
        }
    };

    auto stage_direct = [&](int kc){
        for (int idx = tid; idx < UN; idx += 256) {
            uint4 hv, lv;
            unit_load(idx, kc * 2, hv, lv);
            lbH[swzu(idx)] = hv;
            lbL[swzu(idx)] = lv;
        }
    };

    uint4 rvH[REGU], rvL[REGU];
    auto load_regs = [&](int kc){
#pragma unroll
        for (int rr = 0; rr < REGU; rr++) {
            int idx = tid + rr * 256;
            uint4 hv = make_uint4(0,0,0,0), lv = hv;
            if (idx < UN) unit_load(idx, kc * 2, hv, lv);
            rvH[rr] = hv; rvL[rr] = lv;
        }
    };
    auto write_regs = [&](){
#pragma unroll
        for (int rr = 0; rr < REGU; rr++) {
            int idx = tid + rr * 256;
            if (idx < UN) { lbH[swzu(idx)] = rvH[rr]; lbL[swzu(idx)] = rvL[rr]; }
        }
    };

    auto compute = [&](int kc){
        bf16x8 aHb[2], aLb[2];
        bf16x8 bH, bL;
        auto loadA = [&](int step, int s){
            const int tt = step / CO2, g = step % CO2;
            const int widx = (ky0 + 2 * (tt >> 1)) * 4 + (p + 2 * (tt & 1));
            const int coA = co0 + g * 32 + ln;
            const size_t wo = ((size_t)widx * CO_PAD + coA) * CIP + kc * 16 + kg * 8;
            aHb[s] = *(const bf16x8*)(wpH + wo);
            aLb[s] = *(const bf16x8*)(wpL + wo);
        };
        loadA(0, 0);
#pragma unroll
        for (int step = 0; step < 4 * CO2; step++) {
            const int tt = step / CO2, g = step % CO2;
            if (g == 0) {
                const int ty = tt >> 1, tx = tt & 1;
                const int u = (ty * 68 + xb * 32 + ln + p + tx) * 2 + kg;
                bH = *(const bf16x8*)&lbH[swzu(u)];
                bL = *(const bf16x8*)&lbL[swzu(u)];
            }
            if (step + 1 < 4 * CO2) loadA(step + 1, (step + 1) & 1);
            const int s = step & 1;
            acc[g][0] = __builtin_amdgcn_mfma_f32_32x32x16_bf16(aHb[s], bH, acc[g][0], 0, 0, 0);
            acc[g][1] = __builtin_amdgcn_mfma_f32_32x32x16_bf16(aHb[s], bL, acc[g][1], 0, 0, 0);
            acc[g][1] = __builtin_amdgcn_mfma_f32_32x32x16_bf16(aLb[s], bH, acc[g][1], 0, 0, 0);
        }
    };

    stage_direct(0);
    __syncthreads();
    for (int kc = 0; kc < NCH; kc++) {
        const bool more = (kc + 1 < NCH);
        if (more) load_regs(kc + 1);
        compute(kc);
        if (more) {
            __syncthreads();
            write_regs();
            __syncthreads();
        }
    }

    const int ox = xh * 128 + p + 2 * (xb * 32 + ln);
    const size_t HWo = (size_t)HOUT * WOUT;
#pragma unroll
    for (int g = 0; g < CO2; g++) {
        const int co32 = co0 + g * 32;
#pragma unroll
        for (int rq = 0; rq < 4; rq++) {
            const int cb4 = co32 + 8 * rq + 4 * kg;
            float v[4];
#pragma unroll
            for (int i = 0; i < 4; i++) {
                const int r = rq * 4 + i;
                const int co = cb4 + i;
                float bv = (co < COUT) ? bias[co] : 0.f;
                float vv = acc[g][0][r] + acc[g][1][r] + bv;
                if (ROUT) vv = fmaxf(vv, 0.f);
                if (WF32 && co < COUT)
                    outF[((size_t)n * COUT + co) * HWo + (size_t)oy * WOUT + ox] = vv;
                v[i] = vv;
            }
            if (PACK) {
                u64t uh = 0, ul = 0;
#pragma unroll
                for (int i = 0; i < 4; i++) {
                    unsigned short ph, pl;
                    fsplit(v[i], ph, pl);
                    uh |= (u64t)ph << (16 * i);
                    ul |= (u64t)pl << (16 * i);
                }
                size_t pa = (((size_t)n * CGO + (co32 >> 3) + rq) * HOUT + oy) * (size_t)WOUT * 8
                          + (size_t)ox * 8 + 4 * kg;
                *(u64t*)(outPH + pa) = uh;
                *(u64t*)(outPL + pa) = ul;
            }
        }
    }
}

// ================= VQ via MFMA (packed z in, packed q out) =================
__global__ __launch_bounds__(256) void vq_mfma(
    const unsigned short* __restrict__ zPH, const unsigned short* __restrict__ zPL,
    const unsigned short* __restrict__ cbH, const unsigned short* __restrict__ cbL,
    const float* __restrict__ cnorm,
    unsigned short* __restrict__ qPH, unsigned short* __restrict__ qPL,
    float* __restrict__ ssep, int* __restrict__ hist)
{
    __shared__ unsigned short zH[128 * 72];
    __shared__ unsigned short zL[128 * 72];
    __shared__ float cnl[512];
    __shared__ int   hl[512];

    const int tid = threadIdx.x;
    const int blk = blockIdx.x;

    for (int i = tid; i < 512; i += 256) { cnl[i] = cnorm[i]; hl[i] = 0; }

    for (int idx = tid; idx < 1024; idx += 256) {
        int tok = idx >> 3, cg = idx & 7;
        int t = blk * 128 + tok;
        int n = t >> 12, pix = t & 4095;
        size_t a = (((size_t)(n * 8 + cg)) * 4096 + pix) * 8;
        *(uint4*)&zH[tok * 72 + cg * 8] = *(const uint4*)(zPH + a);
        *(uint4*)&zL[tok * 72 + cg * 8] = *(const uint4*)(zPL + a);
    }
    __syncthreads();

    const int l  = tid & 63, wv = tid >> 6;
    const int ln = l & 31, kg = l >> 5;
    const int tok = wv * 32 + ln;

    float xn = 0.f;
#pragma unroll
    for (int j8 = 0; j8 < 8; j8++) {
        bf16x8 vH = *(const bf16x8*)&zH[tok * 72 + j8 * 8];
        bf16x8 vL = *(const bf16x8*)&zL[tok * 72 + j8 * 8];
#pragma unroll
        for (int j = 0; j < 8; j++) {
            float xv = bf2f((unsigned short)vH[j]) + bf2f((unsigned short)vL[j]);
            xn = fmaf(xv, xv, xn);
        }
    }

    float bm = 3.4e38f; int bidx = 0;
    for (int cg = 0; cg < 16; cg++) {
        f32x16 a0 = {}, a1 = {};
#pragma unroll
        for (int ks = 0; ks < 4; ks++) {
            const size_t wo = ((size_t)(cg * 32 + ln)) * 64 + ks * 16 + kg * 8;
            bf16x8 aH = *(const bf16x8*)(cbH + wo);
            bf16x8 aL = *(const bf16x8*)(cbL + wo);
            bf16x8 bH = *(const bf16x8*)&zH[tok * 72 + ks * 16 + kg * 8];
            bf16x8 bL = *(const bf16x8*)&zL[tok * 72 + ks * 16 + kg * 8];
            a0 = __builtin_amdgcn_mfma_f32_32x32x16_bf16(aH, bH, a0, 0, 0, 0);
            a1 = __builtin_amdgcn_mfma_f32_32x32x16_bf16(aH, bL, a1, 0, 0, 0);
            a1 = __builtin_amdgcn_mfma_f32_32x32x16_bf16(aL, bH, a1, 0, 0, 0);
        }
#pragma unroll
        for (int r = 0; r < 16; r++) {
            int m    = (r & 3) + 8 * (r >> 2) + 4 * kg;   // ascending in r
            int code = cg * 32 + m;
            float s  = a0[r] + a1[r];
            float dm = cnl[code] - 2.f * s;
            if (dm < bm) { bm = dm; bidx = code; }
        }
    }

    float bm2 = __shfl_xor(bm, 32);
    int   bi2 = __shfl_xor(bidx, 32);
    if (bm2 < bm || (bm2 == bm && bi2 < bidx)) { bm = bm2; bidx = bi2; }

    // packed q gather from packed codebook
    {
        int t = blk * 128 + tok;
        int n = t >> 12, pix = t & 4095;
#pragma unroll
        for (int cgl = 0; cgl < 4; cgl++) {
            int cg = kg * 4 + cgl;
            uint4 hv = *(const uint4*)(cbH + (size_t)bidx * 64 + cg * 8);
            uint4 lv = *(const uint4*)(cbL + (size_t)bidx * 64 + cg * 8);
            size_t a = (((size_t)(n * 8 + cg)) * 4096 + pix) * 8;
            *(uint4*)(qPH + a) = hv;
            *(uint4*)(qPL + a) = lv;
        }
    }

    float bestd = xn + bm;
    float c = (kg == 0) ? bestd : 0.f;
#pragma unroll
    for (int o = 32; o > 0; o >>= 1) c += __shfl_down(c, o, 64);
    if (l == 0) ssep[blk * 4 + wv] = c;
    if (kg == 0) atomicAdd(&hl[bidx], 1);
    __syncthreads();
    for (int i = tid; i < 512; i += 256) if (hl[i] > 0) atomicAdd(&hist[i], hl[i]);
}

__global__ void vq_init(int* hist)
{
    for (int i = threadIdx.x; i < 512; i += 256) hist[i] = 0;
}

__global__ __launch_bounds__(256) void vq_finalize(
    const float* __restrict__ ssep, const int* __restrict__ hist,
    float* __restrict__ o_loss, float* __restrict__ o_perp)
{
    __shared__ float red[256];
    const int tid = threadIdx.x;
    float h = 0.f;
    for (int i = tid; i < 512; i += 256) {
        float p = (float)hist[i] * (1.0f / 65536.0f);
        h -= p * logf(p + 1e-10f);
    }
    red[tid] = h;
    __syncthreads();
    for (int st = 128; st > 0; st >>= 1) {
        if (tid < st) red[tid] += red[tid + st];
        __syncthreads();
    }
    const float H = red[0];
    __syncthreads();
    float s = 0.f;
    for (int i = tid; i < 2048; i += 256) s += ssep[i];
    red[tid] = s;
    __syncthreads();
    for (int st = 128; st > 0; st >>= 1) {
        if (tid < st) red[tid] += red[tid + st];
        __syncthreads();
    }
    if (tid == 0) {
        *o_loss = 1.25f * red[0] / 4194304.0f;
        *o_perp = expf(H);
    }
}

extern "C" void kernel_launch(void* const* d_in, const int* in_sizes, int n_in,
                              void* d_out, int out_size, void* d_ws, size_t ws_size,
                              hipStream_t stream)
{
    const float* x       = (const float*)d_in[0];
    const float* enc_w1  = (const float*)d_in[1];
    const float* enc_b1  = (const float*)d_in[2];
    const float* enc_w2  = (const float*)d_in[3];
    const float* enc_b2  = (const float*)d_in[4];
    const float* enc_w3  = (const float*)d_in[5];
    const float* enc_b3  = (const float*)d_in[6];
    const float* enc_rw3 = (const float*)d_in[7];
    const float* enc_rb3 = (const float*)d_in[8];
    const float* enc_rw1 = (const float*)d_in[9];
    const float* enc_rb1 = (const float*)d_in[10];
    const float* pre_w   = (const float*)d_in[11];
    const float* pre_b   = (const float*)d_in[12];
    const float* cb      = (const float*)d_in[13];
    const float* dec_w1  = (const float*)d_in[14];
    const float* dec_b1  = (const float*)d_in[15];
    const float* dec_rw3 = (const float*)d_in[16];
    const float* dec_rb3 = (const float*)d_in[17];
    const float* dec_rw1 = (const float*)d_in[18];
    const float* dec_rb1 = (const float*)d_in[19];
    const float* dw1     = (const float*)d_in[20];
    const float* db1     = (const float*)d_in[21];
    const float* dw2     = (const float*)d_in[22];
    const float* db2     = (const float*)d_in[23];

    float* o      = (float*)d_out;
    float* loss_p = o;
    float* recon  = o + 1;
    float* perp_p = o + 1 + 16 * 3 * 256 * 256;

    // ws: R1(H,L) 16.78M shorts each | R2(H,L) | Cf 8.39M f32 | SSE 2048 | HIST | weights
    unsigned short* R1H = (unsigned short*)d_ws;
    unsigned short* R1L = R1H + 16777216;
    unsigned short* R2H = R1L + 16777216;
    unsigned short* R2L = R2H + 16777216;
    float* Cf  = (float*)(R2L + 16777216);
    float* SSE = Cf + 8388608;
    int*   HIST = (int*)(SSE + 2048);

    // packed activation aliases (lifetime-disjoint)
    unsigned short *xPH = R1H,            *xPL = R1L;             // until enc1
    unsigned short *BPH = R1H,            *BPL = R1L;             // enc2->enc3
    unsigned short *zPH = R1H + 8388608,  *zPL = R1L + 8388608;   // pre->vq
    unsigned short *DtPH = R1H + 12582912,*DtPL = R1L + 12582912; // res temps
    unsigned short *dAPH = R1H,           *dAPL = R1L;            // convt1->convt2
    unsigned short *APH = R2H,            *APL = R2L;             // enc1->enc2
    unsigned short *CPH = R2H,            *CPL = R2L;             // relu(C), enc3..convt1
    unsigned short *qPH = R2H + 8388608,  *qPL = R2L + 8388608;   // vq->dec1

    unsigned short* wp_cur = (unsigned short*)(((size_t)(HIST + 512) + 31) & ~(size_t)31);
    auto carve = [&](size_t n_us) {
        unsigned short* p = wp_cur;
        wp_cur += ((n_us + 15) & ~(size_t)15);
        return p;
    };
    auto PK = [&](const float* w, unsigned short* hi, unsigned short* lo,
                  int Co, int Ci, int KK, int CoP, int CiP) {
        int tot = KK * CoP * CiP;
        pack_w<<<dim3((tot + 255) / 256), dim3(256), 0, stream>>>(w, hi, lo, Co, Ci, KK, CoP, CiP);
    };

    unsigned short *e1H = carve(16*64*16),  *e1L = carve(16*64*16);
    unsigned short *e2H = carve(16*128*64), *e2L = carve(16*128*64);
    unsigned short *e3H = carve(9*128*128), *e3L = carve(9*128*128);
    unsigned short *er3aH = carve(9*32*128), *er3aL = carve(9*32*128);
    unsigned short *er3bH = carve(9*32*128), *er3bL = carve(9*32*128);
    unsigned short *er1aH = carve(128*32),   *er1aL = carve(128*32);
    unsigned short *er1bH = carve(128*32),   *er1bL = carve(128*32);
    unsigned short *preH = carve(64*128),    *preL = carve(64*128);
    unsigned short *d1H  = carve(9*128*64),  *d1L  = carve(9*128*64);
    unsigned short *dr3aH = carve(9*32*128), *dr3aL = carve(9*32*128);
    unsigned short *dr3bH = carve(9*32*128), *dr3bL = carve(9*32*128);
    unsigned short *dr1aH = carve(128*32),   *dr1aL = carve(128*32);
    unsigned short *dr1bH = carve(128*32),   *dr1bL = carve(128*32);
    unsigned short *ct1H = carve(16*64*128), *ct1L = carve(16*64*128);
    unsigned short *ct2H = carve(16*32*64),  *ct2L = carve(16*32*64);
    unsigned short *cbH  = carve(512*64),    *cbL  = carve(512*64);
    float* CN = (float*)carve(1024);

    PK(enc_w1, e1H, e1L, 64, 3, 16, 64, 16);
    PK(enc_w2, e2H, e2L, 128, 64, 16, 128, 64);
    PK(enc_w3, e3H, e3L, 128, 128, 9, 128, 128);
    PK(enc_rw3,             er3aH, er3aL, 32, 128, 9, 32, 128);
    PK(enc_rw3 + 32*128*9,  er3bH, er3bL, 32, 128, 9, 32, 128);
    PK(enc_rw1,             er1aH, er1aL, 128, 32, 1, 128, 32);
    PK(enc_rw1 + 128*32,    er1bH, er1bL, 128, 32, 1, 128, 32);
    PK(pre_w, preH, preL, 64, 128, 1, 64, 128);
    PK(dec_w1, d1H, d1L, 128, 64, 9, 128, 64);
    PK(dec_rw3,             dr3aH, dr3aL, 32, 128, 9, 32, 128);
    PK(dec_rw3 + 32*128*9,  dr3bH, dr3bL, 32, 128, 9, 32, 128);
    PK(dec_rw1,             dr1aH, dr1aL, 128, 32, 1, 128, 32);
    PK(dec_rw1 + 128*32,    dr1bH, dr1bL, 128, 32, 1, 128, 32);
    PK(dw1, ct1H, ct1L, 64, 128, 16, 64, 128);
    PK(dw2, ct2H, ct2L, 3, 64, 16, 32, 64);
    PK(cb,  cbH,  cbL,  512, 64, 1, 512, 64);
    cb_norm<<<dim3(2), dim3(256), 0, stream>>>(cb, CN);
    pack_x<<<dim3(4096), dim3(256), 0, stream>>>(x, xPH, xPL);

    const int N = 16;

    // ---- encoder ----
    conv_mfma<4,2,1, 16,64, 256,256, 128,128, 1,64, 2,2,1, 64,  true,false,false,true,false>
        <<<dim3(256,1,N),256,0,stream>>>(xPH,xPL, e1H,e1L, enc_b1, nullptr, nullptr, APH,APL);
    conv_mfma<4,2,1, 64,128, 128,128, 64,64, 1,64, 2,2,1, 128, true,false,false,true,false>
        <<<dim3(64,2,N),256,0,stream>>>(APH,APL, e2H,e2L, enc_b2, nullptr, nullptr, BPH,BPL);
    conv_mfma<3,1,1, 128,128, 64,64, 64,64, 1,64, 2,2,1, 128, true,true,true,false,false>
        <<<dim3(64,2,N),256,0,stream>>>(BPH,BPL, e3H,e3L, enc_b3, nullptr, Cf, CPH,CPL);
    conv_mfma<3,1,1, 128,32, 64,64, 64,64, 2,64, 1,4,1, 32,   true,true,false,false,false>
        <<<dim3(32,1,N),256,0,stream>>>(CPH,CPL, er3aH,er3aL, enc_rb3, nullptr, nullptr, DtPH,DtPL);
    conv_mfma<1,1,0, 32,128, 64,64, 64,64, 1,64, 2,2,1, 128,  true,true,true,false,true>
        <<<dim3(64,2,N),256,0,stream>>>(DtPH,DtPL, er1aH,er1aL, enc_rb1, Cf, Cf, CPH,CPL);
    conv_mfma<3,1,1, 128,32, 64,64, 64,64, 2,64, 1,4,1, 32,   true,true,false,false,false>
        <<<dim3(32,1,N),256,0,stream>>>(CPH,CPL, er3bH,er3bL, enc_rb3 + 32, nullptr, nullptr, DtPH,DtPL);
    conv_mfma<1,1,0, 32,128, 64,64, 64,64, 1,64, 2,2,1, 128,  true,true,true,false,true>
        <<<dim3(64,2,N),256,0,stream>>>(DtPH,DtPL, er1bH,er1bL, enc_rb1 + 128, Cf, Cf, CPH,CPL);
    conv_mfma<1,1,0, 128,64, 64,64, 64,64, 1,64, 2,2,1, 64,   true,false,false,false,false>
        <<<dim3(64,1,N),256,0,stream>>>(CPH,CPL, preH,preL, pre_b, nullptr, nullptr, zPH,zPL);

    // ---- VQ ----
    vq_init<<<dim3(1), dim3(256), 0, stream>>>(HIST);
    vq_mfma<<<dim3(512), dim3(256), 0, stream>>>(zPH,zPL, cbH,cbL, CN, qPH,qPL, SSE, HIST);
    vq_finalize<<<dim3(1), dim3(256), 0, stream>>>(SSE, HIST, loss_p, perp_p);

    // ---- decoder ----
    conv_mfma<3,1,1, 64,128, 64,64, 64,64, 1,64, 2,2,1, 128,  true,true,true,false,false>
        <<<dim3(64,2,N),256,0,stream>>>(qPH,qPL, d1H,d1L, dec_b1, nullptr, Cf, CPH,CPL);
    conv_mfma<3,1,1, 128,32, 64,64, 64,64, 2,64, 1,4,1, 32,   true,true,false,false,false>
        <<<dim3(32,1,N),256,0,stream>>>(CPH,CPL, dr3aH,dr3aL, dec_rb3, nullptr, nullptr, DtPH,DtPL);
    conv_mfma<1,1,0, 32,128, 64,64, 64,64, 1,64, 2,2,1, 128,  true,true,true,false,true>
        <<<dim3(64,2,N),256,0,stream>>>(DtPH,DtPL, dr1aH,dr1aL, dec_rb1, Cf, Cf, CPH,CPL);
    conv_mfma<3,1,1, 128,32, 64,64, 64,64, 2,64, 1,4,1, 32,   true,true,false,false,false>
        <<<dim3(32,1,N),256,0,stream>>>(CPH,CPL, dr3bH,dr3bL, dec_rb3 + 32, nullptr, nullptr, DtPH,DtPL);
    conv_mfma<1,1,0, 32,128, 64,64, 64,64, 1,64, 2,2,1, 128,  true,true,true,false,true>
        <<<dim3(64,2,N),256,0,stream>>>(DtPH,DtPL, dr1bH,dr1bL, dec_rb1 + 128, Cf, Cf, CPH,CPL);
    convt_mfma<128,64, 64,64, 1, 64,  true,false,true>
        <<<dim3(128,2,N),256,0,stream>>>(CPH,CPL, ct1H,ct1L, db1, nullptr, dAPH,dAPL);
    convt_mfma<64,3, 128,128, 1, 32,  false,true,false>
        <<<dim3(512,1,N),256,0,stream>>>(dAPH,dAPL, ct2H,ct2L, db2, recon, nullptr,nullptr);
}

// Round 9
// 640.474 us; speedup vs baseline: 10.7890x; 1.7375x over previous
//
#include <hip/hip_runtime.h>

typedef __attribute__((ext_vector_type(8)))  short bf16x8;
typedef __attribute__((ext_vector_type(16))) float f32x16;
typedef unsigned long long u64t;

// bank-spread swizzle on 16B units: permutes u mod 8 for lane-strides 1 and 2
__device__ __forceinline__ int swzu(int u)
{
    return u ^ (((u >> 3) & 1) | (((u >> 4) & 1) << 1));
}

// split fp32 -> (hi, lo) bf16 pair, RNE both
__device__ __forceinline__ void fsplit(float v, unsigned short& h, unsigned short& l)
{
    union { float f; unsigned u; } a; a.f = v;
    unsigned uh = a.u + 0x7fffu + ((a.u >> 16) & 1u);
    h = (unsigned short)(uh >> 16);
    union { float f; unsigned u; } hb; hb.u = (unsigned)h << 16;
    float r = v - hb.f;
    union { float f; unsigned u; } b; b.f = r;
    unsigned ul = b.u + 0x7fffu + ((b.u >> 16) & 1u);
    l = (unsigned short)(ul >> 16);
}

__device__ __forceinline__ float bf2f(unsigned short u)
{
    union { float f; unsigned v; } a; a.v = (unsigned)u << 16; return a.f;
}

// pack OIHW fp32 weights -> [tap][co_pad][ci_pad] bf16 hi/lo, zero-padded
__global__ void pack_w(const float* __restrict__ w, unsigned short* __restrict__ hi,
                       unsigned short* __restrict__ lo, int Cout, int Cin, int KK,
                       int CoP, int CiP)
{
    int i = blockIdx.x * 256 + threadIdx.x;
    int tot = KK * CoP * CiP;
    if (i >= tot) return;
    int t  = i / (CoP * CiP);
    int r  = i - t * (CoP * CiP);
    int co = r / CiP;
    int ci = r - co * CiP;
    float v = (co < Cout && ci < Cin) ? w[((size_t)co * Cin + ci) * KK + t] : 0.f;
    unsigned short h, l;
    fsplit(v, h, l);
    hi[i] = h; lo[i] = l;
}

__global__ void cb_norm(const float* __restrict__ cb, float* __restrict__ cn)
{
    int i = blockIdx.x * 256 + threadIdx.x;
    if (i >= 512) return;
    float s = 0.f;
    for (int d = 0; d < 64; d++) s = fmaf(cb[i*64+d], cb[i*64+d], s);
    cn[i] = s;
}

// pack input image (3 ch) -> packed [n][cg=2][256][256][8] bf16 hi, ch 3..15 zero
__global__ __launch_bounds__(256) void pack_x(const float* __restrict__ x,
    unsigned short* __restrict__ PH)
{
    int idx = blockIdx.x * 256 + threadIdx.x;      // 16*65536 total
    int n = idx >> 16, pix = idx & 65535;
    unsigned short h[8], l[8];
#pragma unroll
    for (int c = 0; c < 8; c++) h[c] = 0;
#pragma unroll
    for (int c = 0; c < 3; c++) {
        float v = x[((size_t)(n * 3 + c) << 16) + pix];
        fsplit(v, h[c], l[c]);
    }
    uint4 hv;
    hv.x = h[0] | ((unsigned)h[1] << 16); hv.y = h[2] | ((unsigned)h[3] << 16);
    hv.z = h[4] | ((unsigned)h[5] << 16); hv.w = h[6] | ((unsigned)h[7] << 16);
    uint4 z4 = make_uint4(0, 0, 0, 0);
    size_t b0 = (((size_t)(n * 2) << 16) + pix) * 8;
    size_t b1 = (((size_t)(n * 2 + 1) << 16) + pix) * 8;
    *(uint4*)(PH + b0) = hv;
    *(uint4*)(PH + b1) = z4;
}

// ============ bf16 MFMA direct conv, packed in/out ============
// LDS unit u = plane*PS + pos (plane = half of 16-ci chunk) -> coalesced staging.
// A-operand double-buffered in registers. blockIdx.y tiles couts.
template<int K,int S,int P,int CIP,int COUT,int HIN,int WIN,int HOUT,int WOUT,
         int TR,int TC,int WM,int WN,int CO2,int CO_PAD,
         bool PACK,bool PRELU,bool PLO,bool WF32,bool ROUT,bool RES>
__global__ __launch_bounds__(256) void conv_mfma(
    const unsigned short* __restrict__ inH,
    const unsigned short* __restrict__ wpH,
    const float* __restrict__ bias, const float* __restrict__ res,
    float* __restrict__ outF, unsigned short* __restrict__ outPH,
    unsigned short* __restrict__ outPL)
{
    constexpr int IHT = (TR - 1) * S + K;
    constexpr int IW  = (TC - 1) * S + K;
    constexpr int PS  = IHT * IW;
    constexpr int UN  = PS * 2;
    constexpr int KK  = K * K;
    constexpr int NCH = CIP / 16;
    constexpr int CG  = CIP / 8;
    constexpr int CGO = (COUT + 7) / 8;
    constexpr int XB  = WOUT / TC;
    constexpr int REGU = (UN + 255) / 256;

    __shared__ uint4 lbH[UN];

    const int tid = threadIdx.x;
    const int bx  = blockIdx.x;
    const int r0  = (bx / XB) * TR;
    const int c0  = (bx % XB) * TC;
    const int co0 = blockIdx.y * (WM * CO2 * 32);
    const int n   = blockIdx.z;

    const int l  = tid & 63, wv = tid >> 6;
    const int wm = wv / WN, wn = wv % WN;
    const int ln = l & 31, kg = l >> 5;
    const int q  = wn * 32 + ln;
    const int lr = q / TC, lc = q % TC;

    const int iy0 = r0 * S - P, ix0 = c0 * S - P;
    const size_t inb = (size_t)n * CG * HIN * WIN;

    f32x16 acc[CO2];
#pragma unroll
    for (int g = 0; g < CO2; g++) acc[g] = (f32x16){};

    auto unit_load = [&](int u, int cgb, uint4& hv){
        int kgu = (u >= PS) ? 1 : 0;
        int pos = u - kgu * PS;
        int py = pos / IW, px = pos - py * IW;
        int gy = iy0 + py, gx = ix0 + px;
        bool ok = ((unsigned)gy < (unsigned)HIN) && ((unsigned)gx < (unsigned)WIN);
        hv = make_uint4(0,0,0,0);
        if (ok) {
            size_t a = (inb + ((size_t)(cgb + kgu) * HIN + gy) * WIN + gx) * 8;
            hv = *(const uint4*)(inH + a);
        }
    };

    auto stage_direct = [&](int kc){
        for (int idx = tid; idx < UN; idx += 256) {
            uint4 hv;
            unit_load(idx, kc * 2, hv);
            lbH[swzu(idx)] = hv;
        }
    };

    uint4 rvH[REGU];
    auto load_regs = [&](int kc){
#pragma unroll
        for (int rr = 0; rr < REGU; rr++) {
            int idx = tid + rr * 256;
            uint4 hv = make_uint4(0,0,0,0);
            if (idx < UN) unit_load(idx, kc * 2, hv);
            rvH[rr] = hv;
        }
    };
    auto write_regs = [&](){
#pragma unroll
        for (int rr = 0; rr < REGU; rr++) {
            int idx = tid + rr * 256;
            if (idx < UN) lbH[swzu(idx)] = rvH[rr];
        }
    };

    auto compute = [&](int kc){
        bf16x8 aHb[2];
        bf16x8 bH;
        auto loadA = [&](int step, int s){
            const int t = step / CO2, g = step % CO2;
            const int coA = co0 + (wm * CO2 + g) * 32 + ln;
            const size_t wo = ((size_t)t * CO_PAD + coA) * CIP + kc * 16 + kg * 8;
            aHb[s] = *(const bf16x8*)(wpH + wo);
        };
        loadA(0, 0);
#pragma unroll
        for (int step = 0; step < KK * CO2; step++) {
            const int t = step / CO2, g = step % CO2;
            if (g == 0) {
                const int ky = t / K, kx = t % K;
                const int u = kg * PS + (lr * S + ky) * IW + lc * S + kx;
                bH = *(const bf16x8*)&lbH[swzu(u)];
            }
            if (step + 1 < KK * CO2) loadA(step + 1, (step + 1) & 1);
            const int s = step & 1;
            acc[g] = __builtin_amdgcn_mfma_f32_32x32x16_bf16(aHb[s], bH, acc[g], 0, 0, 0);
        }
    };

    stage_direct(0);
    __syncthreads();
    for (int kc = 0; kc < NCH; kc++) {
        const bool more = (kc + 1 < NCH);
        if (more) load_regs(kc + 1);
        compute(kc);
        if (more) {
            __syncthreads();
            write_regs();
            __syncthreads();
        }
    }

    const int gy = r0 + lr, gx = c0 + lc;
    const size_t HWo = (size_t)HOUT * WOUT;
#pragma unroll
    for (int g = 0; g < CO2; g++) {
        const int co32 = co0 + (wm * CO2 + g) * 32;
#pragma unroll
        for (int rq = 0; rq < 4; rq++) {
            const int cb4 = co32 + 8 * rq + 4 * kg;
            float v[4];
#pragma unroll
            for (int i = 0; i < 4; i++) {
                const int r = rq * 4 + i;
                const int co = cb4 + i;
                float bv = (co < COUT) ? bias[co] : 0.f;
                float vv = acc[g][r] + bv;
                if (RES && co < COUT)
                    vv += res[((size_t)n * COUT + co) * HWo + (size_t)gy * WOUT + gx];
                if (ROUT) vv = fmaxf(vv, 0.f);
                if (WF32 && co < COUT)
                    outF[((size_t)n * COUT + co) * HWo + (size_t)gy * WOUT + gx] = vv;
                v[i] = vv;
            }
            if (PACK) {
                u64t uh = 0, ul = 0;
#pragma unroll
                for (int i = 0; i < 4; i++) {
                    float pv = PRELU ? fmaxf(v[i], 0.f) : v[i];
                    unsigned short ph, pl;
                    fsplit(pv, ph, pl);
                    uh |= (u64t)ph << (16 * i);
                    ul |= (u64t)pl << (16 * i);
                }
                size_t pa = (((size_t)n * CGO + (co32 >> 3) + rq) * HOUT + gy) * (size_t)WOUT * 8
                          + (size_t)gx * 8 + 4 * kg;
                *(u64t*)(outPH + pa) = uh;
                if (PLO) *(u64t*)(outPL + pa) = ul;
            }
        }
    }
}

// ============ bf16 MFMA 1x1 conv — no LDS, no barriers ============
// Block: 64 pixels x 64 couts (4 waves: wm co-group, wn pixel-group).
template<int CIP,int COUT,int HW,int CO_PAD,
         bool PACK,bool PRELU,bool PLO,bool WF32,bool ROUT,bool RES>
__global__ __launch_bounds__(256) void conv1x1_mfma(
    const unsigned short* __restrict__ inH,
    const unsigned short* __restrict__ wpH,
    const float* __restrict__ bias, const float* __restrict__ res,
    float* __restrict__ outF, unsigned short* __restrict__ outPH,
    unsigned short* __restrict__ outPL)
{
    constexpr int NCH = CIP / 16;
    constexpr int CG  = CIP / 8;
    constexpr int CGO = (COUT + 7) / 8;

    const int tid = threadIdx.x;
    const int bx  = blockIdx.x;
    const int co0 = blockIdx.y * 64;
    const int n   = blockIdx.z;

    const int l  = tid & 63, wv = tid >> 6;
    const int wm = wv >> 1, wn = wv & 1;
    const int ln = l & 31, kg = l >> 5;

    const int pix = bx * 64 + wn * 32 + ln;
    const int coA = co0 + wm * 32 + ln;

    f32x16 acc = {};
#pragma unroll
    for (int kc = 0; kc < NCH; kc++) {
        bf16x8 b = *(const bf16x8*)(inH + ((size_t)(n * CG + kc * 2 + kg) * HW + pix) * 8);
        bf16x8 a = *(const bf16x8*)(wpH + ((size_t)coA * CIP + kc * 16 + kg * 8));
        acc = __builtin_amdgcn_mfma_f32_32x32x16_bf16(a, b, acc, 0, 0, 0);
    }

    const int co32 = co0 + wm * 32;
#pragma unroll
    for (int rq = 0; rq < 4; rq++) {
        const int cb4 = co32 + 8 * rq + 4 * kg;
        float v[4];
#pragma unroll
        for (int i = 0; i < 4; i++) {
            const int r = rq * 4 + i;
            const int co = cb4 + i;
            float bv = (co < COUT) ? bias[co] : 0.f;
            float vv = acc[r] + bv;
            if (RES && co < COUT)
                vv += res[((size_t)n * COUT + co) * HW + pix];
            if (ROUT) vv = fmaxf(vv, 0.f);
            if (WF32 && co < COUT)
                outF[((size_t)n * COUT + co) * HW + pix] = vv;
            v[i] = vv;
        }
        if (PACK) {
            u64t uh = 0, ul = 0;
#pragma unroll
            for (int i = 0; i < 4; i++) {
                float pv = PRELU ? fmaxf(v[i], 0.f) : v[i];
                unsigned short ph, pl;
                fsplit(pv, ph, pl);
                uh |= (u64t)ph << (16 * i);
                ul |= (u64t)pl << (16 * i);
            }
            size_t pa = (((size_t)n * CGO + (co32 >> 3) + rq) * HW + pix) * 8 + 4 * kg;
            *(u64t*)(outPH + pa) = uh;
            if (PLO) *(u64t*)(outPL + pa) = ul;
        }
    }
}

// ============ bf16 MFMA transpose conv k=4 s=2 p=1, packed in/out ============
template<int CIP,int COUT,int HIN,int WIN,int CO2,int CO_PAD,
         bool PACK,bool WF32,bool ROUT>
__global__ __launch_bounds__(256) void convt_mfma(
    const unsigned short* __restrict__ inH,
    const unsigned short* __restrict__ wpH,
    const float* __restrict__ bias, float* __restrict__ outF,
    unsigned short* __restrict__ outPH)
{
    constexpr int HOUT = 2 * HIN, WOUT = 2 * WIN;
    constexpr int XHN  = WOUT / 128;
    constexpr int PS   = 2 * 68;
    constexpr int UN   = PS * 2;
    constexpr int NCH  = CIP / 16;
    constexpr int CG   = CIP / 8;
    constexpr int CGO  = (COUT + 7) / 8;
    constexpr int REGU = (UN + 255) / 256;

    __shared__ uint4 lbH[UN];

    const int tid = threadIdx.x;
    const int oy  = blockIdx.x / XHN;
    const int xh  = blockIdx.x % XHN;
    const int co0 = blockIdx.y * (CO2 * 32);
    const int n   = blockIdx.z;

    const int ky0 = oy & 1;
    const int iyb = ((oy + ky0) >> 1) - 1;

    const int l  = tid & 63, wv = tid >> 6;
    const int p  = wv & 1, xb = wv >> 1;
    const int ln = l & 31, kg = l >> 5;

    const size_t inb = (size_t)n * CG * HIN * WIN;

    f32x16 acc[CO2];
#pragma unroll
    for (int g = 0; g < CO2; g++) acc[g] = (f32x16){};

    auto unit_load = [&](int u, int cgb, uint4& hv){
        int kgu = (u >= PS) ? 1 : 0;
        int pos = u - kgu * PS;
        int rr = pos / 68, cc = pos - rr * 68;
        int gy = iyb + rr, gx = xh * 64 + cc - 1;
        bool ok = ((unsigned)gy < (unsigned)HIN) && ((unsigned)gx < (unsigned)WIN);
        hv = make_uint4(0,0,0,0);
        if (ok) {
            size_t a = (inb + ((size_t)(cgb + kgu) * HIN + gy) * WIN + gx) * 8;
            hv = *(const uint4*)(inH + a);
        }
    };

    auto stage_direct = [&](int kc){
        for (int idx = tid; idx < UN; idx += 256) {
            uint4 hv;
            unit_load(idx, kc * 2, hv);
            lbH[swzu(idx)] = hv;
        }
    };

    uint4 rvH[REGU];
    auto load_regs = [&](int kc){
#pragma unroll
        for (int rr = 0; rr < REGU; rr++) {
            int idx = tid + rr * 256;
            uint4 hv = make_uint4(0,0,0,0);
            if (idx < UN) unit_load(idx, kc * 2, hv);
            rvH[rr] = hv;
        }
    };
    auto write_regs = [&](){
#pragma unroll
        for (int rr = 0; rr < REGU; rr++) {
            int idx = tid + rr * 256;
            if (idx < UN) lbH[swzu(idx)] = rvH[rr];
        }
    };

    auto compute = [&](int kc){
        bf16x8 aHb[2];
        bf16x8 bH;
        auto loadA = [&](int step, int s){
            const int tt = step / CO2, g = step % CO2;
            const int widx = (ky0 + 2 * (tt >> 1)) * 4 + (p + 2 * (tt & 1));
            const int coA = co0 + g * 32 + ln;
            const size_t wo = ((size_t)widx * CO_PAD + coA) * CIP + kc * 16 + kg * 8;
            aHb[s] = *(const bf16x8*)(wpH + wo);
        };
        loadA(0, 0);
#pragma unroll
        for (int step = 0; step < 4 * CO2; step++) {
            const int tt = step / CO2, g = step % CO2;
            if (g == 0) {
                const int ty = tt >> 1, tx = tt & 1;
                const int u = kg * PS + ty * 68 + xb * 32 + ln + p + tx;
                bH = *(const bf16x8*)&lbH[swzu(u)];
            }
            if (step + 1 < 4 * CO2) loadA(step + 1, (step + 1) & 1);
            const int s = step & 1;
            acc[g] = __builtin_amdgcn_mfma_f32_32x32x16_bf16(aHb[s], bH, acc[g], 0, 0, 0);
        }
    };

    stage_direct(0);
    __syncthreads();
    for (int kc = 0; kc < NCH; kc++) {
        const bool more = (kc + 1 < NCH);
        if (more) load_regs(kc + 1);
        compute(kc);
        if (more) {
            __syncthreads();
            write_regs();
            __syncthreads();
        }
    }

    const int ox = xh * 128 + p + 2 * (xb * 32 + ln);
    const size_t HWo = (size_t)HOUT * WOUT;
#pragma unroll
    for (int g = 0; g < CO2; g++) {
        const int co32 = co0 + g * 32;
#pragma unroll
        for (int rq = 0; rq < 4; rq++) {
            const int cb4 = co32 + 8 * rq + 4 * kg;
            float v[4];
#pragma unroll
            for (int i = 0; i < 4; i++) {
                const int r = rq * 4 + i;
                const int co = cb4 + i;
                float bv = (co < COUT) ? bias[co] : 0.f;
                float vv = acc[g][r] + bv;
                if (ROUT) vv = fmaxf(vv, 0.f);
                if (WF32 && co < COUT)
                    outF[((size_t)n * COUT + co) * HWo + (size_t)oy * WOUT + ox] = vv;
                v[i] = vv;
            }
            if (PACK) {
                u64t uh = 0;
#pragma unroll
                for (int i = 0; i < 4; i++) {
                    unsigned short ph, pl;
                    fsplit(v[i], ph, pl);
                    uh |= (u64t)ph << (16 * i);
                }
                size_t pa = (((size_t)n * CGO + (co32 >> 3) + rq) * HOUT + oy) * (size_t)WOUT * 8
                          + (size_t)ox * 8 + 4 * kg;
                *(u64t*)(outPH + pa) = uh;
            }
        }
    }
}

// ================= VQ via MFMA (split precision, packed z in, packed q out) ==========
__global__ __launch_bounds__(256) void vq_mfma(
    const unsigned short* __restrict__ zPH, const unsigned short* __restrict__ zPL,
    const unsigned short* __restrict__ cbH, const unsigned short* __restrict__ cbL,
    const float* __restrict__ cnorm,
    unsigned short* __restrict__ qPH,
    float* __restrict__ ssep, int* __restrict__ hist)
{
    __shared__ unsigned short zH[128 * 72];
    __shared__ unsigned short zL[128 * 72];
    __shared__ float cnl[512];
    __shared__ int   hl[512];

    const int tid = threadIdx.x;
    const int blk = blockIdx.x;

    for (int i = tid; i < 512; i += 256) { cnl[i] = cnorm[i]; hl[i] = 0; }

    for (int idx = tid; idx < 1024; idx += 256) {
        int tok = idx >> 3, cg = idx & 7;
        int t = blk * 128 + tok;
        int n = t >> 12, pix = t & 4095;
        size_t a = (((size_t)(n * 8 + cg)) * 4096 + pix) * 8;
        *(uint4*)&zH[tok * 72 + cg * 8] = *(const uint4*)(zPH + a);
        *(uint4*)&zL[tok * 72 + cg * 8] = *(const uint4*)(zPL + a);
    }
    __syncthreads();

    const int l  = tid & 63, wv = tid >> 6;
    const int ln = l & 31, kg = l >> 5;
    const int tok = wv * 32 + ln;

    float xn = 0.f;
#pragma unroll
    for (int j8 = 0; j8 < 8; j8++) {
        bf16x8 vH = *(const bf16x8*)&zH[tok * 72 + j8 * 8];
        bf16x8 vL = *(const bf16x8*)&zL[tok * 72 + j8 * 8];
#pragma unroll
        for (int j = 0; j < 8; j++) {
            float xv = bf2f((unsigned short)vH[j]) + bf2f((unsigned short)vL[j]);
            xn = fmaf(xv, xv, xn);
        }
    }

    float bm = 3.4e38f; int bidx = 0;
    for (int cg = 0; cg < 16; cg++) {
        f32x16 a0 = {}, a1 = {};
#pragma unroll
        for (int ks = 0; ks < 4; ks++) {
            const size_t wo = ((size_t)(cg * 32 + ln)) * 64 + ks * 16 + kg * 8;
            bf16x8 aH = *(const bf16x8*)(cbH + wo);
            bf16x8 aL = *(const bf16x8*)(cbL + wo);
            bf16x8 bH = *(const bf16x8*)&zH[tok * 72 + ks * 16 + kg * 8];
            bf16x8 bL = *(const bf16x8*)&zL[tok * 72 + ks * 16 + kg * 8];
            a0 = __builtin_amdgcn_mfma_f32_32x32x16_bf16(aH, bH, a0, 0, 0, 0);
            a1 = __builtin_amdgcn_mfma_f32_32x32x16_bf16(aH, bL, a1, 0, 0, 0);
            a1 = __builtin_amdgcn_mfma_f32_32x32x16_bf16(aL, bH, a1, 0, 0, 0);
        }
#pragma unroll
        for (int r = 0; r < 16; r++) {
            int m    = (r & 3) + 8 * (r >> 2) + 4 * kg;   // ascending in r
            int code = cg * 32 + m;
            float s  = a0[r] + a1[r];
            float dm = cnl[code] - 2.f * s;
            if (dm < bm) { bm = dm; bidx = code; }
        }
    }

    float bm2 = __shfl_xor(bm, 32);
    int   bi2 = __shfl_xor(bidx, 32);
    if (bm2 < bm || (bm2 == bm && bi2 < bidx)) { bm = bm2; bidx = bi2; }

    // packed q gather (bf16 hi of codebook)
    {
        int t = blk * 128 + tok;
        int n = t >> 12, pix = t & 4095;
#pragma unroll
        for (int cgl = 0; cgl < 4; cgl++) {
            int cg = kg * 4 + cgl;
            uint4 hv = *(const uint4*)(cbH + (size_t)bidx * 64 + cg * 8);
            size_t a = (((size_t)(n * 8 + cg)) * 4096 + pix) * 8;
            *(uint4*)(qPH + a) = hv;
        }
    }

    float bestd = xn + bm;
    float c = (kg == 0) ? bestd : 0.f;
#pragma unroll
    for (int o = 32; o > 0; o >>= 1) c += __shfl_down(c, o, 64);
    if (l == 0) ssep[blk * 4 + wv] = c;
    if (kg == 0) atomicAdd(&hl[bidx], 1);
    __syncthreads();
    for (int i = tid; i < 512; i += 256) if (hl[i] > 0) atomicAdd(&hist[i], hl[i]);
}

__global__ void vq_init(int* hist)
{
    for (int i = threadIdx.x; i < 512; i += 256) hist[i] = 0;
}

__global__ __launch_bounds__(256) void vq_finalize(
    const float* __restrict__ ssep, const int* __restrict__ hist,
    float* __restrict__ o_loss, float* __restrict__ o_perp)
{
    __shared__ float red[256];
    const int tid = threadIdx.x;
    float h = 0.f;
    for (int i = tid; i < 512; i += 256) {
        float p = (float)hist[i] * (1.0f / 65536.0f);
        h -= p * logf(p + 1e-10f);
    }
    red[tid] = h;
    __syncthreads();
    for (int st = 128; st > 0; st >>= 1) {
        if (tid < st) red[tid] += red[tid + st];
        __syncthreads();
    }
    const float H = red[0];
    __syncthreads();
    float s = 0.f;
    for (int i = tid; i < 2048; i += 256) s += ssep[i];
    red[tid] = s;
    __syncthreads();
    for (int st = 128; st > 0; st >>= 1) {
        if (tid < st) red[tid] += red[tid + st];
        __syncthreads();
    }
    if (tid == 0) {
        *o_loss = 1.25f * red[0] / 4194304.0f;
        *o_perp = expf(H);
    }
}

extern "C" void kernel_launch(void* const* d_in, const int* in_sizes, int n_in,
                              void* d_out, int out_size, void* d_ws, size_t ws_size,
                              hipStream_t stream)
{
    const float* x       = (const float*)d_in[0];
    const float* enc_w1  = (const float*)d_in[1];
    const float* enc_b1  = (const float*)d_in[2];
    const float* enc_w2  = (const float*)d_in[3];
    const float* enc_b2  = (const float*)d_in[4];
    const float* enc_w3  = (const float*)d_in[5];
    const float* enc_b3  = (const float*)d_in[6];
    const float* enc_rw3 = (const float*)d_in[7];
    const float* enc_rb3 = (const float*)d_in[8];
    const float* enc_rw1 = (const float*)d_in[9];
    const float* enc_rb1 = (const float*)d_in[10];
    const float* pre_w   = (const float*)d_in[11];
    const float* pre_b   = (const float*)d_in[12];
    const float* cb      = (const float*)d_in[13];
    const float* dec_w1  = (const float*)d_in[14];
    const float* dec_b1  = (const float*)d_in[15];
    const float* dec_rw3 = (const float*)d_in[16];
    const float* dec_rb3 = (const float*)d_in[17];
    const float* dec_rw1 = (const float*)d_in[18];
    const float* dec_rb1 = (const float*)d_in[19];
    const float* dw1     = (const float*)d_in[20];
    const float* db1     = (const float*)d_in[21];
    const float* dw2     = (const float*)d_in[22];
    const float* db2     = (const float*)d_in[23];

    float* o      = (float*)d_out;
    float* loss_p = o;
    float* recon  = o + 1;
    float* perp_p = o + 1 + 16 * 3 * 256 * 256;

    // ws: R1(H,L) 16.78M shorts each | R2(H,L) | Cf 8.39M f32 | SSE 2048 | HIST | weights
    unsigned short* R1H = (unsigned short*)d_ws;
    unsigned short* R1L = R1H + 16777216;
    unsigned short* R2H = R1L + 16777216;
    unsigned short* R2L = R2H + 16777216;
    float* Cf  = (float*)(R2L + 16777216);
    float* SSE = Cf + 8388608;
    int*   HIST = (int*)(SSE + 2048);

    // packed activation aliases (lifetime-disjoint)
    unsigned short *xPH = R1H;                                  // until enc1
    unsigned short *BPH = R1H;                                  // enc2->enc3
    unsigned short *zPH = R1H + 8388608, *zPL = R1L + 8388608;  // pre->vq (split!)
    unsigned short *DtPH = R1H + 12582912;                      // res temps
    unsigned short *dAPH = R1H;                                 // convt1->convt2
    unsigned short *APH = R2H;                                  // enc1->enc2
    unsigned short *CPH = R2H;                                  // relu(C), enc3..convt1
    unsigned short *qPH = R2H + 8388608;                        // vq->dec1

    unsigned short* wp_cur = (unsigned short*)(((size_t)(HIST + 512) + 31) & ~(size_t)31);
    auto carve = [&](size_t n_us) {
        unsigned short* p = wp_cur;
        wp_cur += ((n_us + 15) & ~(size_t)15);
        return p;
    };
    auto PK = [&](const float* w, unsigned short* hi, unsigned short* lo,
                  int Co, int Ci, int KK, int CoP, int CiP) {
        int tot = KK * CoP * CiP;
        pack_w<<<dim3((tot + 255) / 256), dim3(256), 0, stream>>>(w, hi, lo, Co, Ci, KK, CoP, CiP);
    };

    unsigned short *e1H = carve(16*64*16),  *e1L = carve(16*64*16);
    unsigned short *e2H = carve(16*128*64), *e2L = carve(16*128*64);
    unsigned short *e3H = carve(9*128*128), *e3L = carve(9*128*128);
    unsigned short *er3aH = carve(9*32*128), *er3aL = carve(9*32*128);
    unsigned short *er3bH = carve(9*32*128), *er3bL = carve(9*32*128);
    unsigned short *er1aH = carve(128*32),   *er1aL = carve(128*32);
    unsigned short *er1bH = carve(128*32),   *er1bL = carve(128*32);
    unsigned short *preH = carve(64*128),    *preL = carve(64*128);
    unsigned short *d1H  = carve(9*128*64),  *d1L  = carve(9*128*64);
    unsigned short *dr3aH = carve(9*32*128), *dr3aL = carve(9*32*128);
    unsigned short *dr3bH = carve(9*32*128), *dr3bL = carve(9*32*128);
    unsigned short *dr1aH = carve(128*32),   *dr1aL = carve(128*32);
    unsigned short *dr1bH = carve(128*32),   *dr1bL = carve(128*32);
    unsigned short *ct1H = carve(16*64*128), *ct1L = carve(16*64*128);
    unsigned short *ct2H = carve(16*32*64),  *ct2L = carve(16*32*64);
    unsigned short *cbH  = carve(512*64),    *cbL  = carve(512*64);
    float* CN = (float*)carve(1024);

    PK(enc_w1, e1H, e1L, 64, 3, 16, 64, 16);
    PK(enc_w2, e2H, e2L, 128, 64, 16, 128, 64);
    PK(enc_w3, e3H, e3L, 128, 128, 9, 128, 128);
    PK(enc_rw3,             er3aH, er3aL, 32, 128, 9, 32, 128);
    PK(enc_rw3 + 32*128*9,  er3bH, er3bL, 32, 128, 9, 32, 128);
    PK(enc_rw1,             er1aH, er1aL, 128, 32, 1, 128, 32);
    PK(enc_rw1 + 128*32,    er1bH, er1bL, 128, 32, 1, 128, 32);
    PK(pre_w, preH, preL, 64, 128, 1, 64, 128);
    PK(dec_w1, d1H, d1L, 128, 64, 9, 128, 64);
    PK(dec_rw3,             dr3aH, dr3aL, 32, 128, 9, 32, 128);
    PK(dec_rw3 + 32*128*9,  dr3bH, dr3bL, 32, 128, 9, 32, 128);
    PK(dec_rw1,             dr1aH, dr1aL, 128, 32, 1, 128, 32);
    PK(dec_rw1 + 128*32,    dr1bH, dr1bL, 128, 32, 1, 128, 32);
    PK(dw1, ct1H, ct1L, 64, 128, 16, 64, 128);
    PK(dw2, ct2H, ct2L, 3, 64, 16, 32, 64);
    PK(cb,  cbH,  cbL,  512, 64, 1, 512, 64);
    cb_norm<<<dim3(2), dim3(256), 0, stream>>>(cb, CN);
    pack_x<<<dim3(4096), dim3(256), 0, stream>>>(x, xPH);

    const int N = 16;

    // ---- encoder ----
    conv_mfma<4,2,1, 16,64, 256,256, 128,128, 1,64, 2,2,1, 64,  true,false,false,false,true,false>
        <<<dim3(256,1,N),256,0,stream>>>(xPH, e1H, enc_b1, nullptr, nullptr, APH, nullptr);
    conv_mfma<4,2,1, 64,128, 128,128, 64,64, 1,64, 2,2,1, 128,  true,false,false,false,true,false>
        <<<dim3(64,2,N),256,0,stream>>>(APH, e2H, enc_b2, nullptr, nullptr, BPH, nullptr);
    conv_mfma<3,1,1, 128,128, 64,64, 64,64, 1,64, 2,2,1, 128,   true,true,false,true,false,false>
        <<<dim3(64,2,N),256,0,stream>>>(BPH, e3H, enc_b3, nullptr, Cf, CPH, nullptr);
    conv_mfma<3,1,1, 128,32, 64,64, 64,64, 2,64, 1,4,1, 32,     true,true,false,false,false,false>
        <<<dim3(32,1,N),256,0,stream>>>(CPH, er3aH, enc_rb3, nullptr, nullptr, DtPH, nullptr);
    conv1x1_mfma<32,128, 4096, 128,  true,true,false,true,false,true>
        <<<dim3(64,2,N),256,0,stream>>>(DtPH, er1aH, enc_rb1, Cf, Cf, CPH, nullptr);
    conv_mfma<3,1,1, 128,32, 64,64, 64,64, 2,64, 1,4,1, 32,     true,true,false,false,false,false>
        <<<dim3(32,1,N),256,0,stream>>>(CPH, er3bH, enc_rb3 + 32, nullptr, nullptr, DtPH, nullptr);
    conv1x1_mfma<32,128, 4096, 128,  true,true,false,true,false,true>
        <<<dim3(64,2,N),256,0,stream>>>(DtPH, er1bH, enc_rb1 + 128, Cf, Cf, CPH, nullptr);
    conv1x1_mfma<128,64, 4096, 64,   true,false,true,false,false,false>
        <<<dim3(64,1,N),256,0,stream>>>(CPH, preH, pre_b, nullptr, nullptr, zPH, zPL);

    // ---- VQ ----
    vq_init<<<dim3(1), dim3(256), 0, stream>>>(HIST);
    vq_mfma<<<dim3(512), dim3(256), 0, stream>>>(zPH, zPL, cbH, cbL, CN, qPH, SSE, HIST);
    vq_finalize<<<dim3(1), dim3(256), 0, stream>>>(SSE, HIST, loss_p, perp_p);

    // ---- decoder ----
    conv_mfma<3,1,1, 64,128, 64,64, 64,64, 1,64, 2,2,1, 128,    true,true,false,true,false,false>
        <<<dim3(64,2,N),256,0,stream>>>(qPH, d1H, dec_b1, nullptr, Cf, CPH, nullptr);
    conv_mfma<3,1,1, 128,32, 64,64, 64,64, 2,64, 1,4,1, 32,     true,true,false,false,false,false>
        <<<dim3(32,1,N),256,0,stream>>>(CPH, dr3aH, dec_rb3, nullptr, nullptr, DtPH, nullptr);
    conv1x1_mfma<32,128, 4096, 128,  true,true,false,true,false,true>
        <<<dim3(64,2,N),256,0,stream>>>(DtPH, dr1aH, dec_rb1, Cf, Cf, CPH, nullptr);
    conv_mfma<3,1,1, 128,32, 64,64, 64,64, 2,64, 1,4,1, 32,     true,true,false,false,false,false>
        <<<dim3(32,1,N),256,0,stream>>>(CPH, dr3bH, dec_rb3 + 32, nullptr, nullptr, DtPH, nullptr);
    conv1x1_mfma<32,128, 4096, 128,  true,true,false,true,false,true>
        <<<dim3(64,2,N),256,0,stream>>>(DtPH, dr1bH, dec_rb1 + 128, Cf, Cf, CPH, nullptr);
    convt_mfma<128,64, 64,64, 1, 64,  true,false,true>
        <<<dim3(128,2,N),256,0,stream>>>(CPH, ct1H, db1, nullptr, dAPH);
    convt_mfma<64,3, 128,128, 1, 32,  false,true,false>
        <<<dim3(512,1,N),256,0,stream>>>(dAPH, ct2H, db2, recon, nullptr);
}

// Round 10
// 520.943 us; speedup vs baseline: 13.2645x; 1.2295x over previous
//
#include <hip/hip_runtime.h>

typedef __attribute__((ext_vector_type(8)))  short bf16x8;
typedef __attribute__((ext_vector_type(16))) float f32x16;
typedef unsigned long long u64t;

// bank-spread swizzle on 16B units
__device__ __forceinline__ int swzu(int u)
{
    return u ^ (((u >> 3) & 1) | (((u >> 4) & 1) << 1));
}

// split fp32 -> (hi, lo) bf16 pair, RNE both
__device__ __forceinline__ void fsplit(float v, unsigned short& h, unsigned short& l)
{
    union { float f; unsigned u; } a; a.f = v;
    unsigned uh = a.u + 0x7fffu + ((a.u >> 16) & 1u);
    h = (unsigned short)(uh >> 16);
    union { float f; unsigned u; } hb; hb.u = (unsigned)h << 16;
    float r = v - hb.f;
    union { float f; unsigned u; } b; b.f = r;
    unsigned ul = b.u + 0x7fffu + ((b.u >> 16) & 1u);
    l = (unsigned short)(ul >> 16);
}

__device__ __forceinline__ float bf2f(unsigned short u)
{
    union { float f; unsigned v; } a; a.v = (unsigned)u << 16; return a.f;
}

// pack OIHW fp32 weights -> [tap][co_pad][ci_pad] bf16 hi/lo, zero-padded
__global__ void pack_w(const float* __restrict__ w, unsigned short* __restrict__ hi,
                       unsigned short* __restrict__ lo, int Cout, int Cin, int KK,
                       int CoP, int CiP)
{
    int i = blockIdx.x * 256 + threadIdx.x;
    int tot = KK * CoP * CiP;
    if (i >= tot) return;
    int t  = i / (CoP * CiP);
    int r  = i - t * (CoP * CiP);
    int co = r / CiP;
    int ci = r - co * CiP;
    float v = (co < Cout && ci < Cin) ? w[((size_t)co * Cin + ci) * KK + t] : 0.f;
    unsigned short h, l;
    fsplit(v, h, l);
    hi[i] = h; lo[i] = l;
}

__global__ void cb_norm(const float* __restrict__ cb, float* __restrict__ cn)
{
    int i = blockIdx.x * 256 + threadIdx.x;
    if (i >= 512) return;
    float s = 0.f;
    for (int d = 0; d < 64; d++) s = fmaf(cb[i*64+d], cb[i*64+d], s);
    cn[i] = s;
}

// pack input image (3 ch) -> packed [n][cg=2][256][256][8] bf16 hi, ch 3..15 zero
__global__ __launch_bounds__(256) void pack_x(const float* __restrict__ x,
    unsigned short* __restrict__ PH)
{
    int idx = blockIdx.x * 256 + threadIdx.x;      // 16*65536 total
    int n = idx >> 16, pix = idx & 65535;
    unsigned short h[8], l[8];
#pragma unroll
    for (int c = 0; c < 8; c++) h[c] = 0;
#pragma unroll
    for (int c = 0; c < 3; c++) {
        float v = x[((size_t)(n * 3 + c) << 16) + pix];
        fsplit(v, h[c], l[c]);
    }
    uint4 hv;
    hv.x = h[0] | ((unsigned)h[1] << 16); hv.y = h[2] | ((unsigned)h[3] << 16);
    hv.z = h[4] | ((unsigned)h[5] << 16); hv.w = h[6] | ((unsigned)h[7] << 16);
    uint4 z4 = make_uint4(0, 0, 0, 0);
    size_t b0 = (((size_t)(n * 2) << 16) + pix) * 8;
    size_t b1 = (((size_t)(n * 2 + 1) << 16) + pix) * 8;
    *(uint4*)(PH + b0) = hv;
    *(uint4*)(PH + b1) = z4;
}

// ============ bf16 MFMA direct conv, packed in/out ============
// Wave tile: PX2 pixel-groups x CO2 co-groups (32x32 each). Chunk = CC*16 ci
// staged in LDS (unit u = plane*PS + pos, coalesced). A/B double-buffered in
// registers one (ks,tap)-step ahead. Summation order: ci ascending, taps within.
template<int K,int S,int P,int CIP,int COUT,int HIN,int WIN,int HOUT,int WOUT,
         int TR,int TC,int WM,int WN,int PX2,int CO2,int CC,int CO_PAD,
         bool PACK,bool PRELU,bool PLO,bool WF32,bool ROUT,bool RES>
__global__ __launch_bounds__(256) void conv_mfma(
    const unsigned short* __restrict__ inH,
    const unsigned short* __restrict__ wpH,
    const float* __restrict__ bias, const float* __restrict__ res,
    float* __restrict__ outF, unsigned short* __restrict__ outPH,
    unsigned short* __restrict__ outPL)
{
    constexpr int IHT = (TR - 1) * S + K;
    constexpr int IW  = (TC - 1) * S + K;
    constexpr int PS  = IHT * IW;
    constexpr int PLN = CC * 2;
    constexpr int UN  = PS * PLN;
    constexpr int KK  = K * K;
    constexpr int NCH = CIP / (CC * 16);
    constexpr int CG  = CIP / 8;
    constexpr int CGO = (COUT + 7) / 8;
    constexpr int XB  = WOUT / TC;
    constexpr int REGU = (UN + 255) / 256;
    constexpr int NST = CC * KK;

    __shared__ uint4 lbH[UN];

    const int tid = threadIdx.x;
    const int bx  = blockIdx.x;
    const int r0  = (bx / XB) * TR;
    const int c0  = (bx % XB) * TC;
    const int co0 = blockIdx.y * (WM * CO2 * 32);
    const int n   = blockIdx.z;

    const int l  = tid & 63, wv = tid >> 6;
    const int wm = wv / WN, wn = wv % WN;
    const int ln = l & 31, kg = l >> 5;

    int pb[PX2], gyv[PX2], gxv[PX2];
#pragma unroll
    for (int p2 = 0; p2 < PX2; p2++) {
        int q = wn * (PX2 * 32) + p2 * 32 + ln;
        int lr = q / TC, lc = q % TC;
        pb[p2] = (lr * S) * IW + lc * S;
        gyv[p2] = r0 + lr; gxv[p2] = c0 + lc;
    }

    const int iy0 = r0 * S - P, ix0 = c0 * S - P;
    const size_t inb = (size_t)n * CG * HIN * WIN;

    f32x16 acc[PX2][CO2];
#pragma unroll
    for (int p2 = 0; p2 < PX2; p2++)
#pragma unroll
        for (int g = 0; g < CO2; g++) acc[p2][g] = (f32x16){};

    auto unit_load = [&](int u, int cgb, uint4& hv){
        int kgu = u / PS, pos = u - kgu * PS;
        int py = pos / IW, px = pos - py * IW;
        int gy = iy0 + py, gx = ix0 + px;
        bool ok = ((unsigned)gy < (unsigned)HIN) && ((unsigned)gx < (unsigned)WIN);
        hv = make_uint4(0,0,0,0);
        if (ok) {
            size_t a = (inb + ((size_t)(cgb + kgu) * HIN + gy) * WIN + gx) * 8;
            hv = *(const uint4*)(inH + a);
        }
    };

    auto stage_direct = [&](int kc){
        for (int idx = tid; idx < UN; idx += 256) {
            uint4 hv;
            unit_load(idx, kc * PLN, hv);
            lbH[swzu(idx)] = hv;
        }
    };

    uint4 rvH[REGU];
    auto load_regs = [&](int kc){
#pragma unroll
        for (int rr = 0; rr < REGU; rr++) {
            int idx = tid + rr * 256;
            uint4 hv = make_uint4(0,0,0,0);
            if (idx < UN) unit_load(idx, kc * PLN, hv);
            rvH[rr] = hv;
        }
    };
    auto write_regs = [&](){
#pragma unroll
        for (int rr = 0; rr < REGU; rr++) {
            int idx = tid + rr * 256;
            if (idx < UN) lbH[swzu(idx)] = rvH[rr];
        }
    };

    auto compute = [&](int kc){
        bf16x8 aC[CO2], aN[CO2], bC[PX2], bN[PX2];
        auto loadA = [&](int step, bf16x8* a){
            const int ks = step / KK, t = step - ks * KK;
#pragma unroll
            for (int g = 0; g < CO2; g++) {
                const int coA = co0 + (wm * CO2 + g) * 32 + ln;
                const size_t wo = ((size_t)t * CO_PAD + coA) * CIP
                                + kc * (CC * 16) + ks * 16 + kg * 8;
                a[g] = *(const bf16x8*)(wpH + wo);
            }
        };
        auto loadB = [&](int step, bf16x8* b){
            const int ks = step / KK, t = step - ks * KK;
            const int ky = t / K, kx = t - ky * K;
#pragma unroll
            for (int p2 = 0; p2 < PX2; p2++) {
                const int u = (ks * 2 + kg) * PS + pb[p2] + ky * IW + kx;
                b[p2] = *(const bf16x8*)&lbH[swzu(u)];
            }
        };
        loadA(0, aC); loadB(0, bC);
#pragma unroll
        for (int step = 0; step < NST; step++) {
            if (step + 1 < NST) { loadA(step + 1, aN); loadB(step + 1, bN); }
#pragma unroll
            for (int p2 = 0; p2 < PX2; p2++)
#pragma unroll
                for (int g = 0; g < CO2; g++)
                    acc[p2][g] = __builtin_amdgcn_mfma_f32_32x32x16_bf16(
                        aC[g], bC[p2], acc[p2][g], 0, 0, 0);
            if (step + 1 < NST) {
#pragma unroll
                for (int g = 0; g < CO2; g++) aC[g] = aN[g];
#pragma unroll
                for (int p2 = 0; p2 < PX2; p2++) bC[p2] = bN[p2];
            }
        }
    };

    stage_direct(0);
    __syncthreads();
    for (int kc = 0; kc < NCH; kc++) {
        const bool more = (kc + 1 < NCH);
        if (more) load_regs(kc + 1);
        compute(kc);
        if (more) {
            __syncthreads();
            write_regs();
            __syncthreads();
        }
    }

    const size_t HWo = (size_t)HOUT * WOUT;
#pragma unroll
    for (int p2 = 0; p2 < PX2; p2++) {
        const int gy = gyv[p2], gx = gxv[p2];
#pragma unroll
        for (int g = 0; g < CO2; g++) {
            const int co32 = co0 + (wm * CO2 + g) * 32;
#pragma unroll
            for (int rq = 0; rq < 4; rq++) {
                const int cb4 = co32 + 8 * rq + 4 * kg;
                float v[4];
#pragma unroll
                for (int i = 0; i < 4; i++) {
                    const int r = rq * 4 + i;
                    const int co = cb4 + i;
                    float bv = (co < COUT) ? bias[co] : 0.f;
                    float vv = acc[p2][g][r] + bv;
                    if (RES && co < COUT)
                        vv += res[((size_t)n * COUT + co) * HWo + (size_t)gy * WOUT + gx];
                    if (ROUT) vv = fmaxf(vv, 0.f);
                    if (WF32 && co < COUT)
                        outF[((size_t)n * COUT + co) * HWo + (size_t)gy * WOUT + gx] = vv;
                    v[i] = vv;
                }
                if (PACK) {
                    u64t uh = 0, ul = 0;
#pragma unroll
                    for (int i = 0; i < 4; i++) {
                        float pv = PRELU ? fmaxf(v[i], 0.f) : v[i];
                        unsigned short ph, pl;
                        fsplit(pv, ph, pl);
                        uh |= (u64t)ph << (16 * i);
                        ul |= (u64t)pl << (16 * i);
                    }
                    size_t pa = (((size_t)n * CGO + (co32 >> 3) + rq) * HOUT + gy) * (size_t)WOUT * 8
                              + (size_t)gx * 8 + 4 * kg;
                    *(u64t*)(outPH + pa) = uh;
                    if (PLO) *(u64t*)(outPL + pa) = ul;
                }
            }
        }
    }
}

// ============ bf16 MFMA 1x1 conv — no LDS, no barriers ============
template<int CIP,int COUT,int HW,int CO_PAD,
         bool PACK,bool PRELU,bool PLO,bool WF32,bool ROUT,bool RES>
__global__ __launch_bounds__(256) void conv1x1_mfma(
    const unsigned short* __restrict__ inH,
    const unsigned short* __restrict__ wpH,
    const float* __restrict__ bias, const float* __restrict__ res,
    float* __restrict__ outF, unsigned short* __restrict__ outPH,
    unsigned short* __restrict__ outPL)
{
    constexpr int NCH = CIP / 16;
    constexpr int CG  = CIP / 8;
    constexpr int CGO = (COUT + 7) / 8;

    const int tid = threadIdx.x;
    const int bx  = blockIdx.x;
    const int co0 = blockIdx.y * 64;
    const int n   = blockIdx.z;

    const int l  = tid & 63, wv = tid >> 6;
    const int wm = wv >> 1, wn = wv & 1;
    const int ln = l & 31, kg = l >> 5;

    const int pix = bx * 64 + wn * 32 + ln;
    const int coA = co0 + wm * 32 + ln;

    f32x16 acc = {};
#pragma unroll
    for (int kc = 0; kc < NCH; kc++) {
        bf16x8 b = *(const bf16x8*)(inH + ((size_t)(n * CG + kc * 2 + kg) * HW + pix) * 8);
        bf16x8 a = *(const bf16x8*)(wpH + ((size_t)coA * CIP + kc * 16 + kg * 8));
        acc = __builtin_amdgcn_mfma_f32_32x32x16_bf16(a, b, acc, 0, 0, 0);
    }

    const int co32 = co0 + wm * 32;
#pragma unroll
    for (int rq = 0; rq < 4; rq++) {
        const int cb4 = co32 + 8 * rq + 4 * kg;
        float v[4];
#pragma unroll
        for (int i = 0; i < 4; i++) {
            const int r = rq * 4 + i;
            const int co = cb4 + i;
            float bv = (co < COUT) ? bias[co] : 0.f;
            float vv = acc[r] + bv;
            if (RES && co < COUT)
                vv += res[((size_t)n * COUT + co) * HW + pix];
            if (ROUT) vv = fmaxf(vv, 0.f);
            if (WF32 && co < COUT)
                outF[((size_t)n * COUT + co) * HW + pix] = vv;
            v[i] = vv;
        }
        if (PACK) {
            u64t uh = 0, ul = 0;
#pragma unroll
            for (int i = 0; i < 4; i++) {
                float pv = PRELU ? fmaxf(v[i], 0.f) : v[i];
                unsigned short ph, pl;
                fsplit(pv, ph, pl);
                uh |= (u64t)ph << (16 * i);
                ul |= (u64t)pl << (16 * i);
            }
            size_t pa = (((size_t)n * CGO + (co32 >> 3) + rq) * HW + pix) * 8 + 4 * kg;
            *(u64t*)(outPH + pa) = uh;
            if (PLO) *(u64t*)(outPL + pa) = ul;
        }
    }
}

// ============ bf16 MFMA transpose conv k=4 s=2 p=1, packed in ============
// Block: 2 output rows of equal parity {oy0, oy0+2} x 128-wide x-half.
// 4 waves = 2 x-parities x 2 x-blocks; wave tile: 2 rows x CO2 co-groups.
template<int CIP,int COUT,int HIN,int WIN,int CO2,int CC,int CO_PAD,
         bool PACK,bool WF32,bool ROUT>
__global__ __launch_bounds__(256) void convt_mfma(
    const unsigned short* __restrict__ inH,
    const unsigned short* __restrict__ wpH,
    const float* __restrict__ bias, float* __restrict__ outF,
    unsigned short* __restrict__ outPH)
{
    constexpr int HOUT = 2 * HIN, WOUT = 2 * WIN;
    constexpr int XHN  = WOUT / 128;
    constexpr int PS   = 3 * 68;
    constexpr int PLN  = CC * 2;
    constexpr int UN   = PS * PLN;
    constexpr int NCH  = CIP / (CC * 16);
    constexpr int CG   = CIP / 8;
    constexpr int CGO  = (COUT + 7) / 8;
    constexpr int REGU = (UN + 255) / 256;
    constexpr int NST  = CC * 4;

    __shared__ uint4 lbH[UN];

    const int tid = threadIdx.x;
    const int xh  = blockIdx.x % XHN;
    const int gr  = blockIdx.x / XHN;
    const int oy0 = (gr >> 1) * 4 + (gr & 1);
    const int co0 = blockIdx.y * (CO2 * 32);
    const int n   = blockIdx.z;

    const int ky0 = oy0 & 1;
    const int iyb = ((oy0 + ky0) >> 1) - 1;

    const int l  = tid & 63, wv = tid >> 6;
    const int pw = wv & 1, xb = wv >> 1;
    const int ln = l & 31, kg = l >> 5;

    const size_t inb = (size_t)n * CG * HIN * WIN;

    f32x16 acc[2][CO2];
#pragma unroll
    for (int r2 = 0; r2 < 2; r2++)
#pragma unroll
        for (int g = 0; g < CO2; g++) acc[r2][g] = (f32x16){};

    auto unit_load = [&](int u, int cgb, uint4& hv){
        int kgu = u / PS, pos = u - kgu * PS;
        int rr = pos / 68, cc = pos - rr * 68;
        int gy = iyb + rr, gx = xh * 64 + cc - 1;
        bool ok = ((unsigned)gy < (unsigned)HIN) && ((unsigned)gx < (unsigned)WIN);
        hv = make_uint4(0,0,0,0);
        if (ok) {
            size_t a = (inb + ((size_t)(cgb + kgu) * HIN + gy) * WIN + gx) * 8;
            hv = *(const uint4*)(inH + a);
        }
    };

    auto stage_direct = [&](int kc){
        for (int idx = tid; idx < UN; idx += 256) {
            uint4 hv;
            unit_load(idx, kc * PLN, hv);
            lbH[swzu(idx)] = hv;
        }
    };

    uint4 rvH[REGU];
    auto load_regs = [&](int kc){
#pragma unroll
        for (int rr = 0; rr < REGU; rr++) {
            int idx = tid + rr * 256;
            uint4 hv = make_uint4(0,0,0,0);
            if (idx < UN) unit_load(idx, kc * PLN, hv);
            rvH[rr] = hv;
        }
    };
    auto write_regs = [&](){
#pragma unroll
        for (int rr = 0; rr < REGU; rr++) {
            int idx = tid + rr * 256;
            if (idx < UN) lbH[swzu(idx)] = rvH[rr];
        }
    };

    auto compute = [&](int kc){
        bf16x8 aC[CO2], aN[CO2], bC[2], bN[2];
        auto loadA = [&](int step, bf16x8* a){
            const int ks = step / 4, tt = step - ks * 4;
            const int widx = (ky0 + 2 * (tt >> 1)) * 4 + (pw + 2 * (tt & 1));
#pragma unroll
            for (int g = 0; g < CO2; g++) {
                const int coA = co0 + g * 32 + ln;
                const size_t wo = ((size_t)widx * CO_PAD + coA) * CIP
                                + kc * (CC * 16) + ks * 16 + kg * 8;
                a[g] = *(const bf16x8*)(wpH + wo);
            }
        };
        auto loadB = [&](int step, bf16x8* b){
            const int ks = step / 4, tt = step - ks * 4;
            const int ty = tt >> 1, tx = tt & 1;
#pragma unroll
            for (int r2 = 0; r2 < 2; r2++) {
                const int u = (ks * 2 + kg) * PS + (r2 + ty) * 68 + xb * 32 + ln + pw + tx;
                b[r2] = *(const bf16x8*)&lbH[swzu(u)];
            }
        };
        loadA(0, aC); loadB(0, bC);
#pragma unroll
        for (int step = 0; step < NST; step++) {
            if (step + 1 < NST) { loadA(step + 1, aN); loadB(step + 1, bN); }
#pragma unroll
            for (int r2 = 0; r2 < 2; r2++)
#pragma unroll
                for (int g = 0; g < CO2; g++)
                    acc[r2][g] = __builtin_amdgcn_mfma_f32_32x32x16_bf16(
                        aC[g], bC[r2], acc[r2][g], 0, 0, 0);
            if (step + 1 < NST) {
#pragma unroll
                for (int g = 0; g < CO2; g++) aC[g] = aN[g];
#pragma unroll
                for (int r2 = 0; r2 < 2; r2++) bC[r2] = bN[r2];
            }
        }
    };

    stage_direct(0);
    __syncthreads();
    for (int kc = 0; kc < NCH; kc++) {
        const bool more = (kc + 1 < NCH);
        if (more) load_regs(kc + 1);
        compute(kc);
        if (more) {
            __syncthreads();
            write_regs();
            __syncthreads();
        }
    }

    const int ox = xh * 128 + pw + 2 * (xb * 32 + ln);
    const size_t HWo = (size_t)HOUT * WOUT;
#pragma unroll
    for (int r2 = 0; r2 < 2; r2++) {
        const int oy = oy0 + 2 * r2;
#pragma unroll
        for (int g = 0; g < CO2; g++) {
            const int co32 = co0 + g * 32;
#pragma unroll
            for (int rq = 0; rq < 4; rq++) {
                const int cb4 = co32 + 8 * rq + 4 * kg;
                float v[4];
#pragma unroll
                for (int i = 0; i < 4; i++) {
                    const int r = rq * 4 + i;
                    const int co = cb4 + i;
                    float bv = (co < COUT) ? bias[co] : 0.f;
                    float vv = acc[r2][g][r] + bv;
                    if (ROUT) vv = fmaxf(vv, 0.f);
                    if (WF32 && co < COUT)
                        outF[((size_t)n * COUT + co) * HWo + (size_t)oy * WOUT + ox] = vv;
                    v[i] = vv;
                }
                if (PACK) {
                    u64t uh = 0;
#pragma unroll
                    for (int i = 0; i < 4; i++) {
                        unsigned short ph, pl;
                        fsplit(v[i], ph, pl);
                        uh |= (u64t)ph << (16 * i);
                    }
                    size_t pa = (((size_t)n * CGO + (co32 >> 3) + rq) * HOUT + oy) * (size_t)WOUT * 8
                              + (size_t)ox * 8 + 4 * kg;
                    *(u64t*)(outPH + pa) = uh;
                }
            }
        }
    }
}

// ================= VQ via MFMA (split precision, packed z in, packed q out) ==========
__global__ __launch_bounds__(256) void vq_mfma(
    const unsigned short* __restrict__ zPH, const unsigned short* __restrict__ zPL,
    const unsigned short* __restrict__ cbH, const unsigned short* __restrict__ cbL,
    const float* __restrict__ cnorm,
    unsigned short* __restrict__ qPH,
    float* __restrict__ ssep, int* __restrict__ hist)
{
    __shared__ unsigned short zH[128 * 72];
    __shared__ unsigned short zL[128 * 72];
    __shared__ float cnl[512];
    __shared__ int   hl[512];

    const int tid = threadIdx.x;
    const int blk = blockIdx.x;

    for (int i = tid; i < 512; i += 256) { cnl[i] = cnorm[i]; hl[i] = 0; }

    for (int idx = tid; idx < 1024; idx += 256) {
        int tok = idx >> 3, cg = idx & 7;
        int t = blk * 128 + tok;
        int n = t >> 12, pix = t & 4095;
        size_t a = (((size_t)(n * 8 + cg)) * 4096 + pix) * 8;
        *(uint4*)&zH[tok * 72 + cg * 8] = *(const uint4*)(zPH + a);
        *(uint4*)&zL[tok * 72 + cg * 8] = *(const uint4*)(zPL + a);
    }
    __syncthreads();

    const int l  = tid & 63, wv = tid >> 6;
    const int ln = l & 31, kg = l >> 5;
    const int tok = wv * 32 + ln;

    float xn = 0.f;
#pragma unroll
    for (int j8 = 0; j8 < 8; j8++) {
        bf16x8 vH = *(const bf16x8*)&zH[tok * 72 + j8 * 8];
        bf16x8 vL = *(const bf16x8*)&zL[tok * 72 + j8 * 8];
#pragma unroll
        for (int j = 0; j < 8; j++) {
            float xv = bf2f((unsigned short)vH[j]) + bf2f((unsigned short)vL[j]);
            xn = fmaf(xv, xv, xn);
        }
    }

    float bm = 3.4e38f; int bidx = 0;
    for (int cg = 0; cg < 16; cg++) {
        f32x16 a0 = {}, a1 = {};
#pragma unroll
        for (int ks = 0; ks < 4; ks++) {
            const size_t wo = ((size_t)(cg * 32 + ln)) * 64 + ks * 16 + kg * 8;
            bf16x8 aH = *(const bf16x8*)(cbH + wo);
            bf16x8 aL = *(const bf16x8*)(cbL + wo);
            bf16x8 bH = *(const bf16x8*)&zH[tok * 72 + ks * 16 + kg * 8];
            bf16x8 bL = *(const bf16x8*)&zL[tok * 72 + ks * 16 + kg * 8];
            a0 = __builtin_amdgcn_mfma_f32_32x32x16_bf16(aH, bH, a0, 0, 0, 0);
            a1 = __builtin_amdgcn_mfma_f32_32x32x16_bf16(aH, bL, a1, 0, 0, 0);
            a1 = __builtin_amdgcn_mfma_f32_32x32x16_bf16(aL, bH, a1, 0, 0, 0);
        }
#pragma unroll
        for (int r = 0; r < 16; r++) {
            int m    = (r & 3) + 8 * (r >> 2) + 4 * kg;   // ascending in r
            int code = cg * 32 + m;
            float s  = a0[r] + a1[r];
            float dm = cnl[code] - 2.f * s;
            if (dm < bm) { bm = dm; bidx = code; }
        }
    }

    float bm2 = __shfl_xor(bm, 32);
    int   bi2 = __shfl_xor(bidx, 32);
    if (bm2 < bm || (bm2 == bm && bi2 < bidx)) { bm = bm2; bidx = bi2; }

    // packed q gather (bf16 hi of codebook)
    {
        int t = blk * 128 + tok;
        int n = t >> 12, pix = t & 4095;
#pragma unroll
        for (int cgl = 0; cgl < 4; cgl++) {
            int cg = kg * 4 + cgl;
            uint4 hv = *(const uint4*)(cbH + (size_t)bidx * 64 + cg * 8);
            size_t a = (((size_t)(n * 8 + cg)) * 4096 + pix) * 8;
            *(uint4*)(qPH + a) = hv;
        }
    }

    float bestd = xn + bm;
    float c = (kg == 0) ? bestd : 0.f;
#pragma unroll
    for (int o = 32; o > 0; o >>= 1) c += __shfl_down(c, o, 64);
    if (l == 0) ssep[blk * 4 + wv] = c;
    if (kg == 0) atomicAdd(&hl[bidx], 1);
    __syncthreads();
    for (int i = tid; i < 512; i += 256) if (hl[i] > 0) atomicAdd(&hist[i], hl[i]);
}

__global__ void vq_init(int* hist)
{
    for (int i = threadIdx.x; i < 512; i += 256) hist[i] = 0;
}

__global__ __launch_bounds__(256) void vq_finalize(
    const float* __restrict__ ssep, const int* __restrict__ hist,
    float* __restrict__ o_loss, float* __restrict__ o_perp)
{
    __shared__ float red[256];
    const int tid = threadIdx.x;
    float h = 0.f;
    for (int i = tid; i < 512; i += 256) {
        float p = (float)hist[i] * (1.0f / 65536.0f);
        h -= p * logf(p + 1e-10f);
    }
    red[tid] = h;
    __syncthreads();
    for (int st = 128; st > 0; st >>= 1) {
        if (tid < st) red[tid] += red[tid + st];
        __syncthreads();
    }
    const float H = red[0];
    __syncthreads();
    float s = 0.f;
    for (int i = tid; i < 2048; i += 256) s += ssep[i];
    red[tid] = s;
    __syncthreads();
    for (int st = 128; st > 0; st >>= 1) {
        if (tid < st) red[tid] += red[tid + st];
        __syncthreads();
    }
    if (tid == 0) {
        *o_loss = 1.25f * red[0] / 4194304.0f;
        *o_perp = expf(H);
    }
}

extern "C" void kernel_launch(void* const* d_in, const int* in_sizes, int n_in,
                              void* d_out, int out_size, void* d_ws, size_t ws_size,
                              hipStream_t stream)
{
    const float* x       = (const float*)d_in[0];
    const float* enc_w1  = (const float*)d_in[1];
    const float* enc_b1  = (const float*)d_in[2];
    const float* enc_w2  = (const float*)d_in[3];
    const float* enc_b2  = (const float*)d_in[4];
    const float* enc_w3  = (const float*)d_in[5];
    const float* enc_b3  = (const float*)d_in[6];
    const float* enc_rw3 = (const float*)d_in[7];
    const float* enc_rb3 = (const float*)d_in[8];
    const float* enc_rw1 = (const float*)d_in[9];
    const float* enc_rb1 = (const float*)d_in[10];
    const float* pre_w   = (const float*)d_in[11];
    const float* pre_b   = (const float*)d_in[12];
    const float* cb      = (const float*)d_in[13];
    const float* dec_w1  = (const float*)d_in[14];
    const float* dec_b1  = (const float*)d_in[15];
    const float* dec_rw3 = (const float*)d_in[16];
    const float* dec_rb3 = (const float*)d_in[17];
    const float* dec_rw1 = (const float*)d_in[18];
    const float* dec_rb1 = (const float*)d_in[19];
    const float* dw1     = (const float*)d_in[20];
    const float* db1     = (const float*)d_in[21];
    const float* dw2     = (const float*)d_in[22];
    const float* db2     = (const float*)d_in[23];

    float* o      = (float*)d_out;
    float* loss_p = o;
    float* recon  = o + 1;
    float* perp_p = o + 1 + 16 * 3 * 256 * 256;

    // ws: R1(H,L) 16.78M shorts each | R2(H,L) | Cf 8.39M f32 | SSE 2048 | HIST | weights
    unsigned short* R1H = (unsigned short*)d_ws;
    unsigned short* R1L = R1H + 16777216;
    unsigned short* R2H = R1L + 16777216;
    unsigned short* R2L = R2H + 16777216;
    float* Cf  = (float*)(R2L + 16777216);
    float* SSE = Cf + 8388608;
    int*   HIST = (int*)(SSE + 2048);

    // packed activation aliases (lifetime-disjoint)
    unsigned short *xPH = R1H;                                  // until enc1
    unsigned short *BPH = R1H;                                  // enc2->enc3
    unsigned short *zPH = R1H + 8388608, *zPL = R1L + 8388608;  // pre->vq (split!)
    unsigned short *DtPH = R1H + 12582912;                      // res temps
    unsigned short *dAPH = R1H;                                 // convt1->convt2
    unsigned short *APH = R2H;                                  // enc1->enc2
    unsigned short *CPH = R2H;                                  // relu(C), enc3..convt1
    unsigned short *qPH = R2H + 8388608;                        // vq->dec1

    unsigned short* wp_cur = (unsigned short*)(((size_t)(HIST + 512) + 31) & ~(size_t)31);
    auto carve = [&](size_t n_us) {
        unsigned short* p = wp_cur;
        wp_cur += ((n_us + 15) & ~(size_t)15);
        return p;
    };
    auto PK = [&](const float* w, unsigned short* hi, unsigned short* lo,
                  int Co, int Ci, int KK, int CoP, int CiP) {
        int tot = KK * CoP * CiP;
        pack_w<<<dim3((tot + 255) / 256), dim3(256), 0, stream>>>(w, hi, lo, Co, Ci, KK, CoP, CiP);
    };

    unsigned short *e1H = carve(16*64*16),  *e1L = carve(16*64*16);
    unsigned short *e2H = carve(16*128*64), *e2L = carve(16*128*64);
    unsigned short *e3H = carve(9*128*128), *e3L = carve(9*128*128);
    unsigned short *er3aH = carve(9*32*128), *er3aL = carve(9*32*128);
    unsigned short *er3bH = carve(9*32*128), *er3bL = carve(9*32*128);
    unsigned short *er1aH = carve(128*32),   *er1aL = carve(128*32);
    unsigned short *er1bH = carve(128*32),   *er1bL = carve(128*32);
    unsigned short *preH = carve(64*128),    *preL = carve(64*128);
    unsigned short *d1H  = carve(9*128*64),  *d1L  = carve(9*128*64);
    unsigned short *dr3aH = carve(9*32*128), *dr3aL = carve(9*32*128);
    unsigned short *dr3bH = carve(9*32*128), *dr3bL = carve(9*32*128);
    unsigned short *dr1aH = carve(128*32),   *dr1aL = carve(128*32);
    unsigned short *dr1bH = carve(128*32),   *dr1bL = carve(128*32);
    unsigned short *ct1H = carve(16*64*128), *ct1L = carve(16*64*128);
    unsigned short *ct2H = carve(16*32*64),  *ct2L = carve(16*32*64);
    unsigned short *cbH  = carve(512*64),    *cbL  = carve(512*64);
    float* CN = (float*)carve(1024);

    PK(enc_w1, e1H, e1L, 64, 3, 16, 64, 16);
    PK(enc_w2, e2H, e2L, 128, 64, 16, 128, 64);
    PK(enc_w3, e3H, e3L, 128, 128, 9, 128, 128);
    PK(enc_rw3,             er3aH, er3aL, 32, 128, 9, 32, 128);
    PK(enc_rw3 + 32*128*9,  er3bH, er3bL, 32, 128, 9, 32, 128);
    PK(enc_rw1,             er1aH, er1aL, 128, 32, 1, 128, 32);
    PK(enc_rw1 + 128*32,    er1bH, er1bL, 128, 32, 1, 128, 32);
    PK(pre_w, preH, preL, 64, 128, 1, 64, 128);
    PK(dec_w1, d1H, d1L, 128, 64, 9, 128, 64);
    PK(dec_rw3,             dr3aH, dr3aL, 32, 128, 9, 32, 128);
    PK(dec_rw3 + 32*128*9,  dr3bH, dr3bL, 32, 128, 9, 32, 128);
    PK(dec_rw1,             dr1aH, dr1aL, 128, 32, 1, 128, 32);
    PK(dec_rw1 + 128*32,    dr1bH, dr1bL, 128, 32, 1, 128, 32);
    PK(dw1, ct1H, ct1L, 64, 128, 16, 64, 128);
    PK(dw2, ct2H, ct2L, 3, 64, 16, 32, 64);
    PK(cb,  cbH,  cbL,  512, 64, 1, 512, 64);
    cb_norm<<<dim3(2), dim3(256), 0, stream>>>(cb, CN);
    pack_x<<<dim3(4096), dim3(256), 0, stream>>>(x, xPH);

    const int N = 16;

    // ---- encoder ----
    conv_mfma<4,2,1, 16,64, 256,256, 128,128, 2,64, 2,2,2,1, 1, 64,
              true,false,false,false,true,false>
        <<<dim3(128,1,N),256,0,stream>>>(xPH, e1H, enc_b1, nullptr, nullptr, APH, nullptr);
    conv_mfma<4,2,1, 64,128, 128,128, 64,64, 2,64, 2,2,2,2, 1, 128,
              true,false,false,false,true,false>
        <<<dim3(32,1,N),256,0,stream>>>(APH, e2H, enc_b2, nullptr, nullptr, BPH, nullptr);
    conv_mfma<3,1,1, 128,128, 64,64, 64,64, 2,64, 2,2,2,2, 2, 128,
              true,true,false,true,false,false>
        <<<dim3(32,1,N),256,0,stream>>>(BPH, e3H, enc_b3, nullptr, Cf, CPH, nullptr);
    conv_mfma<3,1,1, 128,32, 64,64, 64,64, 4,64, 1,4,2,1, 2, 32,
              true,true,false,false,false,false>
        <<<dim3(16,1,N),256,0,stream>>>(CPH, er3aH, enc_rb3, nullptr, nullptr, DtPH, nullptr);
    conv1x1_mfma<32,128, 4096, 128,  true,true,false,true,false,true>
        <<<dim3(64,2,N),256,0,stream>>>(DtPH, er1aH, enc_rb1, Cf, Cf, CPH, nullptr);
    conv_mfma<3,1,1, 128,32, 64,64, 64,64, 4,64, 1,4,2,1, 2, 32,
              true,true,false,false,false,false>
        <<<dim3(16,1,N),256,0,stream>>>(CPH, er3bH, enc_rb3 + 32, nullptr, nullptr, DtPH, nullptr);
    conv1x1_mfma<32,128, 4096, 128,  true,true,false,true,false,true>
        <<<dim3(64,2,N),256,0,stream>>>(DtPH, er1bH, enc_rb1 + 128, Cf, Cf, CPH, nullptr);
    conv1x1_mfma<128,64, 4096, 64,   true,false,true,false,false,false>
        <<<dim3(64,1,N),256,0,stream>>>(CPH, preH, pre_b, nullptr, nullptr, zPH, zPL);

    // ---- VQ ----
    vq_init<<<dim3(1), dim3(256), 0, stream>>>(HIST);
    vq_mfma<<<dim3(512), dim3(256), 0, stream>>>(zPH, zPL, cbH, cbL, CN, qPH, SSE, HIST);
    vq_finalize<<<dim3(1), dim3(256), 0, stream>>>(SSE, HIST, loss_p, perp_p);

    // ---- decoder ----
    conv_mfma<3,1,1, 64,128, 64,64, 64,64, 2,64, 2,2,2,2, 2, 128,
              true,true,false,true,false,false>
        <<<dim3(32,1,N),256,0,stream>>>(qPH, d1H, dec_b1, nullptr, Cf, CPH, nullptr);
    conv_mfma<3,1,1, 128,32, 64,64, 64,64, 4,64, 1,4,2,1, 2, 32,
              true,true,false,false,false,false>
        <<<dim3(16,1,N),256,0,stream>>>(CPH, dr3aH, dec_rb3, nullptr, nullptr, DtPH, nullptr);
    conv1x1_mfma<32,128, 4096, 128,  true,true,false,true,false,true>
        <<<dim3(64,2,N),256,0,stream>>>(DtPH, dr1aH, dec_rb1, Cf, Cf, CPH, nullptr);
    conv_mfma<3,1,1, 128,32, 64,64, 64,64, 4,64, 1,4,2,1, 2, 32,
              true,true,false,false,false,false>
        <<<dim3(16,1,N),256,0,stream>>>(CPH, dr3bH, dec_rb3 + 32, nullptr, nullptr, DtPH, nullptr);
    conv1x1_mfma<32,128, 4096, 128,  true,true,false,true,false,true>
        <<<dim3(64,2,N),256,0,stream>>>(DtPH, dr1bH, dec_rb1 + 128, Cf, Cf, CPH, nullptr);
    convt_mfma<128,64, 64,64, 2, 2, 64,  true,false,true>
        <<<dim3(64,1,N),256,0,stream>>>(CPH, ct1H, db1, nullptr, dAPH);
    convt_mfma<64,3, 128,128, 1, 2, 32,  false,true,false>
        <<<dim3(256,1,N),256,0,stream>>>(dAPH, ct2H, db2, recon, nullptr);
}